// Round 1
// baseline (1156.591 us; speedup 1.0000x reference)
//
#include <hip/hip_runtime.h>

#define B_ 2
#define N_ 2048
#define C_ 256
#define H_ 8
#define HD_ 32
#define EPSf 1e-5f

// ---- workspace layout (floats) --------------------------------------------
static constexpr size_t SZf      = (size_t)B_ * C_ * N_;   // 1,048,576
static constexpr size_t OFF_FAN  = 0;          // featA_norm (B,C,N)
static constexpr size_t OFF_Q    = 1 * SZf;    // q proj
static constexpr size_t OFF_K    = 2 * SZf;    // k proj
static constexpr size_t OFF_V    = 3 * SZf;    // v proj
static constexpr size_t OFF_QD   = 4 * SZf;    // qd proj
static constexpr size_t OFF_KD   = 5 * SZf;    // kd proj
static constexpr size_t OFF_CTXS = 6 * SZf;    // ctx_sim (then LN'd in place)
static constexpr size_t OFF_CTXD = 7 * SZf;    // ctx_dis (then LN'd in place)
static constexpr size_t OFF_X1   = 8 * SZf;    // fusion hidden (B,2C,N) = 2*SZf
static constexpr size_t OFF_QQ   = 10 * SZf;                    // (B,N)
static constexpr size_t OFF_KK   = 10 * SZf + (size_t)B_ * N_;  // (B,N)
static constexpr size_t WS_FLOATS = 10 * SZf + 2 * (size_t)B_ * N_; // ~42 MB

// ---- LayerNorm over channel axis: one block per (b,n) ----------------------
__global__ __launch_bounds__(256) void ln_kernel(const float* __restrict__ in,
    float* __restrict__ out, const float* __restrict__ g, const float* __restrict__ bta){
  int bn = blockIdx.x;
  int b = bn / N_, n = bn % N_;
  int c = threadIdx.x;
  size_t idx = ((size_t)(b * C_ + c)) * N_ + n;
  float v = in[idx];
  float s1 = v, s2 = v * v;
  #pragma unroll
  for (int off = 32; off > 0; off >>= 1){
    s1 += __shfl_down(s1, off);
    s2 += __shfl_down(s2, off);
  }
  __shared__ float p1[4], p2[4], mv[2];
  int wid = threadIdx.x >> 6, lane = threadIdx.x & 63;
  if (lane == 0){ p1[wid] = s1; p2[wid] = s2; }
  __syncthreads();
  if (threadIdx.x == 0){
    float a = p1[0] + p1[1] + p1[2] + p1[3];
    float q = p2[0] + p2[1] + p2[2] + p2[3];
    float m = a / (float)C_;
    float var = q / (float)C_ - m * m;
    mv[0] = m; mv[1] = rsqrtf(var + EPSf);
  }
  __syncthreads();
  out[idx] = (v - mv[0]) * mv[1] * g[c] + bta[c];
}

// ---- 5-way projection GEMM: Y = W(256x256) @ X + bias ----------------------
__global__ __launch_bounds__(256) void proj_kernel(float* __restrict__ ws,
    const float* __restrict__ featB,
    const float* __restrict__ qw, const float* __restrict__ qb,
    const float* __restrict__ kw, const float* __restrict__ kb,
    const float* __restrict__ vw, const float* __restrict__ vb,
    const float* __restrict__ qdw, const float* __restrict__ qdb,
    const float* __restrict__ kdw, const float* __restrict__ kdb){
  int p = blockIdx.z % 5, b = blockIdx.z / 5;
  size_t boff = (size_t)b * C_ * N_;
  const float *W, *bias, *X; float* Y;
  if (p == 0)      { W = qw;  bias = qb;  X = ws + OFF_FAN + boff; Y = ws + OFF_Q  + boff; }
  else if (p == 1) { W = kw;  bias = kb;  X = featB + boff;        Y = ws + OFF_K  + boff; }
  else if (p == 2) { W = vw;  bias = vb;  X = featB + boff;        Y = ws + OFF_V  + boff; }
  else if (p == 3) { W = qdw; bias = qdb; X = ws + OFF_FAN + boff; Y = ws + OFF_QD + boff; }
  else             { W = kdw; bias = kdb; X = featB + boff;        Y = ws + OFF_KD + boff; }

  __shared__ float As[16][65], Bs[16][65];
  int t = threadIdx.x, tx = t & 15, ty = t >> 4;
  int o0 = blockIdx.y * 64, n0 = blockIdx.x * 64;
  float acc[4][4] = {};
  for (int k0 = 0; k0 < C_; k0 += 16){
    int kkl = t & 15, ob = t >> 4;
    #pragma unroll
    for (int i = 0; i < 4; i++)
      As[kkl][ob + 16 * i] = W[(size_t)(o0 + ob + 16 * i) * C_ + k0 + kkl];
    int nn = t & 63, kb4 = t >> 6;
    #pragma unroll
    for (int i = 0; i < 4; i++)
      Bs[kb4 + 4 * i][nn] = X[(size_t)(k0 + kb4 + 4 * i) * N_ + n0 + nn];
    __syncthreads();
    #pragma unroll
    for (int kk2 = 0; kk2 < 16; kk2++){
      float a[4], bb[4];
      #pragma unroll
      for (int i = 0; i < 4; i++) a[i] = As[kk2][ty * 4 + i];
      #pragma unroll
      for (int j = 0; j < 4; j++) bb[j] = Bs[kk2][tx * 4 + j];
      #pragma unroll
      for (int i = 0; i < 4; i++)
        #pragma unroll
        for (int j = 0; j < 4; j++)
          acc[i][j] += a[i] * bb[j];
    }
    __syncthreads();
  }
  #pragma unroll
  for (int i = 0; i < 4; i++){
    int o = o0 + ty * 4 + i;
    float bz = bias[o];
    #pragma unroll
    for (int j = 0; j < 4; j++)
      Y[(size_t)o * N_ + n0 + tx * 4 + j] = acc[i][j] + bz;
  }
}

// ---- row norms |qd|^2, |kd|^2 ---------------------------------------------
__global__ __launch_bounds__(256) void norms_kernel(const float* __restrict__ qd,
    const float* __restrict__ kd, float* __restrict__ qq, float* __restrict__ kk){
  int b = blockIdx.y, n0 = blockIdx.x * 64;
  int nn = threadIdx.x & 63, cg = threadIdx.x >> 6;
  float s1 = 0.f, s2 = 0.f;
  for (int c = cg; c < C_; c += 4){
    size_t idx = ((size_t)(b * C_ + c)) * N_ + n0 + nn;
    float a = qd[idx]; s1 += a * a;
    float d = kd[idx]; s2 += d * d;
  }
  __shared__ float r1[4][64], r2[4][64];
  r1[cg][nn] = s1; r2[cg][nn] = s2;
  __syncthreads();
  if (cg == 0){
    qq[b * N_ + n0 + nn] = r1[0][nn] + r1[1][nn] + r1[2][nn] + r1[3][nn];
    kk[b * N_ + n0 + nn] = r2[0][nn] + r2[1][nn] + r2[2][nn] + r2[3][nn];
  }
}

// ---- similarity path: flash attention, one block = (b, h, 32 query rows) ---
__global__ __launch_bounds__(256) void sim_attn(
    const float* __restrict__ qbuf, const float* __restrict__ kbuf, const float* __restrict__ vbuf,
    const float* __restrict__ xyzA, const float* __restrict__ xyzB,
    const float* __restrict__ sbw1, const float* __restrict__ sbg, const float* __restrict__ sbb,
    const float* __restrict__ sbm, const float* __restrict__ sbv,
    const float* __restrict__ sbw2, const float* __restrict__ sbb2,
    float* __restrict__ ctxs){
  int n0 = blockIdx.x * 32, h = blockIdx.y, b = blockIdx.z;
  int t = threadIdx.x;
  __shared__ float ks[64][33];
  __shared__ float vs[64][36];   // stride 36 -> 16B-aligned rows for float4 reads
  __shared__ float ss[32][65];
  __shared__ float xa[32][3], xb[64][3];
  __shared__ float mrun[32], lrun[32], alps[32];
  __shared__ float Acf[4], Bcf[4], W2h[4];
  __shared__ float C0s;

  if (t < 4){
    float rs = rsqrtf(sbv[t] + EPSf);
    Acf[t] = -sbw1[t] * rs * sbg[t];
    Bcf[t] = -sbm[t] * rs * sbg[t] + sbb[t];
    W2h[t] = sbw2[h * 4 + t];
  }
  if (t == 0) C0s = sbb2[h];
  if (t < 32){
    mrun[t] = -1e30f; lrun[t] = 0.f;
    xa[t][0] = xyzA[((size_t)(b * N_ + n0 + t)) * 3 + 0];
    xa[t][1] = xyzA[((size_t)(b * N_ + n0 + t)) * 3 + 1];
    xa[t][2] = xyzA[((size_t)(b * N_ + n0 + t)) * 3 + 2];
  }
  // q row for this thread's scores mapping (r = t&31), pre-scaled by 1/sqrt(HD)
  float qreg[32];
  {
    int r = t & 31;
    const float inv = 0.17677669529663687f;
    #pragma unroll
    for (int d = 0; d < 32; d++)
      qreg[d] = qbuf[((size_t)(b * C_ + h * HD_ + d)) * N_ + n0 + r] * inv;
  }
  float acc0 = 0.f, acc1 = 0.f, acc2 = 0.f, acc3 = 0.f; // PV mapping r=t>>3, dc=(t&7)*4
  __syncthreads();

  for (int m0 = 0; m0 < N_; m0 += 64){
    { // stage K/V tile
      int m = t & 63, dg = t >> 6;
      #pragma unroll
      for (int i = 0; i < 8; i++){
        int d = dg + 4 * i;
        size_t gi = ((size_t)(b * C_ + h * HD_ + d)) * N_ + m0 + m;
        ks[m][d] = kbuf[gi];
        vs[m][d] = vbuf[gi];
      }
      if (t < 64){
        xb[t][0] = xyzB[((size_t)(b * N_ + m0 + t)) * 3 + 0];
        xb[t][1] = xyzB[((size_t)(b * N_ + m0 + t)) * 3 + 1];
        xb[t][2] = xyzB[((size_t)(b * N_ + m0 + t)) * 3 + 2];
      }
    }
    __syncthreads();
    { // scores: thread (r = t&31) computes 8 columns
      int r = t & 31, mg = t >> 5;
      float ax = xa[r][0], ay = xa[r][1], az = xa[r][2];
      #pragma unroll
      for (int mi = 0; mi < 8; mi++){
        int m = mg * 8 + mi;
        float dot = 0.f;
        #pragma unroll
        for (int d = 0; d < 32; d++) dot += qreg[d] * ks[m][d];
        float dx = ax - xb[m][0], dy = ay - xb[m][1], dz = az - xb[m][2];
        float dist = sqrtf(dx * dx + dy * dy + dz * dz);
        float sb = C0s;
        #pragma unroll
        for (int j = 0; j < 4; j++)
          sb += W2h[j] * fmaxf(fmaf(Acf[j], dist, Bcf[j]), 0.f);
        ss[r][m] = dot + sb;
      }
    }
    __syncthreads();
    { // online softmax: 8 threads per row
      int r = t >> 3, sub = t & 7;
      float v8[8];
      float mx = -1e30f;
      #pragma unroll
      for (int i = 0; i < 8; i++){ v8[i] = ss[r][sub * 8 + i]; mx = fmaxf(mx, v8[i]); }
      #pragma unroll
      for (int off = 1; off < 8; off <<= 1) mx = fmaxf(mx, __shfl_xor(mx, off));
      float newm = fmaxf(mrun[r], mx);
      float al = __expf(mrun[r] - newm);
      float psum = 0.f;
      #pragma unroll
      for (int i = 0; i < 8; i++){
        float pv = __expf(v8[i] - newm);
        ss[r][sub * 8 + i] = pv;
        psum += pv;
      }
      #pragma unroll
      for (int off = 1; off < 8; off <<= 1) psum += __shfl_xor(psum, off);
      if (sub == 0){
        lrun[r] = lrun[r] * al + psum;
        mrun[r] = newm;
        alps[r] = al;
      }
    }
    __syncthreads();
    { // PV accumulate: thread = (row r, 4 head-dims)
      int r = t >> 3, dc = (t & 7) * 4;
      float al = alps[r];
      acc0 *= al; acc1 *= al; acc2 *= al; acc3 *= al;
      for (int m = 0; m < 64; m++){
        float pv = ss[r][m];
        const float4 v4 = *reinterpret_cast<const float4*>(&vs[m][dc]);
        acc0 += pv * v4.x; acc1 += pv * v4.y; acc2 += pv * v4.z; acc3 += pv * v4.w;
      }
    }
    __syncthreads();
  }
  {
    int r = t >> 3, dc = (t & 7) * 4;
    float invl = 1.f / lrun[r];
    size_t base = ((size_t)(b * C_ + h * HD_ + dc)) * N_ + n0 + r;
    ctxs[base]          = acc0 * invl;
    ctxs[base + N_]     = acc1 * invl;
    ctxs[base + 2 * N_] = acc2 * invl;
    ctxs[base + 3 * N_] = acc3 * invl;
  }
}

// ---- dissimilarity path: one block = (b, 16 query rows, ALL heads) ---------
// LDS column swizzle for qds/kds: CI(c) spreads the stride-16 channel groups
#define CI(c) ((c) + ((c) >> 4))

__global__ __launch_bounds__(256) void dis_attn(
    const float* __restrict__ qdbuf, const float* __restrict__ kdbuf, const float* __restrict__ vbuf,
    const float* __restrict__ qq, const float* __restrict__ kkn,
    const float* __restrict__ xyzA, const float* __restrict__ xyzB,
    const float* __restrict__ sbw1, const float* __restrict__ sbg, const float* __restrict__ sbb,
    const float* __restrict__ sbm, const float* __restrict__ sbv,
    const float* __restrict__ sbw2, const float* __restrict__ sbb2,
    float* __restrict__ ctxd){
  int n0 = blockIdx.x * 16, b = blockIdx.y;
  int t = threadIdx.x;
  __shared__ float qds[16][271];   // 271 odd -> conflict-free with CI swizzle
  __shared__ float kds[16][271];
  __shared__ float vs2[16][260];   // 260 -> 16B-aligned rows for float4
  __shared__ float sd[16][8][17];
  __shared__ float xa[16][3], xb[16][3], qqs[16], kks[16];
  __shared__ float mrun[16][8], lrun[16][8], alph[16][8];
  __shared__ float Acf[4], Bcf[4], W2[8][4], C0s[8];

  if (t < 4){
    float rs = rsqrtf(sbv[t] + EPSf);
    Acf[t] = -sbw1[t] * rs * sbg[t];
    Bcf[t] = -sbm[t] * rs * sbg[t] + sbb[t];
  }
  if (t < 32) W2[t >> 2][t & 3] = sbw2[t];
  if (t < 8)  C0s[t] = sbb2[t];
  { // load qd rows (swizzled)
    int r = t & 15, cg = t >> 4;
    #pragma unroll
    for (int i = 0; i < 16; i++){
      int c = i * 16 + cg;
      qds[r][CI(c)] = qdbuf[((size_t)(b * C_ + c)) * N_ + n0 + r];
    }
  }
  if (t < 16){
    qqs[t] = qq[b * N_ + n0 + t];
    xa[t][0] = xyzA[((size_t)(b * N_ + n0 + t)) * 3 + 0];
    xa[t][1] = xyzA[((size_t)(b * N_ + n0 + t)) * 3 + 1];
    xa[t][2] = xyzA[((size_t)(b * N_ + n0 + t)) * 3 + 2];
  }
  if (t < 128){ mrun[t >> 3][t & 7] = -1e30f; lrun[t >> 3][t & 7] = 0.f; }
  float acc[4][4];
  #pragma unroll
  for (int i = 0; i < 4; i++)
    #pragma unroll
    for (int j = 0; j < 4; j++) acc[i][j] = 0.f;
  __syncthreads();

  for (int m0 = 0; m0 < N_; m0 += 16){
    { // stage kd / v tiles
      int m = t & 15, cg = t >> 4;
      #pragma unroll
      for (int i = 0; i < 16; i++){
        int c = i * 16 + cg;
        size_t gi = ((size_t)(b * C_ + c)) * N_ + m0 + m;
        kds[m][CI(c)] = kdbuf[gi];
        vs2[m][c] = vbuf[gi];
      }
      if (t < 16){
        kks[t] = kkn[b * N_ + m0 + t];
        xb[t][0] = xyzB[((size_t)(b * N_ + m0 + t)) * 3 + 0];
        xb[t][1] = xyzB[((size_t)(b * N_ + m0 + t)) * 3 + 1];
        xb[t][2] = xyzB[((size_t)(b * N_ + m0 + t)) * 3 + 2];
      }
    }
    __syncthreads();
    { // scores: one (r,m) pair per thread; dot over 256 channels, shared by 8 heads
      int r = t >> 4, m = t & 15;
      float a0 = 0.f, a1 = 0.f, a2 = 0.f, a3 = 0.f;
      for (int c = 0; c < C_; c += 4){
        int ci = c + (c >> 4);   // blocks of 4 never straddle a 16-boundary
        a0 += qds[r][ci    ] * kds[m][ci    ];
        a1 += qds[r][ci + 1] * kds[m][ci + 1];
        a2 += qds[r][ci + 2] * kds[m][ci + 2];
        a3 += qds[r][ci + 3] * kds[m][ci + 3];
      }
      float dot = (a0 + a1) + (a2 + a3);
      float d2 = qqs[r] + kks[m] - 2.f * dot;       // reference cdist formula
      float fdist = sqrtf(fmaxf(d2, 0.f));
      float dx = xa[r][0] - xb[m][0], dy = xa[r][1] - xb[m][1], dz = xa[r][2] - xb[m][2];
      float sdist = sqrtf(dx * dx + dy * dy + dz * dz);
      float u0 = fmaxf(fmaf(Acf[0], sdist, Bcf[0]), 0.f);
      float u1 = fmaxf(fmaf(Acf[1], sdist, Bcf[1]), 0.f);
      float u2 = fmaxf(fmaf(Acf[2], sdist, Bcf[2]), 0.f);
      float u3 = fmaxf(fmaf(Acf[3], sdist, Bcf[3]), 0.f);
      #pragma unroll
      for (int hh = 0; hh < 8; hh++){
        float sb = C0s[hh] + W2[hh][0] * u0 + W2[hh][1] * u1 + W2[hh][2] * u2 + W2[hh][3] * u3;
        sd[r][hh][m] = fdist + sb;
      }
    }
    __syncthreads();
    if (t < 128){ // online softmax per (row, head)
      int r = t >> 3, hh = t & 7;
      float mx = -1e30f;
      #pragma unroll
      for (int m = 0; m < 16; m++) mx = fmaxf(mx, sd[r][hh][m]);
      float newm = fmaxf(mrun[r][hh], mx);
      float al = __expf(mrun[r][hh] - newm);
      float s = 0.f;
      #pragma unroll
      for (int m = 0; m < 16; m++){
        float pv = __expf(sd[r][hh][m] - newm);
        sd[r][hh][m] = pv;
        s += pv;
      }
      lrun[r][hh] = lrun[r][hh] * al + s;
      mrun[r][hh] = newm;
      alph[r][hh] = al;
    }
    __syncthreads();
    { // PV: thread = (4 rows rg*4+i, 4 channels cq*4+j); head = channel/32
      int rg = t >> 6, cq = t & 63, hh = cq >> 3;
      float al0 = alph[rg * 4 + 0][hh], al1 = alph[rg * 4 + 1][hh];
      float al2 = alph[rg * 4 + 2][hh], al3 = alph[rg * 4 + 3][hh];
      #pragma unroll
      for (int j = 0; j < 4; j++){
        acc[0][j] *= al0; acc[1][j] *= al1; acc[2][j] *= al2; acc[3][j] *= al3;
      }
      for (int m = 0; m < 16; m++){
        const float4 v4 = *reinterpret_cast<const float4*>(&vs2[m][cq * 4]);
        float p0 = sd[rg * 4 + 0][hh][m], p1 = sd[rg * 4 + 1][hh][m];
        float p2 = sd[rg * 4 + 2][hh][m], p3 = sd[rg * 4 + 3][hh][m];
        acc[0][0] += p0 * v4.x; acc[0][1] += p0 * v4.y; acc[0][2] += p0 * v4.z; acc[0][3] += p0 * v4.w;
        acc[1][0] += p1 * v4.x; acc[1][1] += p1 * v4.y; acc[1][2] += p1 * v4.z; acc[1][3] += p1 * v4.w;
        acc[2][0] += p2 * v4.x; acc[2][1] += p2 * v4.y; acc[2][2] += p2 * v4.z; acc[2][3] += p2 * v4.w;
        acc[3][0] += p3 * v4.x; acc[3][1] += p3 * v4.y; acc[3][2] += p3 * v4.z; acc[3][3] += p3 * v4.w;
      }
    }
    __syncthreads();
  }
  {
    int rg = t >> 6, cq = t & 63, hh = cq >> 3;
    #pragma unroll
    for (int i = 0; i < 4; i++){
      float invl = 1.f / lrun[rg * 4 + i][hh];
      #pragma unroll
      for (int j = 0; j < 4; j++)
        ctxd[((size_t)(b * C_ + cq * 4 + j)) * N_ + n0 + rg * 4 + i] = acc[i][j] * invl;
    }
  }
}

// ---- fusion MLP stage 1: x1 = ReLU(BN(fw1 @ concat(fAn, ctxs, ctxd))) ------
__global__ __launch_bounds__(256) void fusion1_kernel(float* __restrict__ ws,
    const float* __restrict__ fw1, const float* __restrict__ fbg, const float* __restrict__ fbb,
    const float* __restrict__ fbm, const float* __restrict__ fbv){
  int b = blockIdx.z;
  const float* seg0 = ws + OFF_FAN  + (size_t)b * C_ * N_;
  const float* seg1 = ws + OFF_CTXS + (size_t)b * C_ * N_;
  const float* seg2 = ws + OFF_CTXD + (size_t)b * C_ * N_;
  float* Y = ws + OFF_X1 + (size_t)b * 2 * C_ * N_;
  __shared__ float As[16][65], Bs[16][65];
  int t = threadIdx.x, tx = t & 15, ty = t >> 4;
  int o0 = blockIdx.y * 64, n0 = blockIdx.x * 64;
  float acc[4][4] = {};
  for (int k0 = 0; k0 < 3 * C_; k0 += 16){
    int kkl = t & 15, ob = t >> 4;
    #pragma unroll
    for (int i = 0; i < 4; i++)
      As[kkl][ob + 16 * i] = fw1[(size_t)(o0 + ob + 16 * i) * (3 * C_) + k0 + kkl];
    int nn = t & 63, kb4 = t >> 6;
    #pragma unroll
    for (int i = 0; i < 4; i++){
      int c = k0 + kb4 + 4 * i;
      const float* base = (c < C_) ? seg0 : (c < 2 * C_ ? seg1 : seg2);
      Bs[kb4 + 4 * i][nn] = base[(size_t)(c & (C_ - 1)) * N_ + n0 + nn];
    }
    __syncthreads();
    #pragma unroll
    for (int kk2 = 0; kk2 < 16; kk2++){
      float a[4], bb[4];
      #pragma unroll
      for (int i = 0; i < 4; i++) a[i] = As[kk2][ty * 4 + i];
      #pragma unroll
      for (int j = 0; j < 4; j++) bb[j] = Bs[kk2][tx * 4 + j];
      #pragma unroll
      for (int i = 0; i < 4; i++)
        #pragma unroll
        for (int j = 0; j < 4; j++)
          acc[i][j] += a[i] * bb[j];
    }
    __syncthreads();
  }
  #pragma unroll
  for (int i = 0; i < 4; i++){
    int o = o0 + ty * 4 + i;
    float mn = fbm[o], rs = rsqrtf(fbv[o] + EPSf), gg = fbg[o], be = fbb[o];
    #pragma unroll
    for (int j = 0; j < 4; j++){
      float x = (acc[i][j] - mn) * rs * gg + be;
      Y[(size_t)o * N_ + n0 + tx * 4 + j] = fmaxf(x, 0.f);
    }
  }
}

// ---- fusion MLP stage 2: out = fw2 @ x1 + fb2 + featA ----------------------
__global__ __launch_bounds__(256) void fusion2_kernel(const float* __restrict__ ws,
    const float* __restrict__ fw2, const float* __restrict__ fb2,
    const float* __restrict__ featA, float* __restrict__ out){
  int b = blockIdx.z;
  const float* X = ws + OFF_X1 + (size_t)b * 2 * C_ * N_;
  __shared__ float As[16][65], Bs[16][65];
  int t = threadIdx.x, tx = t & 15, ty = t >> 4;
  int o0 = blockIdx.y * 64, n0 = blockIdx.x * 64;
  float acc[4][4] = {};
  for (int k0 = 0; k0 < 2 * C_; k0 += 16){
    int kkl = t & 15, ob = t >> 4;
    #pragma unroll
    for (int i = 0; i < 4; i++)
      As[kkl][ob + 16 * i] = fw2[(size_t)(o0 + ob + 16 * i) * (2 * C_) + k0 + kkl];
    int nn = t & 63, kb4 = t >> 6;
    #pragma unroll
    for (int i = 0; i < 4; i++)
      Bs[kb4 + 4 * i][nn] = X[(size_t)(k0 + kb4 + 4 * i) * N_ + n0 + nn];
    __syncthreads();
    #pragma unroll
    for (int kk2 = 0; kk2 < 16; kk2++){
      float a[4], bb[4];
      #pragma unroll
      for (int i = 0; i < 4; i++) a[i] = As[kk2][ty * 4 + i];
      #pragma unroll
      for (int j = 0; j < 4; j++) bb[j] = Bs[kk2][tx * 4 + j];
      #pragma unroll
      for (int i = 0; i < 4; i++)
        #pragma unroll
        for (int j = 0; j < 4; j++)
          acc[i][j] += a[i] * bb[j];
    }
    __syncthreads();
  }
  #pragma unroll
  for (int i = 0; i < 4; i++){
    int o = o0 + ty * 4 + i;
    float bz = fb2[o];
    #pragma unroll
    for (int j = 0; j < 4; j++){
      size_t oi = ((size_t)(b * C_ + o)) * N_ + n0 + tx * 4 + j;
      out[oi] = acc[i][j] + bz + featA[oi];
    }
  }
}

extern "C" void kernel_launch(void* const* d_in, const int* in_sizes, int n_in,
                              void* d_out, int out_size, void* d_ws, size_t ws_size,
                              hipStream_t stream){
  (void)in_sizes; (void)n_in; (void)out_size;
  if (ws_size < WS_FLOATS * sizeof(float)) return;  // need ~42 MB scratch

  const float* xyzA  = (const float*)d_in[0];
  const float* featA = (const float*)d_in[1];
  const float* xyzB  = (const float*)d_in[2];
  const float* featB = (const float*)d_in[3];
  const float* qw  = (const float*)d_in[4];   const float* qb  = (const float*)d_in[5];
  const float* kw  = (const float*)d_in[6];   const float* kb  = (const float*)d_in[7];
  const float* vw  = (const float*)d_in[8];   const float* vb  = (const float*)d_in[9];
  const float* sbw1= (const float*)d_in[10];  const float* sbg = (const float*)d_in[11];
  const float* sbb = (const float*)d_in[12];  const float* sbm = (const float*)d_in[13];
  const float* sbv = (const float*)d_in[14];  const float* sbw2= (const float*)d_in[15];
  const float* sbb2= (const float*)d_in[16];
  const float* qdw = (const float*)d_in[17];  const float* qdb = (const float*)d_in[18];
  const float* kdw = (const float*)d_in[19];  const float* kdb = (const float*)d_in[20];
  const float* ling= (const float*)d_in[21];  const float* linb= (const float*)d_in[22];
  const float* lsg = (const float*)d_in[23];  const float* lsb = (const float*)d_in[24];
  const float* ldg = (const float*)d_in[25];  const float* ldb = (const float*)d_in[26];
  const float* fw1 = (const float*)d_in[27];  const float* fbg = (const float*)d_in[28];
  const float* fbb = (const float*)d_in[29];  const float* fbm = (const float*)d_in[30];
  const float* fbv = (const float*)d_in[31];  const float* fw2 = (const float*)d_in[32];
  const float* fb2 = (const float*)d_in[33];
  float* ws = (float*)d_ws;
  float* out = (float*)d_out;

  ln_kernel<<<B_ * N_, 256, 0, stream>>>(featA, ws + OFF_FAN, ling, linb);
  proj_kernel<<<dim3(N_ / 64, C_ / 64, 5 * B_), 256, 0, stream>>>(
      ws, featB, qw, qb, kw, kb, vw, vb, qdw, qdb, kdw, kdb);
  norms_kernel<<<dim3(N_ / 64, B_), 256, 0, stream>>>(
      ws + OFF_QD, ws + OFF_KD, ws + OFF_QQ, ws + OFF_KK);
  sim_attn<<<dim3(N_ / 32, H_, B_), 256, 0, stream>>>(
      ws + OFF_Q, ws + OFF_K, ws + OFF_V, xyzA, xyzB,
      sbw1, sbg, sbb, sbm, sbv, sbw2, sbb2, ws + OFF_CTXS);
  dis_attn<<<dim3(N_ / 16, B_), 256, 0, stream>>>(
      ws + OFF_QD, ws + OFF_KD, ws + OFF_V, ws + OFF_QQ, ws + OFF_KK,
      xyzA, xyzB, sbw1, sbg, sbb, sbm, sbv, sbw2, sbb2, ws + OFF_CTXD);
  ln_kernel<<<B_ * N_, 256, 0, stream>>>(ws + OFF_CTXS, ws + OFF_CTXS, lsg, lsb);
  ln_kernel<<<B_ * N_, 256, 0, stream>>>(ws + OFF_CTXD, ws + OFF_CTXD, ldg, ldb);
  fusion1_kernel<<<dim3(N_ / 64, (2 * C_) / 64, B_), 256, 0, stream>>>(
      ws, fw1, fbg, fbb, fbm, fbv);
  fusion2_kernel<<<dim3(N_ / 64, C_ / 64, B_), 256, 0, stream>>>(
      ws, fw2, fb2, featA, out);
}

// Round 2
// 562.394 us; speedup vs baseline: 2.0566x; 2.0566x over previous
//
#include <hip/hip_runtime.h>

#define B_ 2
#define N_ 2048
#define C_ 256
#define H_ 8
#define HD_ 32
#define EPSf 1e-5f

typedef __bf16 bf16x8 __attribute__((ext_vector_type(8)));
typedef float  f32x4  __attribute__((ext_vector_type(4)));

// ---- workspace layout -------------------------------------------------------
static constexpr size_t SZf      = (size_t)B_ * C_ * N_;   // 1,048,576
static constexpr size_t OFF_FAN  = 0;
static constexpr size_t OFF_Q    = 1 * SZf;
static constexpr size_t OFF_K    = 2 * SZf;
static constexpr size_t OFF_V    = 3 * SZf;
static constexpr size_t OFF_QD   = 4 * SZf;
static constexpr size_t OFF_KD   = 5 * SZf;
static constexpr size_t OFF_CTXS = 6 * SZf;
static constexpr size_t OFF_CTXD = 7 * SZf;
static constexpr size_t OFF_X1   = 8 * SZf;
static constexpr size_t OFF_QQ   = 10 * SZf;
static constexpr size_t OFF_KK   = 10 * SZf + (size_t)B_ * N_;
static constexpr size_t WS_FLOATS = 10 * SZf + 2 * (size_t)B_ * N_;
// bf16 pack region appended after the float region (float region is 16B-multiple)
static constexpr size_t PK_Q  = 0;          // (B,H,N,HD)  q * 1/sqrt(HD)
static constexpr size_t PK_K  = 1 * SZf;    // (B,H,N,HD)
static constexpr size_t PK_V  = 2 * SZf;    // (B,C,N)
static constexpr size_t PK_QD = 3 * SZf;    // (B,N,C)
static constexpr size_t PK_KD = 4 * SZf;    // (B,N,C)
static constexpr size_t WS_BYTES_NEW = WS_FLOATS * sizeof(float) + 5 * SZf * sizeof(unsigned short);

__device__ __forceinline__ float rfl(float x){
  return __uint_as_float(__builtin_amdgcn_readfirstlane(__float_as_uint(x)));
}

// ---- LayerNorm over channel axis: one block per (b,n) ----------------------
__global__ __launch_bounds__(256) void ln_kernel(const float* __restrict__ in,
    float* __restrict__ out, const float* __restrict__ g, const float* __restrict__ bta){
  int bn = blockIdx.x;
  int b = bn / N_, n = bn % N_;
  int c = threadIdx.x;
  size_t idx = ((size_t)(b * C_ + c)) * N_ + n;
  float v = in[idx];
  float s1 = v, s2 = v * v;
  #pragma unroll
  for (int off = 32; off > 0; off >>= 1){
    s1 += __shfl_down(s1, off);
    s2 += __shfl_down(s2, off);
  }
  __shared__ float p1[4], p2[4], mv[2];
  int wid = threadIdx.x >> 6, lane = threadIdx.x & 63;
  if (lane == 0){ p1[wid] = s1; p2[wid] = s2; }
  __syncthreads();
  if (threadIdx.x == 0){
    float a = p1[0] + p1[1] + p1[2] + p1[3];
    float q = p2[0] + p2[1] + p2[2] + p2[3];
    float m = a / (float)C_;
    float var = q / (float)C_ - m * m;
    mv[0] = m; mv[1] = rsqrtf(var + EPSf);
  }
  __syncthreads();
  out[idx] = (v - mv[0]) * mv[1] * g[c] + bta[c];
}

// ---- 5-way projection GEMM: Y = W(256x256) @ X + bias ----------------------
__global__ __launch_bounds__(256) void proj_kernel(float* __restrict__ ws,
    const float* __restrict__ featB,
    const float* __restrict__ qw, const float* __restrict__ qb,
    const float* __restrict__ kw, const float* __restrict__ kb,
    const float* __restrict__ vw, const float* __restrict__ vb,
    const float* __restrict__ qdw, const float* __restrict__ qdb,
    const float* __restrict__ kdw, const float* __restrict__ kdb){
  int p = blockIdx.z % 5, b = blockIdx.z / 5;
  size_t boff = (size_t)b * C_ * N_;
  const float *W, *bias, *X; float* Y;
  if (p == 0)      { W = qw;  bias = qb;  X = ws + OFF_FAN + boff; Y = ws + OFF_Q  + boff; }
  else if (p == 1) { W = kw;  bias = kb;  X = featB + boff;        Y = ws + OFF_K  + boff; }
  else if (p == 2) { W = vw;  bias = vb;  X = featB + boff;        Y = ws + OFF_V  + boff; }
  else if (p == 3) { W = qdw; bias = qdb; X = ws + OFF_FAN + boff; Y = ws + OFF_QD + boff; }
  else             { W = kdw; bias = kdb; X = featB + boff;        Y = ws + OFF_KD + boff; }

  __shared__ float As[16][65], Bs[16][65];
  int t = threadIdx.x, tx = t & 15, ty = t >> 4;
  int o0 = blockIdx.y * 64, n0 = blockIdx.x * 64;
  float acc[4][4] = {};
  for (int k0 = 0; k0 < C_; k0 += 16){
    int kkl = t & 15, ob = t >> 4;
    #pragma unroll
    for (int i = 0; i < 4; i++)
      As[kkl][ob + 16 * i] = W[(size_t)(o0 + ob + 16 * i) * C_ + k0 + kkl];
    int nn = t & 63, kb4 = t >> 6;
    #pragma unroll
    for (int i = 0; i < 4; i++)
      Bs[kb4 + 4 * i][nn] = X[(size_t)(k0 + kb4 + 4 * i) * N_ + n0 + nn];
    __syncthreads();
    #pragma unroll
    for (int kk2 = 0; kk2 < 16; kk2++){
      float a[4], bb[4];
      #pragma unroll
      for (int i = 0; i < 4; i++) a[i] = As[kk2][ty * 4 + i];
      #pragma unroll
      for (int j = 0; j < 4; j++) bb[j] = Bs[kk2][tx * 4 + j];
      #pragma unroll
      for (int i = 0; i < 4; i++)
        #pragma unroll
        for (int j = 0; j < 4; j++)
          acc[i][j] += a[i] * bb[j];
    }
    __syncthreads();
  }
  #pragma unroll
  for (int i = 0; i < 4; i++){
    int o = o0 + ty * 4 + i;
    float bz = bias[o];
    #pragma unroll
    for (int j = 0; j < 4; j++)
      Y[(size_t)o * N_ + n0 + tx * 4 + j] = acc[i][j] + bz;
  }
}

// ---- row norms |qd|^2, |kd|^2 ---------------------------------------------
__global__ __launch_bounds__(256) void norms_kernel(const float* __restrict__ qd,
    const float* __restrict__ kd, float* __restrict__ qq, float* __restrict__ kk){
  int b = blockIdx.y, n0 = blockIdx.x * 64;
  int nn = threadIdx.x & 63, cg = threadIdx.x >> 6;
  float s1 = 0.f, s2 = 0.f;
  for (int c = cg; c < C_; c += 4){
    size_t idx = ((size_t)(b * C_ + c)) * N_ + n0 + nn;
    float a = qd[idx]; s1 += a * a;
    float d = kd[idx]; s2 += d * d;
  }
  __shared__ float r1[4][64], r2[4][64];
  r1[cg][nn] = s1; r2[cg][nn] = s2;
  __syncthreads();
  if (cg == 0){
    qq[b * N_ + n0 + nn] = r1[0][nn] + r1[1][nn] + r1[2][nn] + r1[3][nn];
    kk[b * N_ + n0 + nn] = r2[0][nn] + r2[1][nn] + r2[2][nn] + r2[3][nn];
  }
}

// ---- bf16 pack: z=0 q (scaled, B,H,N,HD) 1 k 2 v(B,C,N) 3 qd(B,N,C) 4 kd ---
__global__ __launch_bounds__(256) void pack_kernel(const float* __restrict__ wsf,
    __bf16* __restrict__ wsh){
  int arr = blockIdx.z, b = blockIdx.y;
  int n0 = (blockIdx.x & 31) * 64, c0 = (blockIdx.x >> 5) * 64;
  size_t srcoff = (arr == 0 ? OFF_Q : arr == 1 ? OFF_K : arr == 2 ? OFF_V :
                   arr == 3 ? OFF_QD : OFF_KD);
  const float* src = wsf + srcoff + (size_t)b * C_ * N_;
  __bf16* dst = wsh + (size_t)arr * SZf;
  int t = threadIdx.x;
  if (arr == 2){
    int nl4 = (t & 15) * 4, cl = t >> 4;
    #pragma unroll
    for (int i = 0; i < 4; i++){
      int c = c0 + cl + i * 16;
      float4 v = *reinterpret_cast<const float4*>(&src[(size_t)c * N_ + n0 + nl4]);
      alignas(8) __bf16 tmp[4] = {(__bf16)v.x, (__bf16)v.y, (__bf16)v.z, (__bf16)v.w};
      *reinterpret_cast<uint2*>(&dst[((size_t)(b * C_ + c)) * N_ + n0 + nl4]) =
          *reinterpret_cast<uint2*>(&tmp[0]);
    }
  } else {
    __shared__ float tile[64][65];
    int cl = t >> 6, nl = t & 63;
    #pragma unroll
    for (int i = 0; i < 16; i++)
      tile[i * 4 + cl][nl] = src[(size_t)(c0 + i * 4 + cl) * N_ + n0 + nl];
    __syncthreads();
    int nloc = t >> 2, cq = (t & 3) * 16;
    float scale = (arr == 0) ? 0.17677669529663687f : 1.0f;
    alignas(16) __bf16 tmp[16];
    #pragma unroll
    for (int j = 0; j < 16; j++) tmp[j] = (__bf16)(tile[cq + j][nloc] * scale);
    int n = n0 + nloc, c = c0 + cq;
    size_t didx;
    if (arr >= 3) didx = ((size_t)b * N_ + n) * C_ + c;
    else {
      int h = c >> 5, d = c & 31;
      didx = (((size_t)(b * H_ + h)) * N_ + n) * HD_ + d;
    }
    *reinterpret_cast<uint4*>(&dst[didx])     = *reinterpret_cast<uint4*>(&tmp[0]);
    *reinterpret_cast<uint4*>(&dst[didx + 8]) = *reinterpret_cast<uint4*>(&tmp[8]);
  }
}

// ---- similarity path, MFMA flash: block = (b,h, 64 rows); wave = 16 rows ----
__global__ __launch_bounds__(256) void sim_attn_mfma(
    const __bf16* __restrict__ qpk, const __bf16* __restrict__ kpk, const __bf16* __restrict__ vpk,
    const float* __restrict__ xyzA, const float* __restrict__ xyzB,
    const float* __restrict__ sbw1, const float* __restrict__ sbg, const float* __restrict__ sbb,
    const float* __restrict__ sbm, const float* __restrict__ sbv,
    const float* __restrict__ sbw2, const float* __restrict__ sbb2,
    float* __restrict__ ctxs){
  const int t = threadIdx.x, w = t >> 6, lane = t & 63, ln = lane & 15, g = lane >> 4;
  const int h = blockIdx.y, b = blockIdx.z;
  const int nbase = blockIdx.x * 64 + w * 16;
  const int n = nbase + ln;

  float Ac[4], Bc[4], W2h[4];
  #pragma unroll
  for (int j = 0; j < 4; j++){
    float rs = rsqrtf(sbv[j] + EPSf);
    Ac[j]  = rfl(-sbw1[j] * rs * sbg[j]);
    Bc[j]  = rfl(-sbm[j] * rs * sbg[j] + sbb[j]);
    W2h[j] = rfl(sbw2[h * 4 + j]);
  }
  float C0 = rfl(sbb2[h]);

  bf16x8 qf = *reinterpret_cast<const bf16x8*>(
      &qpk[(((size_t)(b * H_ + h)) * N_ + n) * HD_ + g * 8]);
  float ax = xyzA[((size_t)(b * N_ + n)) * 3 + 0];
  float ay = xyzA[((size_t)(b * N_ + n)) * 3 + 1];
  float az = xyzA[((size_t)(b * N_ + n)) * 3 + 2];

  f32x4 oacc[2];
  #pragma unroll
  for (int i = 0; i < 2; i++) oacc[i] = (f32x4){0.f, 0.f, 0.f, 0.f};
  float mrun = -1e30f, lrun = 0.f;

  __shared__ __align__(16) float ss[4][16][68];
  __shared__ float4 xbb[4][64];

  for (int m0 = 0; m0 < N_; m0 += 64){
    {
      const float* xp = &xyzB[((size_t)(b * N_ + m0 + lane)) * 3];
      xbb[w][lane] = make_float4(xp[0], xp[1], xp[2], 0.f);
    }
    f32x4 sacc[4];
    #pragma unroll
    for (int i = 0; i < 4; i++) sacc[i] = (f32x4){0.f, 0.f, 0.f, 0.f};
    #pragma unroll
    for (int mt = 0; mt < 4; mt++){
      bf16x8 kf = *reinterpret_cast<const bf16x8*>(
          &kpk[(((size_t)(b * H_ + h)) * N_ + m0 + mt * 16 + ln) * HD_ + g * 8]);
      sacc[mt] = __builtin_amdgcn_mfma_f32_16x16x32_bf16(qf, kf, sacc[mt], 0, 0, 0);
    }
    #pragma unroll
    for (int mt = 0; mt < 4; mt++)
      #pragma unroll
      for (int r = 0; r < 4; r++)
        ss[w][g * 4 + r][mt * 16 + ln] = sacc[mt][r];
    __syncthreads();

    #pragma unroll
    for (int kh = 0; kh < 2; kh++){
      float s8[8];
      {
        float4 sa = *reinterpret_cast<const float4*>(&ss[w][ln][kh * 32 + g * 8]);
        float4 sb = *reinterpret_cast<const float4*>(&ss[w][ln][kh * 32 + g * 8 + 4]);
        s8[0]=sa.x; s8[1]=sa.y; s8[2]=sa.z; s8[3]=sa.w;
        s8[4]=sb.x; s8[5]=sb.y; s8[6]=sb.z; s8[7]=sb.w;
      }
      float mx = -1e30f;
      #pragma unroll
      for (int j = 0; j < 8; j++){
        float4 xk = xbb[w][kh * 32 + g * 8 + j];
        float dx = ax - xk.x, dy = ay - xk.y, dz = az - xk.z;
        float sd = sqrtf(dx * dx + dy * dy + dz * dz);
        float bias = C0;
        #pragma unroll
        for (int u = 0; u < 4; u++)
          bias += W2h[u] * fmaxf(fmaf(Ac[u], sd, Bc[u]), 0.f);
        s8[j] += bias;
        mx = fmaxf(mx, s8[j]);
      }
      mx = fmaxf(mx, __shfl_xor(mx, 16));
      mx = fmaxf(mx, __shfl_xor(mx, 32));
      float nm = fmaxf(mrun, mx);
      float al = __expf(mrun - nm);
      float ps = 0.f;
      bf16x8 pf;
      #pragma unroll
      for (int j = 0; j < 8; j++){
        float pv = __expf(s8[j] - nm);
        ps += pv;
        pf[j] = (__bf16)pv;
      }
      ps += __shfl_xor(ps, 16);
      ps += __shfl_xor(ps, 32);
      lrun = lrun * al + ps; mrun = nm;
      oacc[0] *= al; oacc[1] *= al;
      #pragma unroll
      for (int dt = 0; dt < 2; dt++){
        bf16x8 vf = *reinterpret_cast<const bf16x8*>(
            &vpk[((size_t)(b * C_ + h * HD_ + dt * 16 + ln)) * N_ + m0 + kh * 32 + g * 8]);
        oacc[dt] = __builtin_amdgcn_mfma_f32_16x16x32_bf16(vf, pf, oacc[dt], 0, 0, 0);
      }
    }
    __syncthreads();
  }
  float invl = 1.f / lrun;
  #pragma unroll
  for (int dt = 0; dt < 2; dt++)
    #pragma unroll
    for (int r = 0; r < 4; r++)
      ctxs[((size_t)(b * C_ + h * HD_ + dt * 16 + g * 4 + r)) * N_ + nbase + ln] =
          oacc[dt][r] * invl;
}

// ---- dissimilarity path, MFMA flash: block = (b, 16 rows); 4 waves m-split --
__global__ __launch_bounds__(256) void dis_attn_mfma(
    const __bf16* __restrict__ qdpk, const __bf16* __restrict__ kdpk, const __bf16* __restrict__ vpk,
    const float* __restrict__ qq, const float* __restrict__ kkn,
    const float* __restrict__ xyzA, const float* __restrict__ xyzB,
    const float* __restrict__ sbw1, const float* __restrict__ sbg, const float* __restrict__ sbb,
    const float* __restrict__ sbm, const float* __restrict__ sbv,
    const float* __restrict__ sbw2, const float* __restrict__ sbb2,
    float* __restrict__ ctxd){
  const int t = threadIdx.x, w = t >> 6, lane = t & 63, ln = lane & 15, g = lane >> 4;
  const int n0 = blockIdx.x * 16, b = blockIdx.y;
  const int n = n0 + ln;

  float Ac[4], Bc[4];
  #pragma unroll
  for (int j = 0; j < 4; j++){
    float rs = rsqrtf(sbv[j] + EPSf);
    Ac[j] = rfl(-sbw1[j] * rs * sbg[j]);
    Bc[j] = rfl(-sbm[j] * rs * sbg[j] + sbb[j]);
  }
  float W2[8][4], C0[8];
  #pragma unroll
  for (int hh = 0; hh < 8; hh++){
    #pragma unroll
    for (int j = 0; j < 4; j++) W2[hh][j] = rfl(sbw2[hh * 4 + j]);
    C0[hh] = rfl(sbb2[hh]);
  }

  bf16x8 qf[8];
  #pragma unroll
  for (int ks = 0; ks < 8; ks++)
    qf[ks] = *reinterpret_cast<const bf16x8*>(
        &qdpk[((size_t)b * N_ + n) * C_ + ks * 32 + g * 8]);
  float qqn = qq[b * N_ + n];
  float ax = xyzA[((size_t)(b * N_ + n)) * 3 + 0];
  float ay = xyzA[((size_t)(b * N_ + n)) * 3 + 1];
  float az = xyzA[((size_t)(b * N_ + n)) * 3 + 2];

  f32x4 oacc[16];
  #pragma unroll
  for (int i = 0; i < 16; i++) oacc[i] = (f32x4){0.f, 0.f, 0.f, 0.f};
  float mh[8], lh[8];
  #pragma unroll
  for (int i = 0; i < 8; i++){ mh[i] = -1e30f; lh[i] = 0.f; }

  __shared__ __align__(16) float ss[4][16][68];
  __shared__ float4 xbb[4][64];
  __shared__ float mst[4][8][16], lst[4][8][16];
  __shared__ float obuf[256][18];

  for (int it = 0; it < 8; ++it){
    int m0 = w * 512 + it * 64;
    {
      const float* xp = &xyzB[((size_t)(b * N_ + m0 + lane)) * 3];
      xbb[w][lane] = make_float4(xp[0], xp[1], xp[2], kkn[b * N_ + m0 + lane]);
    }
    f32x4 gacc[4];
    #pragma unroll
    for (int i = 0; i < 4; i++) gacc[i] = (f32x4){0.f, 0.f, 0.f, 0.f};
    #pragma unroll
    for (int ks = 0; ks < 8; ks++){
      #pragma unroll
      for (int mt = 0; mt < 4; mt++){
        bf16x8 kf = *reinterpret_cast<const bf16x8*>(
            &kdpk[((size_t)b * N_ + m0 + mt * 16 + ln) * C_ + ks * 32 + g * 8]);
        gacc[mt] = __builtin_amdgcn_mfma_f32_16x16x32_bf16(qf[ks], kf, gacc[mt], 0, 0, 0);
      }
    }
    #pragma unroll
    for (int mt = 0; mt < 4; mt++)
      #pragma unroll
      for (int r = 0; r < 4; r++)
        ss[w][g * 4 + r][mt * 16 + ln] = gacc[mt][r];
    __syncthreads();

    #pragma unroll
    for (int kh = 0; kh < 2; kh++){
      float fd[8], u0[8], u1[8], u2[8], u3[8];
      {
        float4 sa = *reinterpret_cast<const float4*>(&ss[w][ln][kh * 32 + g * 8]);
        float4 sb = *reinterpret_cast<const float4*>(&ss[w][ln][kh * 32 + g * 8 + 4]);
        float gdot[8] = {sa.x, sa.y, sa.z, sa.w, sb.x, sb.y, sb.z, sb.w};
        #pragma unroll
        for (int j = 0; j < 8; j++){
          float4 xk = xbb[w][kh * 32 + g * 8 + j];
          float d2 = qqn + xk.w - 2.f * gdot[j];
          fd[j] = sqrtf(fmaxf(d2, 0.f));
          float dx = ax - xk.x, dy = ay - xk.y, dz = az - xk.z;
          float sd = sqrtf(dx * dx + dy * dy + dz * dz);
          u0[j] = fmaxf(fmaf(Ac[0], sd, Bc[0]), 0.f);
          u1[j] = fmaxf(fmaf(Ac[1], sd, Bc[1]), 0.f);
          u2[j] = fmaxf(fmaf(Ac[2], sd, Bc[2]), 0.f);
          u3[j] = fmaxf(fmaf(Ac[3], sd, Bc[3]), 0.f);
        }
      }
      #pragma unroll
      for (int hh = 0; hh < 8; hh++){
        float mx = -1e30f, s8h[8];
        #pragma unroll
        for (int j = 0; j < 8; j++){
          s8h[j] = fd[j] + C0[hh] + W2[hh][0] * u0[j] + W2[hh][1] * u1[j]
                 + W2[hh][2] * u2[j] + W2[hh][3] * u3[j];
          mx = fmaxf(mx, s8h[j]);
        }
        mx = fmaxf(mx, __shfl_xor(mx, 16));
        mx = fmaxf(mx, __shfl_xor(mx, 32));
        float nm = fmaxf(mh[hh], mx);
        float al = __expf(mh[hh] - nm);
        float ps = 0.f;
        bf16x8 pf;
        #pragma unroll
        for (int j = 0; j < 8; j++){
          float pv = __expf(s8h[j] - nm);
          ps += pv;
          pf[j] = (__bf16)pv;
        }
        ps += __shfl_xor(ps, 16);
        ps += __shfl_xor(ps, 32);
        lh[hh] = lh[hh] * al + ps; mh[hh] = nm;
        oacc[2 * hh] *= al; oacc[2 * hh + 1] *= al;
        #pragma unroll
        for (int dt = 0; dt < 2; dt++){
          bf16x8 vf = *reinterpret_cast<const bf16x8*>(
              &vpk[((size_t)(b * C_ + hh * HD_ + dt * 16 + ln)) * N_ + m0 + kh * 32 + g * 8]);
          oacc[2 * hh + dt] = __builtin_amdgcn_mfma_f32_16x16x32_bf16(vf, pf, oacc[2 * hh + dt], 0, 0, 0);
        }
      }
    }
    __syncthreads();
  }

  // cross-wave flash combine
  if (lane < 16){
    #pragma unroll
    for (int hh = 0; hh < 8; hh++){ mst[w][hh][lane] = mh[hh]; lst[w][hh][lane] = lh[hh]; }
  }
  __syncthreads();
  float scl[8], Lf[8];
  #pragma unroll
  for (int hh = 0; hh < 8; hh++){
    float M = fmaxf(fmaxf(mst[0][hh][ln], mst[1][hh][ln]),
                    fmaxf(mst[2][hh][ln], mst[3][hh][ln]));
    float L = lst[0][hh][ln] * __expf(mst[0][hh][ln] - M)
            + lst[1][hh][ln] * __expf(mst[1][hh][ln] - M)
            + lst[2][hh][ln] * __expf(mst[2][hh][ln] - M)
            + lst[3][hh][ln] * __expf(mst[3][hh][ln] - M);
    Lf[hh] = L;
    scl[hh] = __expf(mh[hh] - M);
  }
  #pragma unroll
  for (int hh = 0; hh < 8; hh++){ oacc[2 * hh] *= scl[hh]; oacc[2 * hh + 1] *= scl[hh]; }
  for (int ph = 0; ph < 4; ph++){
    if (w == ph){
      #pragma unroll
      for (int tl = 0; tl < 16; tl++)
        #pragma unroll
        for (int r = 0; r < 4; r++){
          int c = tl * 16 + g * 4 + r;
          if (ph == 0) obuf[c][ln] = oacc[tl][r];
          else         obuf[c][ln] += oacc[tl][r];
        }
    }
    __syncthreads();
  }
  #pragma unroll
  for (int tt = 0; tt < 4; tt++){
    int tl = w * 4 + tt;
    float invl = 1.f / Lf[tl >> 1];
    #pragma unroll
    for (int r = 0; r < 4; r++){
      int c = tl * 16 + g * 4 + r;
      ctxd[((size_t)(b * C_ + c)) * N_ + n0 + ln] = obuf[c][ln] * invl;
    }
  }
}

// ================= legacy scalar attention kernels (ws-size fallback) =======
__global__ __launch_bounds__(256) void sim_attn(
    const float* __restrict__ qbuf, const float* __restrict__ kbuf, const float* __restrict__ vbuf,
    const float* __restrict__ xyzA, const float* __restrict__ xyzB,
    const float* __restrict__ sbw1, const float* __restrict__ sbg, const float* __restrict__ sbb,
    const float* __restrict__ sbm, const float* __restrict__ sbv,
    const float* __restrict__ sbw2, const float* __restrict__ sbb2,
    float* __restrict__ ctxs){
  int n0 = blockIdx.x * 32, h = blockIdx.y, b = blockIdx.z;
  int t = threadIdx.x;
  __shared__ float ks[64][33];
  __shared__ float vs[64][36];
  __shared__ float ssx[32][65];
  __shared__ float xa[32][3], xb[64][3];
  __shared__ float mrun[32], lrun[32], alps[32];
  __shared__ float Acf[4], Bcf[4], W2h[4];
  __shared__ float C0s;

  if (t < 4){
    float rs = rsqrtf(sbv[t] + EPSf);
    Acf[t] = -sbw1[t] * rs * sbg[t];
    Bcf[t] = -sbm[t] * rs * sbg[t] + sbb[t];
    W2h[t] = sbw2[h * 4 + t];
  }
  if (t == 0) C0s = sbb2[h];
  if (t < 32){
    mrun[t] = -1e30f; lrun[t] = 0.f;
    xa[t][0] = xyzA[((size_t)(b * N_ + n0 + t)) * 3 + 0];
    xa[t][1] = xyzA[((size_t)(b * N_ + n0 + t)) * 3 + 1];
    xa[t][2] = xyzA[((size_t)(b * N_ + n0 + t)) * 3 + 2];
  }
  float qreg[32];
  {
    int r = t & 31;
    const float inv = 0.17677669529663687f;
    #pragma unroll
    for (int d = 0; d < 32; d++)
      qreg[d] = qbuf[((size_t)(b * C_ + h * HD_ + d)) * N_ + n0 + r] * inv;
  }
  float acc0 = 0.f, acc1 = 0.f, acc2 = 0.f, acc3 = 0.f;
  __syncthreads();

  for (int m0 = 0; m0 < N_; m0 += 64){
    {
      int m = t & 63, dg = t >> 6;
      #pragma unroll
      for (int i = 0; i < 8; i++){
        int d = dg + 4 * i;
        size_t gi = ((size_t)(b * C_ + h * HD_ + d)) * N_ + m0 + m;
        ks[m][d] = kbuf[gi];
        vs[m][d] = vbuf[gi];
      }
      if (t < 64){
        xb[t][0] = xyzB[((size_t)(b * N_ + m0 + t)) * 3 + 0];
        xb[t][1] = xyzB[((size_t)(b * N_ + m0 + t)) * 3 + 1];
        xb[t][2] = xyzB[((size_t)(b * N_ + m0 + t)) * 3 + 2];
      }
    }
    __syncthreads();
    {
      int r = t & 31, mg = t >> 5;
      float axx = xa[r][0], ayy = xa[r][1], azz = xa[r][2];
      #pragma unroll
      for (int mi = 0; mi < 8; mi++){
        int m = mg * 8 + mi;
        float dot = 0.f;
        #pragma unroll
        for (int d = 0; d < 32; d++) dot += qreg[d] * ks[m][d];
        float dx = axx - xb[m][0], dy = ayy - xb[m][1], dz = azz - xb[m][2];
        float dist = sqrtf(dx * dx + dy * dy + dz * dz);
        float sb = C0s;
        #pragma unroll
        for (int j = 0; j < 4; j++)
          sb += W2h[j] * fmaxf(fmaf(Acf[j], dist, Bcf[j]), 0.f);
        ssx[r][m] = dot + sb;
      }
    }
    __syncthreads();
    {
      int r = t >> 3, sub = t & 7;
      float v8[8];
      float mx = -1e30f;
      #pragma unroll
      for (int i = 0; i < 8; i++){ v8[i] = ssx[r][sub * 8 + i]; mx = fmaxf(mx, v8[i]); }
      #pragma unroll
      for (int off = 1; off < 8; off <<= 1) mx = fmaxf(mx, __shfl_xor(mx, off));
      float newm = fmaxf(mrun[r], mx);
      float al = __expf(mrun[r] - newm);
      float psum = 0.f;
      #pragma unroll
      for (int i = 0; i < 8; i++){
        float pv = __expf(v8[i] - newm);
        ssx[r][sub * 8 + i] = pv;
        psum += pv;
      }
      #pragma unroll
      for (int off = 1; off < 8; off <<= 1) psum += __shfl_xor(psum, off);
      if (sub == 0){
        lrun[r] = lrun[r] * al + psum;
        mrun[r] = newm;
        alps[r] = al;
      }
    }
    __syncthreads();
    {
      int r = t >> 3, dc = (t & 7) * 4;
      float al = alps[r];
      acc0 *= al; acc1 *= al; acc2 *= al; acc3 *= al;
      for (int m = 0; m < 64; m++){
        float pv = ssx[r][m];
        const float4 v4 = *reinterpret_cast<const float4*>(&vs[m][dc]);
        acc0 += pv * v4.x; acc1 += pv * v4.y; acc2 += pv * v4.z; acc3 += pv * v4.w;
      }
    }
    __syncthreads();
  }
  {
    int r = t >> 3, dc = (t & 7) * 4;
    float invl = 1.f / lrun[r];
    size_t base = ((size_t)(b * C_ + h * HD_ + dc)) * N_ + n0 + r;
    ctxs[base]          = acc0 * invl;
    ctxs[base + N_]     = acc1 * invl;
    ctxs[base + 2 * N_] = acc2 * invl;
    ctxs[base + 3 * N_] = acc3 * invl;
  }
}

#define CI(c) ((c) + ((c) >> 4))
__global__ __launch_bounds__(256) void dis_attn(
    const float* __restrict__ qdbuf, const float* __restrict__ kdbuf, const float* __restrict__ vbuf,
    const float* __restrict__ qq, const float* __restrict__ kkn,
    const float* __restrict__ xyzA, const float* __restrict__ xyzB,
    const float* __restrict__ sbw1, const float* __restrict__ sbg, const float* __restrict__ sbb,
    const float* __restrict__ sbm, const float* __restrict__ sbv,
    const float* __restrict__ sbw2, const float* __restrict__ sbb2,
    float* __restrict__ ctxd){
  int n0 = blockIdx.x * 16, b = blockIdx.y;
  int t = threadIdx.x;
  __shared__ float qds[16][271];
  __shared__ float kds[16][271];
  __shared__ float vs2[16][260];
  __shared__ float sd[16][8][17];
  __shared__ float xa[16][3], xb[16][3], qqs[16], kks[16];
  __shared__ float mrun[16][8], lrun[16][8], alph[16][8];
  __shared__ float Acf[4], Bcf[4], W2[8][4], C0s[8];

  if (t < 4){
    float rs = rsqrtf(sbv[t] + EPSf);
    Acf[t] = -sbw1[t] * rs * sbg[t];
    Bcf[t] = -sbm[t] * rs * sbg[t] + sbb[t];
  }
  if (t < 32) W2[t >> 2][t & 3] = sbw2[t];
  if (t < 8)  C0s[t] = sbb2[t];
  {
    int r = t & 15, cg = t >> 4;
    #pragma unroll
    for (int i = 0; i < 16; i++){
      int c = i * 16 + cg;
      qds[r][CI(c)] = qdbuf[((size_t)(b * C_ + c)) * N_ + n0 + r];
    }
  }
  if (t < 16){
    qqs[t] = qq[b * N_ + n0 + t];
    xa[t][0] = xyzA[((size_t)(b * N_ + n0 + t)) * 3 + 0];
    xa[t][1] = xyzA[((size_t)(b * N_ + n0 + t)) * 3 + 1];
    xa[t][2] = xyzA[((size_t)(b * N_ + n0 + t)) * 3 + 2];
  }
  if (t < 128){ mrun[t >> 3][t & 7] = -1e30f; lrun[t >> 3][t & 7] = 0.f; }
  float acc[4][4];
  #pragma unroll
  for (int i = 0; i < 4; i++)
    #pragma unroll
    for (int j = 0; j < 4; j++) acc[i][j] = 0.f;
  __syncthreads();

  for (int m0 = 0; m0 < N_; m0 += 16){
    {
      int m = t & 15, cg = t >> 4;
      #pragma unroll
      for (int i = 0; i < 16; i++){
        int c = i * 16 + cg;
        size_t gi = ((size_t)(b * C_ + c)) * N_ + m0 + m;
        kds[m][CI(c)] = kdbuf[gi];
        vs2[m][c] = vbuf[gi];
      }
      if (t < 16){
        kks[t] = kkn[b * N_ + m0 + t];
        xb[t][0] = xyzB[((size_t)(b * N_ + m0 + t)) * 3 + 0];
        xb[t][1] = xyzB[((size_t)(b * N_ + m0 + t)) * 3 + 1];
        xb[t][2] = xyzB[((size_t)(b * N_ + m0 + t)) * 3 + 2];
      }
    }
    __syncthreads();
    {
      int r = t >> 4, m = t & 15;
      float a0 = 0.f, a1 = 0.f, a2 = 0.f, a3 = 0.f;
      for (int c = 0; c < C_; c += 4){
        int ci = c + (c >> 4);
        a0 += qds[r][ci    ] * kds[m][ci    ];
        a1 += qds[r][ci + 1] * kds[m][ci + 1];
        a2 += qds[r][ci + 2] * kds[m][ci + 2];
        a3 += qds[r][ci + 3] * kds[m][ci + 3];
      }
      float dot = (a0 + a1) + (a2 + a3);
      float d2 = qqs[r] + kks[m] - 2.f * dot;
      float fdist = sqrtf(fmaxf(d2, 0.f));
      float dx = xa[r][0] - xb[m][0], dy = xa[r][1] - xb[m][1], dz = xa[r][2] - xb[m][2];
      float sdist = sqrtf(dx * dx + dy * dy + dz * dz);
      float uu0 = fmaxf(fmaf(Acf[0], sdist, Bcf[0]), 0.f);
      float uu1 = fmaxf(fmaf(Acf[1], sdist, Bcf[1]), 0.f);
      float uu2 = fmaxf(fmaf(Acf[2], sdist, Bcf[2]), 0.f);
      float uu3 = fmaxf(fmaf(Acf[3], sdist, Bcf[3]), 0.f);
      #pragma unroll
      for (int hh = 0; hh < 8; hh++){
        float sb = C0s[hh] + W2[hh][0] * uu0 + W2[hh][1] * uu1 + W2[hh][2] * uu2 + W2[hh][3] * uu3;
        sd[r][hh][m] = fdist + sb;
      }
    }
    __syncthreads();
    if (t < 128){
      int r = t >> 3, hh = t & 7;
      float mx = -1e30f;
      #pragma unroll
      for (int m = 0; m < 16; m++) mx = fmaxf(mx, sd[r][hh][m]);
      float newm = fmaxf(mrun[r][hh], mx);
      float al = __expf(mrun[r][hh] - newm);
      float s = 0.f;
      #pragma unroll
      for (int m = 0; m < 16; m++){
        float pv = __expf(sd[r][hh][m] - newm);
        sd[r][hh][m] = pv;
        s += pv;
      }
      lrun[r][hh] = lrun[r][hh] * al + s;
      mrun[r][hh] = newm;
      alph[r][hh] = al;
    }
    __syncthreads();
    {
      int rg = t >> 6, cq = t & 63, hh = cq >> 3;
      float al0 = alph[rg * 4 + 0][hh], al1 = alph[rg * 4 + 1][hh];
      float al2 = alph[rg * 4 + 2][hh], al3 = alph[rg * 4 + 3][hh];
      #pragma unroll
      for (int j = 0; j < 4; j++){
        acc[0][j] *= al0; acc[1][j] *= al1; acc[2][j] *= al2; acc[3][j] *= al3;
      }
      for (int m = 0; m < 16; m++){
        const float4 v4 = *reinterpret_cast<const float4*>(&vs2[m][cq * 4]);
        float p0 = sd[rg * 4 + 0][hh][m], p1 = sd[rg * 4 + 1][hh][m];
        float p2 = sd[rg * 4 + 2][hh][m], p3 = sd[rg * 4 + 3][hh][m];
        acc[0][0] += p0 * v4.x; acc[0][1] += p0 * v4.y; acc[0][2] += p0 * v4.z; acc[0][3] += p0 * v4.w;
        acc[1][0] += p1 * v4.x; acc[1][1] += p1 * v4.y; acc[1][2] += p1 * v4.z; acc[1][3] += p1 * v4.w;
        acc[2][0] += p2 * v4.x; acc[2][1] += p2 * v4.y; acc[2][2] += p2 * v4.z; acc[2][3] += p2 * v4.w;
        acc[3][0] += p3 * v4.x; acc[3][1] += p3 * v4.y; acc[3][2] += p3 * v4.z; acc[3][3] += p3 * v4.w;
      }
    }
    __syncthreads();
  }
  {
    int rg = t >> 6, cq = t & 63, hh = cq >> 3;
    #pragma unroll
    for (int i = 0; i < 4; i++){
      float invl = 1.f / lrun[rg * 4 + i][hh];
      #pragma unroll
      for (int j = 0; j < 4; j++)
        ctxd[((size_t)(b * C_ + cq * 4 + j)) * N_ + n0 + rg * 4 + i] = acc[i][j] * invl;
    }
  }
}

// ---- fusion MLP stage 1 -----------------------------------------------------
__global__ __launch_bounds__(256) void fusion1_kernel(float* __restrict__ ws,
    const float* __restrict__ fw1, const float* __restrict__ fbg, const float* __restrict__ fbb,
    const float* __restrict__ fbm, const float* __restrict__ fbv){
  int b = blockIdx.z;
  const float* seg0 = ws + OFF_FAN  + (size_t)b * C_ * N_;
  const float* seg1 = ws + OFF_CTXS + (size_t)b * C_ * N_;
  const float* seg2 = ws + OFF_CTXD + (size_t)b * C_ * N_;
  float* Y = ws + OFF_X1 + (size_t)b * 2 * C_ * N_;
  __shared__ float As[16][65], Bs[16][65];
  int t = threadIdx.x, tx = t & 15, ty = t >> 4;
  int o0 = blockIdx.y * 64, n0 = blockIdx.x * 64;
  float acc[4][4] = {};
  for (int k0 = 0; k0 < 3 * C_; k0 += 16){
    int kkl = t & 15, ob = t >> 4;
    #pragma unroll
    for (int i = 0; i < 4; i++)
      As[kkl][ob + 16 * i] = fw1[(size_t)(o0 + ob + 16 * i) * (3 * C_) + k0 + kkl];
    int nn = t & 63, kb4 = t >> 6;
    #pragma unroll
    for (int i = 0; i < 4; i++){
      int c = k0 + kb4 + 4 * i;
      const float* base = (c < C_) ? seg0 : (c < 2 * C_ ? seg1 : seg2);
      Bs[kb4 + 4 * i][nn] = base[(size_t)(c & (C_ - 1)) * N_ + n0 + nn];
    }
    __syncthreads();
    #pragma unroll
    for (int kk2 = 0; kk2 < 16; kk2++){
      float a[4], bb[4];
      #pragma unroll
      for (int i = 0; i < 4; i++) a[i] = As[kk2][ty * 4 + i];
      #pragma unroll
      for (int j = 0; j < 4; j++) bb[j] = Bs[kk2][tx * 4 + j];
      #pragma unroll
      for (int i = 0; i < 4; i++)
        #pragma unroll
        for (int j = 0; j < 4; j++)
          acc[i][j] += a[i] * bb[j];
    }
    __syncthreads();
  }
  #pragma unroll
  for (int i = 0; i < 4; i++){
    int o = o0 + ty * 4 + i;
    float mn = fbm[o], rs = rsqrtf(fbv[o] + EPSf), gg = fbg[o], be = fbb[o];
    #pragma unroll
    for (int j = 0; j < 4; j++){
      float x = (acc[i][j] - mn) * rs * gg + be;
      Y[(size_t)o * N_ + n0 + tx * 4 + j] = fmaxf(x, 0.f);
    }
  }
}

// ---- fusion MLP stage 2 -----------------------------------------------------
__global__ __launch_bounds__(256) void fusion2_kernel(const float* __restrict__ ws,
    const float* __restrict__ fw2, const float* __restrict__ fb2,
    const float* __restrict__ featA, float* __restrict__ out){
  int b = blockIdx.z;
  const float* X = ws + OFF_X1 + (size_t)b * 2 * C_ * N_;
  __shared__ float As[16][65], Bs[16][65];
  int t = threadIdx.x, tx = t & 15, ty = t >> 4;
  int o0 = blockIdx.y * 64, n0 = blockIdx.x * 64;
  float acc[4][4] = {};
  for (int k0 = 0; k0 < 2 * C_; k0 += 16){
    int kkl = t & 15, ob = t >> 4;
    #pragma unroll
    for (int i = 0; i < 4; i++)
      As[kkl][ob + 16 * i] = fw2[(size_t)(o0 + ob + 16 * i) * (2 * C_) + k0 + kkl];
    int nn = t & 63, kb4 = t >> 6;
    #pragma unroll
    for (int i = 0; i < 4; i++)
      Bs[kb4 + 4 * i][nn] = X[(size_t)(k0 + kb4 + 4 * i) * N_ + n0 + nn];
    __syncthreads();
    #pragma unroll
    for (int kk2 = 0; kk2 < 16; kk2++){
      float a[4], bb[4];
      #pragma unroll
      for (int i = 0; i < 4; i++) a[i] = As[kk2][ty * 4 + i];
      #pragma unroll
      for (int j = 0; j < 4; j++) bb[j] = Bs[kk2][tx * 4 + j];
      #pragma unroll
      for (int i = 0; i < 4; i++)
        #pragma unroll
        for (int j = 0; j < 4; j++)
          acc[i][j] += a[i] * bb[j];
    }
    __syncthreads();
  }
  #pragma unroll
  for (int i = 0; i < 4; i++){
    int o = o0 + ty * 4 + i;
    float bz = fb2[o];
    #pragma unroll
    for (int j = 0; j < 4; j++){
      size_t oi = ((size_t)(b * C_ + o)) * N_ + n0 + tx * 4 + j;
      out[oi] = acc[i][j] + bz + featA[oi];
    }
  }
}

extern "C" void kernel_launch(void* const* d_in, const int* in_sizes, int n_in,
                              void* d_out, int out_size, void* d_ws, size_t ws_size,
                              hipStream_t stream){
  (void)in_sizes; (void)n_in; (void)out_size;
  if (ws_size < WS_FLOATS * sizeof(float)) return;

  const float* xyzA  = (const float*)d_in[0];
  const float* featA = (const float*)d_in[1];
  const float* xyzB  = (const float*)d_in[2];
  const float* featB = (const float*)d_in[3];
  const float* qw  = (const float*)d_in[4];   const float* qb  = (const float*)d_in[5];
  const float* kw  = (const float*)d_in[6];   const float* kb  = (const float*)d_in[7];
  const float* vw  = (const float*)d_in[8];   const float* vb  = (const float*)d_in[9];
  const float* sbw1= (const float*)d_in[10];  const float* sbg = (const float*)d_in[11];
  const float* sbb = (const float*)d_in[12];  const float* sbm = (const float*)d_in[13];
  const float* sbv = (const float*)d_in[14];  const float* sbw2= (const float*)d_in[15];
  const float* sbb2= (const float*)d_in[16];
  const float* qdw = (const float*)d_in[17];  const float* qdb = (const float*)d_in[18];
  const float* kdw = (const float*)d_in[19];  const float* kdb = (const float*)d_in[20];
  const float* ling= (const float*)d_in[21];  const float* linb= (const float*)d_in[22];
  const float* lsg = (const float*)d_in[23];  const float* lsb = (const float*)d_in[24];
  const float* ldg = (const float*)d_in[25];  const float* ldb = (const float*)d_in[26];
  const float* fw1 = (const float*)d_in[27];  const float* fbg = (const float*)d_in[28];
  const float* fbb = (const float*)d_in[29];  const float* fbm = (const float*)d_in[30];
  const float* fbv = (const float*)d_in[31];  const float* fw2 = (const float*)d_in[32];
  const float* fb2 = (const float*)d_in[33];
  float* ws = (float*)d_ws;
  float* out = (float*)d_out;
  bool use_mfma = (ws_size >= WS_BYTES_NEW);
  __bf16* wsh = (__bf16*)(ws + WS_FLOATS);

  ln_kernel<<<B_ * N_, 256, 0, stream>>>(featA, ws + OFF_FAN, ling, linb);
  proj_kernel<<<dim3(N_ / 64, C_ / 64, 5 * B_), 256, 0, stream>>>(
      ws, featB, qw, qb, kw, kb, vw, vb, qdw, qdb, kdw, kdb);
  norms_kernel<<<dim3(N_ / 64, B_), 256, 0, stream>>>(
      ws + OFF_QD, ws + OFF_KD, ws + OFF_QQ, ws + OFF_KK);
  if (use_mfma){
    pack_kernel<<<dim3(128, B_, 5), 256, 0, stream>>>(ws, wsh);
    sim_attn_mfma<<<dim3(N_ / 64, H_, B_), 256, 0, stream>>>(
        wsh + PK_Q, wsh + PK_K, wsh + PK_V, xyzA, xyzB,
        sbw1, sbg, sbb, sbm, sbv, sbw2, sbb2, ws + OFF_CTXS);
    dis_attn_mfma<<<dim3(N_ / 16, B_), 256, 0, stream>>>(
        wsh + PK_QD, wsh + PK_KD, wsh + PK_V, ws + OFF_QQ, ws + OFF_KK,
        xyzA, xyzB, sbw1, sbg, sbb, sbm, sbv, sbw2, sbb2, ws + OFF_CTXD);
  } else {
    sim_attn<<<dim3(N_ / 32, H_, B_), 256, 0, stream>>>(
        ws + OFF_Q, ws + OFF_K, ws + OFF_V, xyzA, xyzB,
        sbw1, sbg, sbb, sbm, sbv, sbw2, sbb2, ws + OFF_CTXS);
    dis_attn<<<dim3(N_ / 16, B_), 256, 0, stream>>>(
        ws + OFF_QD, ws + OFF_KD, ws + OFF_V, ws + OFF_QQ, ws + OFF_KK,
        xyzA, xyzB, sbw1, sbg, sbb, sbm, sbv, sbw2, sbb2, ws + OFF_CTXD);
  }
  ln_kernel<<<B_ * N_, 256, 0, stream>>>(ws + OFF_CTXS, ws + OFF_CTXS, lsg, lsb);
  ln_kernel<<<B_ * N_, 256, 0, stream>>>(ws + OFF_CTXD, ws + OFF_CTXD, ldg, ldb);
  fusion1_kernel<<<dim3(N_ / 64, (2 * C_) / 64, B_), 256, 0, stream>>>(
      ws, fw1, fbg, fbb, fbm, fbv);
  fusion2_kernel<<<dim3(N_ / 64, C_ / 64, B_), 256, 0, stream>>>(
      ws, fw2, fb2, featA, out);
}

// Round 3
// 317.400 us; speedup vs baseline: 3.6439x; 1.7719x over previous
//
#include <hip/hip_runtime.h>

#define B_ 2
#define N_ 2048
#define C_ 256
#define H_ 8
#define HD_ 32
#define EPSf 1e-5f

typedef __bf16   bf16x8 __attribute__((ext_vector_type(8)));
typedef float    f32x4  __attribute__((ext_vector_type(4)));
typedef _Float16 f16x8  __attribute__((ext_vector_type(8)));

// ---- workspace layout (byte offsets) ---------------------------------------
static constexpr size_t MB_ = 1024 * 1024;
static constexpr size_t OFF_FANT = 0;                    // bf16 (B,N,C)   2MB  featA_norm^T
static constexpr size_t OFF_FBT  = 2 * MB_;              // bf16 (B,N,C)   2MB  featB^T
static constexpr size_t OFF_QPK  = 4 * MB_;              // bf16 (B,H,N,HD) 2MB (q*1/sqrt(hd))
static constexpr size_t OFF_KPK  = 6 * MB_;              // bf16 (B,H,N,HD) 2MB
static constexpr size_t OFF_VPK  = 8 * MB_;              // bf16 (B,C,N)   2MB
static constexpr size_t OFF_QDT  = 10 * MB_;             // bf16 (B,N,C)   2MB
static constexpr size_t OFF_KDT  = 12 * MB_;             // bf16 (B,N,C)   2MB
static constexpr size_t OFF_QQ   = 14 * MB_;             // f32 (B,N)     16KB
static constexpr size_t OFF_KK   = 14 * MB_ + 16 * 1024; // f32 (B,N)     16KB
static constexpr size_t OFF_FDH  = 14 * MB_ + 64 * 1024; // f16 (B,N,N)   16MB
static constexpr size_t OFF_CTXS = 31 * MB_;             // f32 (B,N,C)    4MB
static constexpr size_t OFF_CTXD = 35 * MB_;             // f32 (B,N,C)    4MB
static constexpr size_t OFF_CSLN = 39 * MB_;             // bf16 (B,N,C)   2MB
static constexpr size_t OFF_CDLN = 41 * MB_;             // bf16 (B,N,C)   2MB
static constexpr size_t OFF_X1T  = 43 * MB_;             // bf16 (B,N,2C)  4MB
static constexpr size_t WS_NEED  = 47 * MB_;

__device__ __forceinline__ float rfl(float x){
  return __uint_as_float(__builtin_amdgcn_readfirstlane(__float_as_uint(x)));
}
__device__ __forceinline__ bf16x8 cvt8(const float* p){
  float4 a = *reinterpret_cast<const float4*>(p);
  float4 c = *reinterpret_cast<const float4*>(p + 4);
  bf16x8 r;
  r[0]=(__bf16)a.x; r[1]=(__bf16)a.y; r[2]=(__bf16)a.z; r[3]=(__bf16)a.w;
  r[4]=(__bf16)c.x; r[5]=(__bf16)c.y; r[6]=(__bf16)c.z; r[7]=(__bf16)c.w;
  return r;
}

// ---- LN(featA) over channels -> fanT bf16 (B,N,C) ---------------------------
__global__ __launch_bounds__(256) void lnA_pack(const float* __restrict__ featA,
    __bf16* __restrict__ fanT, const float* __restrict__ gam, const float* __restrict__ bet){
  int b = blockIdx.y, n0 = blockIdx.x * 32;
  int t = threadIdx.x, nl = t & 31, cg = t >> 5;
  __shared__ float tile[256][33];
  __shared__ float red1[8][32], red2[8][32], mus[32], rss[32];
  __shared__ float gsh[256], bsh[256];
  gsh[t] = gam[t]; bsh[t] = bet[t];
  #pragma unroll
  for (int i = 0; i < 32; i++){
    int c = cg * 32 + i;
    tile[c][nl] = featA[((size_t)(b * C_ + c)) * N_ + n0 + nl];
  }
  __syncthreads();
  float s1 = 0.f, s2 = 0.f;
  #pragma unroll
  for (int i = 0; i < 32; i++){
    float v = tile[cg * 32 + i][nl];
    s1 += v; s2 += v * v;
  }
  red1[cg][nl] = s1; red2[cg][nl] = s2;
  __syncthreads();
  if (t < 32){
    float a = 0.f, q = 0.f;
    #pragma unroll
    for (int i = 0; i < 8; i++){ a += red1[i][t]; q += red2[i][t]; }
    float m = a / (float)C_;
    mus[t] = m; rss[t] = rsqrtf(q / (float)C_ - m * m + EPSf);
  }
  __syncthreads();
  float mu = mus[nl], rs = rss[nl];
  size_t obase = ((size_t)(b * N_ + n0 + nl)) * C_;
  #pragma unroll
  for (int i = 0; i < 32; i++){
    int c = cg * 32 + i;
    fanT[obase + c] = (__bf16)((tile[c][nl] - mu) * rs * gsh[c] + bsh[c]);
  }
}

// ---- featB (B,C,N) fp32 -> fbT (B,N,C) bf16 ---------------------------------
__global__ __launch_bounds__(256) void packT_kernel(const float* __restrict__ featB,
    __bf16* __restrict__ fbT){
  int b = blockIdx.z, c0 = blockIdx.y * 64, n0 = blockIdx.x * 64;
  int t = threadIdx.x;
  __shared__ float tile[64][65];
  int cl = t >> 6, nl = t & 63;
  #pragma unroll
  for (int i = 0; i < 16; i++)
    tile[i * 4 + cl][nl] = featB[((size_t)(b * C_ + c0 + i * 4 + cl)) * N_ + n0 + nl];
  __syncthreads();
  int nr = t >> 2, cc = (t & 3) * 16;
  alignas(16) __bf16 tmp[16];
  #pragma unroll
  for (int j = 0; j < 16; j++) tmp[j] = (__bf16)tile[cc + j][nr];
  size_t d = ((size_t)(b * N_ + n0 + nr)) * C_ + c0 + cc;
  *reinterpret_cast<uint4*>(&fbT[d])     = *reinterpret_cast<uint4*>(&tmp[0]);
  *reinterpret_cast<uint4*>(&fbT[d + 8]) = *reinterpret_cast<uint4*>(&tmp[8]);
}

// ---- 5 projection GEMMs, bf16 MFMA -----------------------------------------
// p=0 q (X=fanT -> qpk scaled)  1 k (fbT -> kpk)  2 v (fbT -> vpk, swapped roles)
// p=3 qd (fanT -> qdT)          4 kd (fbT -> kdT)
__global__ __launch_bounds__(256) void proj_mfma(const __bf16* __restrict__ fanT,
    const __bf16* __restrict__ fbT, __bf16* __restrict__ wsh,
    const float* __restrict__ qw, const float* __restrict__ qb,
    const float* __restrict__ kw, const float* __restrict__ kb,
    const float* __restrict__ vw, const float* __restrict__ vb,
    const float* __restrict__ qdw, const float* __restrict__ qdb,
    const float* __restrict__ kdw, const float* __restrict__ kdb){
  const int p = blockIdx.z % 5, b = blockIdx.z / 5;
  const int t = threadIdx.x, w = t >> 6, lane = t & 63, ln = lane & 15, g = lane >> 4;
  const float *W, *bias;
  const __bf16* X;
  __bf16* Y;
  if (p == 0)      { W = qw;  bias = qb;  X = fanT; Y = wsh + (OFF_QPK - OFF_FANT) / 2; }
  else if (p == 1) { W = kw;  bias = kb;  X = fbT;  Y = wsh + (OFF_KPK - OFF_FANT) / 2; }
  else if (p == 2) { W = vw;  bias = vb;  X = fbT;  Y = wsh + (OFF_VPK - OFF_FANT) / 2; }
  else if (p == 3) { W = qdw; bias = qdb; X = fanT; Y = wsh + (OFF_QDT - OFF_FANT) / 2; }
  else             { W = kdw; bias = kdb; X = fbT;  Y = wsh + (OFF_KDT - OFF_FANT) / 2; }

  f32x4 acc[4];
  #pragma unroll
  for (int i = 0; i < 4; i++) acc[i] = (f32x4){0.f, 0.f, 0.f, 0.f};

  if (p != 2){
    // D[n][o]: A = X rows (n), B = W rows (o)
    const int n0w = blockIdx.x * 64 + w * 16, o0 = blockIdx.y * 64;
    #pragma unroll
    for (int ks = 0; ks < 8; ks++){
      bf16x8 af = *reinterpret_cast<const bf16x8*>(
          &X[((size_t)(b * N_ + n0w + ln)) * C_ + ks * 32 + g * 8]);
      #pragma unroll
      for (int ot = 0; ot < 4; ot++){
        bf16x8 bf = cvt8(&W[(size_t)(o0 + ot * 16 + ln) * C_ + ks * 32 + g * 8]);
        acc[ot] = __builtin_amdgcn_mfma_f32_16x16x32_bf16(af, bf, acc[ot], 0, 0, 0);
      }
    }
    const float inv = 0.17677669529663687f;
    #pragma unroll
    for (int ot = 0; ot < 4; ot++){
      int o = o0 + ot * 16 + ln;
      float bz = bias[o];
      #pragma unroll
      for (int r = 0; r < 4; r++){
        int n = n0w + g * 4 + r;
        float val = acc[ot][r] + bz;
        if (p == 0){
          val *= inv;
          Y[(((size_t)(b * H_ + (o >> 5))) * N_ + n) * HD_ + (o & 31)] = (__bf16)val;
        } else if (p == 1){
          Y[(((size_t)(b * H_ + (o >> 5))) * N_ + n) * HD_ + (o & 31)] = (__bf16)val;
        } else {
          Y[((size_t)(b * N_ + n)) * C_ + o] = (__bf16)val;
        }
      }
    }
  } else {
    // v: D[o][n]: A = W rows (o), B = X rows (n); output (B,C,N)
    const int o0w = blockIdx.y * 64 + w * 16, n0 = blockIdx.x * 64;
    #pragma unroll
    for (int ks = 0; ks < 8; ks++){
      bf16x8 af = cvt8(&W[(size_t)(o0w + ln) * C_ + ks * 32 + g * 8]);
      #pragma unroll
      for (int nt = 0; nt < 4; nt++){
        bf16x8 bf = *reinterpret_cast<const bf16x8*>(
            &X[((size_t)(b * N_ + n0 + nt * 16 + ln)) * C_ + ks * 32 + g * 8]);
        acc[nt] = __builtin_amdgcn_mfma_f32_16x16x32_bf16(af, bf, acc[nt], 0, 0, 0);
      }
    }
    float bz[4];
    #pragma unroll
    for (int r = 0; r < 4; r++) bz[r] = vb[o0w + g * 4 + r];
    #pragma unroll
    for (int nt = 0; nt < 4; nt++)
      #pragma unroll
      for (int r = 0; r < 4; r++){
        int o = o0w + g * 4 + r, n = n0 + nt * 16 + ln;
        Y[((size_t)(b * C_ + o)) * N_ + n] = (__bf16)(acc[nt][r] + bz[r]);
      }
  }
}

// ---- row norms from bf16 qdT/kdT -------------------------------------------
__global__ __launch_bounds__(256) void norms_b(const __bf16* __restrict__ qdT,
    const __bf16* __restrict__ kdT, float* __restrict__ qq, float* __restrict__ kk){
  int b = blockIdx.y, n = blockIdx.x * 64 + (threadIdx.x >> 2), part = threadIdx.x & 3;
  size_t base = ((size_t)(b * N_ + n)) * C_ + part * 64;
  float s1 = 0.f, s2 = 0.f;
  #pragma unroll
  for (int i = 0; i < 8; i++){
    bf16x8 a = *reinterpret_cast<const bf16x8*>(&qdT[base + i * 8]);
    bf16x8 d = *reinterpret_cast<const bf16x8*>(&kdT[base + i * 8]);
    #pragma unroll
    for (int j = 0; j < 8; j++){
      float fa = (float)a[j]; s1 += fa * fa;
      float fd = (float)d[j]; s2 += fd * fd;
    }
  }
  s1 += __shfl_xor(s1, 1); s1 += __shfl_xor(s1, 2);
  s2 += __shfl_xor(s2, 1); s2 += __shfl_xor(s2, 2);
  if (part == 0){ qq[b * N_ + n] = s1; kk[b * N_ + n] = s2; }
}

// ---- feature cdist Gram -> fdh fp16 (B,N,N) --------------------------------
__global__ __launch_bounds__(256) void fdist_mfma(const __bf16* __restrict__ qdT,
    const __bf16* __restrict__ kdT, const float* __restrict__ qq,
    const float* __restrict__ kk, _Float16* __restrict__ fdh){
  const int t = threadIdx.x, w = t >> 6, lane = t & 63, ln = lane & 15, g = lane >> 4;
  const int b = blockIdx.z, n0 = blockIdx.y * 64 + w * 16, m0 = blockIdx.x * 64;
  __shared__ _Float16 sbl[4][16][68];

  bf16x8 qfr[8];
  #pragma unroll
  for (int ks = 0; ks < 8; ks++)
    qfr[ks] = *reinterpret_cast<const bf16x8*>(
        &qdT[((size_t)(b * N_ + n0 + ln)) * C_ + ks * 32 + g * 8]);
  float qqv[4];
  #pragma unroll
  for (int r = 0; r < 4; r++) qqv[r] = qq[b * N_ + n0 + g * 4 + r];

  #pragma unroll
  for (int mt = 0; mt < 4; mt++){
    f32x4 a = (f32x4){0.f, 0.f, 0.f, 0.f};
    #pragma unroll
    for (int ks = 0; ks < 8; ks++){
      bf16x8 kfr = *reinterpret_cast<const bf16x8*>(
          &kdT[((size_t)(b * N_ + m0 + mt * 16 + ln)) * C_ + ks * 32 + g * 8]);
      a = __builtin_amdgcn_mfma_f32_16x16x32_bf16(qfr[ks], kfr, a, 0, 0, 0);
    }
    float kkv = kk[b * N_ + m0 + mt * 16 + ln];
    #pragma unroll
    for (int r = 0; r < 4; r++){
      float d2 = qqv[r] + kkv - 2.f * a[r];
      sbl[w][g * 4 + r][mt * 16 + ln] = (_Float16)sqrtf(fmaxf(d2, 0.f));
    }
  }
  __syncthreads();
  #pragma unroll
  for (int it = 0; it < 8; it++){
    int row = (lane >> 5) + it * 2, colu = lane & 31;
    uint u = *reinterpret_cast<const uint*>(&sbl[w][row][colu * 2]);
    *reinterpret_cast<uint*>(&fdh[((size_t)(b * N_ + n0 + row)) * N_ + m0 + colu * 2]) = u;
  }
}

// ---- fused dual-path flash attention ----------------------------------------
__global__ __launch_bounds__(256) void dual_attn(
    const __bf16* __restrict__ qpk, const __bf16* __restrict__ kpk, const __bf16* __restrict__ vpk,
    const _Float16* __restrict__ fdh,
    const float* __restrict__ xyzA, const float* __restrict__ xyzB,
    const float* __restrict__ sbw1, const float* __restrict__ sbg, const float* __restrict__ sbb,
    const float* __restrict__ sbm, const float* __restrict__ sbv,
    const float* __restrict__ sbw2, const float* __restrict__ sbb2,
    float* __restrict__ ctxsT, float* __restrict__ ctxdT){
  const int t = threadIdx.x, w = t >> 6, lane = t & 63, ln = lane & 15, g = lane >> 4;
  const int h = blockIdx.y, b = blockIdx.z;
  const int nbase = blockIdx.x * 64 + w * 16;
  const int n = nbase + ln;

  float Ac[4], Bc[4], W2h[4];
  #pragma unroll
  for (int j = 0; j < 4; j++){
    float rs = rsqrtf(sbv[j] + EPSf);
    Ac[j]  = rfl(-sbw1[j] * rs * sbg[j]);
    Bc[j]  = rfl(-sbm[j] * rs * sbg[j] + sbb[j]);
    W2h[j] = rfl(sbw2[h * 4 + j]);
  }
  float C0 = rfl(sbb2[h]);

  bf16x8 qf = *reinterpret_cast<const bf16x8*>(
      &qpk[(((size_t)(b * H_ + h)) * N_ + n) * HD_ + g * 8]);
  float ax = xyzA[((size_t)(b * N_ + n)) * 3 + 0];
  float ay = xyzA[((size_t)(b * N_ + n)) * 3 + 1];
  float az = xyzA[((size_t)(b * N_ + n)) * 3 + 2];
  const _Float16* fdrow = &fdh[((size_t)(b * N_ + n)) * N_];

  f32x4 os[2], od[2];
  #pragma unroll
  for (int i = 0; i < 2; i++){ os[i] = (f32x4){0.f,0.f,0.f,0.f}; od[i] = (f32x4){0.f,0.f,0.f,0.f}; }
  float ms = -3e38f, ls = 0.f, md = -3e38f, ld = 0.f;

  __shared__ __align__(16) float ss[4][16][68];
  __shared__ float4 xbb[4][64];

  for (int m0 = 0; m0 < N_; m0 += 64){
    __syncthreads();
    {
      const float* xp = &xyzB[((size_t)(b * N_ + m0 + lane)) * 3];
      xbb[w][lane] = make_float4(xp[0], xp[1], xp[2], 0.f);
    }
    f32x4 sa[4];
    #pragma unroll
    for (int i = 0; i < 4; i++) sa[i] = (f32x4){0.f, 0.f, 0.f, 0.f};
    #pragma unroll
    for (int mt = 0; mt < 4; mt++){
      bf16x8 kf = *reinterpret_cast<const bf16x8*>(
          &kpk[(((size_t)(b * H_ + h)) * N_ + m0 + mt * 16 + ln) * HD_ + g * 8]);
      sa[mt] = __builtin_amdgcn_mfma_f32_16x16x32_bf16(qf, kf, sa[mt], 0, 0, 0);
    }
    #pragma unroll
    for (int mt = 0; mt < 4; mt++)
      #pragma unroll
      for (int r = 0; r < 4; r++)
        ss[w][g * 4 + r][mt * 16 + ln] = sa[mt][r];
    __syncthreads();

    #pragma unroll
    for (int kh = 0; kh < 2; kh++){
      float s8[8], d8[8];
      {
        float4 A4 = *reinterpret_cast<const float4*>(&ss[w][ln][kh * 32 + g * 8]);
        float4 B4 = *reinterpret_cast<const float4*>(&ss[w][ln][kh * 32 + g * 8 + 4]);
        s8[0]=A4.x; s8[1]=A4.y; s8[2]=A4.z; s8[3]=A4.w;
        s8[4]=B4.x; s8[5]=B4.y; s8[6]=B4.z; s8[7]=B4.w;
      }
      f16x8 fv = *reinterpret_cast<const f16x8*>(&fdrow[m0 + kh * 32 + g * 8]);
      float mxs = -3e38f, mxd = -3e38f;
      #pragma unroll
      for (int j = 0; j < 8; j++){
        float4 xk = xbb[w][kh * 32 + g * 8 + j];
        float dx = ax - xk.x, dy = ay - xk.y, dz = az - xk.z;
        float sd = sqrtf(dx * dx + dy * dy + dz * dz);
        float bias = C0;
        #pragma unroll
        for (int u = 0; u < 4; u++)
          bias += W2h[u] * fmaxf(fmaf(Ac[u], sd, Bc[u]), 0.f);
        s8[j] += bias;
        d8[j] = (float)fv[j] + bias;
        mxs = fmaxf(mxs, s8[j]);
        mxd = fmaxf(mxd, d8[j]);
      }
      mxs = fmaxf(mxs, __shfl_xor(mxs, 16)); mxs = fmaxf(mxs, __shfl_xor(mxs, 32));
      mxd = fmaxf(mxd, __shfl_xor(mxd, 16)); mxd = fmaxf(mxd, __shfl_xor(mxd, 32));
      float nms = fmaxf(ms, mxs), als = __expf(ms - nms);
      float nmd = fmaxf(md, mxd), ald = __expf(md - nmd);
      float pss = 0.f, psd = 0.f;
      bf16x8 pfs, pfd;
      #pragma unroll
      for (int j = 0; j < 8; j++){
        float pv = __expf(s8[j] - nms); pss += pv; pfs[j] = (__bf16)pv;
        float qv = __expf(d8[j] - nmd); psd += qv; pfd[j] = (__bf16)qv;
      }
      pss += __shfl_xor(pss, 16); pss += __shfl_xor(pss, 32);
      psd += __shfl_xor(psd, 16); psd += __shfl_xor(psd, 32);
      ls = ls * als + pss; ms = nms;
      ld = ld * ald + psd; md = nmd;
      os[0] *= als; os[1] *= als; od[0] *= ald; od[1] *= ald;
      #pragma unroll
      for (int dt = 0; dt < 2; dt++){
        bf16x8 vf = *reinterpret_cast<const bf16x8*>(
            &vpk[((size_t)(b * C_ + h * HD_ + dt * 16 + ln)) * N_ + m0 + kh * 32 + g * 8]);
        os[dt] = __builtin_amdgcn_mfma_f32_16x16x32_bf16(vf, pfs, os[dt], 0, 0, 0);
        od[dt] = __builtin_amdgcn_mfma_f32_16x16x32_bf16(vf, pfd, od[dt], 0, 0, 0);
      }
    }
  }
  float is = 1.f / ls, idv = 1.f / ld;
  #pragma unroll
  for (int dt = 0; dt < 2; dt++)
    #pragma unroll
    for (int r = 0; r < 4; r++){
      int ch = h * HD_ + dt * 16 + g * 4 + r;
      size_t base = ((size_t)(b * N_ + n)) * C_ + ch;
      ctxsT[base] = os[dt][r] * is;
      ctxdT[base] = od[dt][r] * idv;
    }
}

// ---- LN of ctx (rows contiguous) -> bf16 ------------------------------------
__global__ __launch_bounds__(256) void ln_ctx(const float* __restrict__ ctxsT,
    const float* __restrict__ ctxdT, __bf16* __restrict__ csLN, __bf16* __restrict__ cdLN,
    const float* __restrict__ lsg, const float* __restrict__ lsb,
    const float* __restrict__ ldg, const float* __restrict__ ldb){
  const float* src = blockIdx.y ? ctxdT : ctxsT;
  __bf16* dst = blockIdx.y ? cdLN : csLN;
  const float* gg = blockIdx.y ? ldg : lsg;
  const float* bb = blockIdx.y ? ldb : lsb;
  int w = threadIdx.x >> 6, lane = threadIdx.x & 63;
  size_t row = (size_t)blockIdx.x * 4 + w;
  float4 v = *reinterpret_cast<const float4*>(&src[row * C_ + lane * 4]);
  float s1 = v.x + v.y + v.z + v.w;
  float s2 = v.x * v.x + v.y * v.y + v.z * v.z + v.w * v.w;
  #pragma unroll
  for (int off = 1; off < 64; off <<= 1){
    s1 += __shfl_xor(s1, off);
    s2 += __shfl_xor(s2, off);
  }
  float m = s1 / (float)C_;
  float rs = rsqrtf(s2 / (float)C_ - m * m + EPSf);
  float4 g4 = *reinterpret_cast<const float4*>(&gg[lane * 4]);
  float4 b4 = *reinterpret_cast<const float4*>(&bb[lane * 4]);
  alignas(8) __bf16 o4[4];
  o4[0] = (__bf16)((v.x - m) * rs * g4.x + b4.x);
  o4[1] = (__bf16)((v.y - m) * rs * g4.y + b4.y);
  o4[2] = (__bf16)((v.z - m) * rs * g4.z + b4.z);
  o4[3] = (__bf16)((v.w - m) * rs * g4.w + b4.w);
  *reinterpret_cast<uint2*>(&dst[row * C_ + lane * 4]) = *reinterpret_cast<uint2*>(o4);
}

// ---- fusion stage 1: X1T = ReLU(BN(fw1 @ [fanT|csLN|cdLN])) bf16 (B,N,2C) ---
__global__ __launch_bounds__(256) void fusion1_mfma(const __bf16* __restrict__ fanT,
    const __bf16* __restrict__ csLN, const __bf16* __restrict__ cdLN,
    __bf16* __restrict__ X1T, const float* __restrict__ fw1,
    const float* __restrict__ fbg, const float* __restrict__ fbb,
    const float* __restrict__ fbm, const float* __restrict__ fbv){
  const int t = threadIdx.x, w = t >> 6, lane = t & 63, ln = lane & 15, g = lane >> 4;
  const int b = blockIdx.z, o0 = blockIdx.y * 64, n0w = blockIdx.x * 64 + w * 16;
  f32x4 acc[4];
  #pragma unroll
  for (int i = 0; i < 4; i++) acc[i] = (f32x4){0.f, 0.f, 0.f, 0.f};
  const __bf16* segs[3] = {fanT, csLN, cdLN};
  #pragma unroll
  for (int ks = 0; ks < 24; ks++){
    const __bf16* base = segs[ks >> 3];
    int coff = (ks & 7) * 32 + g * 8;
    bf16x8 af = *reinterpret_cast<const bf16x8*>(
        &base[((size_t)(b * N_ + n0w + ln)) * C_ + coff]);
    #pragma unroll
    for (int ot = 0; ot < 4; ot++){
      bf16x8 bf = cvt8(&fw1[(size_t)(o0 + ot * 16 + ln) * (3 * C_) + ks * 32 + g * 8]);
      acc[ot] = __builtin_amdgcn_mfma_f32_16x16x32_bf16(af, bf, acc[ot], 0, 0, 0);
    }
  }
  #pragma unroll
  for (int ot = 0; ot < 4; ot++){
    int o = o0 + ot * 16 + ln;
    float mn = fbm[o], rs = rsqrtf(fbv[o] + EPSf), gg = fbg[o], be = fbb[o];
    #pragma unroll
    for (int r = 0; r < 4; r++){
      int n = n0w + g * 4 + r;
      float x = (acc[ot][r] - mn) * rs * gg + be;
      X1T[((size_t)(b * N_ + n)) * (2 * C_) + o] = (__bf16)fmaxf(x, 0.f);
    }
  }
}

// ---- fusion stage 2: out = fw2 @ X1 + fb2 + featA (B,C,N) fp32 --------------
__global__ __launch_bounds__(256) void fusion2_mfma(const __bf16* __restrict__ X1T,
    const float* __restrict__ fw2, const float* __restrict__ fb2,
    const float* __restrict__ featA, float* __restrict__ out){
  const int t = threadIdx.x, w = t >> 6, lane = t & 63, ln = lane & 15, g = lane >> 4;
  const int b = blockIdx.z, o0w = blockIdx.y * 64 + w * 16, n0 = blockIdx.x * 64;
  f32x4 acc[4];
  #pragma unroll
  for (int i = 0; i < 4; i++) acc[i] = (f32x4){0.f, 0.f, 0.f, 0.f};
  #pragma unroll
  for (int ks = 0; ks < 16; ks++){
    bf16x8 af = cvt8(&fw2[(size_t)(o0w + ln) * (2 * C_) + ks * 32 + g * 8]);
    #pragma unroll
    for (int nt = 0; nt < 4; nt++){
      bf16x8 bf = *reinterpret_cast<const bf16x8*>(
          &X1T[((size_t)(b * N_ + n0 + nt * 16 + ln)) * (2 * C_) + ks * 32 + g * 8]);
      acc[nt] = __builtin_amdgcn_mfma_f32_16x16x32_bf16(af, bf, acc[nt], 0, 0, 0);
    }
  }
  float bz[4];
  #pragma unroll
  for (int r = 0; r < 4; r++) bz[r] = fb2[o0w + g * 4 + r];
  #pragma unroll
  for (int nt = 0; nt < 4; nt++)
    #pragma unroll
    for (int r = 0; r < 4; r++){
      int o = o0w + g * 4 + r, n = n0 + nt * 16 + ln;
      size_t oi = ((size_t)(b * C_ + o)) * N_ + n;
      out[oi] = acc[nt][r] + bz[r] + featA[oi];
    }
}

extern "C" void kernel_launch(void* const* d_in, const int* in_sizes, int n_in,
                              void* d_out, int out_size, void* d_ws, size_t ws_size,
                              hipStream_t stream){
  (void)in_sizes; (void)n_in; (void)out_size;
  if (ws_size < WS_NEED) return;

  const float* xyzA  = (const float*)d_in[0];
  const float* featA = (const float*)d_in[1];
  const float* xyzB  = (const float*)d_in[2];
  const float* featB = (const float*)d_in[3];
  const float* qw  = (const float*)d_in[4];   const float* qb  = (const float*)d_in[5];
  const float* kw  = (const float*)d_in[6];   const float* kb  = (const float*)d_in[7];
  const float* vw  = (const float*)d_in[8];   const float* vb  = (const float*)d_in[9];
  const float* sbw1= (const float*)d_in[10];  const float* sbg = (const float*)d_in[11];
  const float* sbb = (const float*)d_in[12];  const float* sbm = (const float*)d_in[13];
  const float* sbv = (const float*)d_in[14];  const float* sbw2= (const float*)d_in[15];
  const float* sbb2= (const float*)d_in[16];
  const float* qdw = (const float*)d_in[17];  const float* qdb = (const float*)d_in[18];
  const float* kdw = (const float*)d_in[19];  const float* kdb = (const float*)d_in[20];
  const float* ling= (const float*)d_in[21];  const float* linb= (const float*)d_in[22];
  const float* lsg = (const float*)d_in[23];  const float* lsb = (const float*)d_in[24];
  const float* ldg = (const float*)d_in[25];  const float* ldb = (const float*)d_in[26];
  const float* fw1 = (const float*)d_in[27];  const float* fbg = (const float*)d_in[28];
  const float* fbb = (const float*)d_in[29];  const float* fbm = (const float*)d_in[30];
  const float* fbv = (const float*)d_in[31];  const float* fw2 = (const float*)d_in[32];
  const float* fb2 = (const float*)d_in[33];

  char* ws = (char*)d_ws;
  __bf16*   fanT = (__bf16*)(ws + OFF_FANT);
  __bf16*   fbT  = (__bf16*)(ws + OFF_FBT);
  __bf16*   qpk  = (__bf16*)(ws + OFF_QPK);
  __bf16*   kpk  = (__bf16*)(ws + OFF_KPK);
  __bf16*   vpk  = (__bf16*)(ws + OFF_VPK);
  __bf16*   qdT  = (__bf16*)(ws + OFF_QDT);
  __bf16*   kdT  = (__bf16*)(ws + OFF_KDT);
  float*    qq   = (float*)(ws + OFF_QQ);
  float*    kk   = (float*)(ws + OFF_KK);
  _Float16* fdh  = (_Float16*)(ws + OFF_FDH);
  float*    ctxsT= (float*)(ws + OFF_CTXS);
  float*    ctxdT= (float*)(ws + OFF_CTXD);
  __bf16*   csLN = (__bf16*)(ws + OFF_CSLN);
  __bf16*   cdLN = (__bf16*)(ws + OFF_CDLN);
  __bf16*   X1T  = (__bf16*)(ws + OFF_X1T);
  float*    out  = (float*)d_out;

  lnA_pack<<<dim3(N_ / 32, B_), 256, 0, stream>>>(featA, fanT, ling, linb);
  packT_kernel<<<dim3(N_ / 64, C_ / 64, B_), 256, 0, stream>>>(featB, fbT);
  proj_mfma<<<dim3(N_ / 64, C_ / 64, 5 * B_), 256, 0, stream>>>(
      fanT, fbT, fanT, qw, qb, kw, kb, vw, vb, qdw, qdb, kdw, kdb);
  norms_b<<<dim3(N_ / 64, B_), 256, 0, stream>>>(qdT, kdT, qq, kk);
  fdist_mfma<<<dim3(N_ / 64, N_ / 64, B_), 256, 0, stream>>>(qdT, kdT, qq, kk, fdh);
  dual_attn<<<dim3(N_ / 64, H_, B_), 256, 0, stream>>>(
      qpk, kpk, vpk, fdh, xyzA, xyzB,
      sbw1, sbg, sbb, sbm, sbv, sbw2, sbb2, ctxsT, ctxdT);
  ln_ctx<<<dim3(B_ * N_ / 4, 2), 256, 0, stream>>>(
      ctxsT, ctxdT, csLN, cdLN, lsg, lsb, ldg, ldb);
  fusion1_mfma<<<dim3(N_ / 64, (2 * C_) / 64, B_), 256, 0, stream>>>(
      fanT, csLN, cdLN, X1T, fw1, fbg, fbb, fbm, fbv);
  fusion2_mfma<<<dim3(N_ / 64, C_ / 64, B_), 256, 0, stream>>>(
      X1T, fw2, fb2, featA, out);
}

// Round 4
// 291.098 us; speedup vs baseline: 3.9732x; 1.0904x over previous
//
#include <hip/hip_runtime.h>

#define B_ 2
#define N_ 2048
#define C_ 256
#define H_ 8
#define HD_ 32
#define EPSf 1e-5f

typedef __bf16   bf16x8 __attribute__((ext_vector_type(8)));
typedef float    f32x4  __attribute__((ext_vector_type(4)));
typedef _Float16 f16x8  __attribute__((ext_vector_type(8)));
typedef _Float16 f16x4  __attribute__((ext_vector_type(4)));
typedef _Float16 f16x2  __attribute__((ext_vector_type(2)));

// ---- workspace layout (byte offsets) ---------------------------------------
static constexpr size_t MB_ = 1024 * 1024;
static constexpr size_t OFF_FANT = 0;                    // bf16 (B,N,C)   2MB
static constexpr size_t OFF_FBT  = 2 * MB_;              // bf16 (B,N,C)   2MB
static constexpr size_t OFF_QPK  = 4 * MB_;              // bf16 (B,H,N,HD) 2MB
static constexpr size_t OFF_KPK  = 6 * MB_;              // bf16 (B,H,N,HD) 2MB
static constexpr size_t OFF_VPK  = 8 * MB_;              // bf16/f16 (B,C,N) 2MB
static constexpr size_t OFF_QDT  = 10 * MB_;             // bf16 (B,N,C)   2MB
static constexpr size_t OFF_KDT  = 12 * MB_;             // bf16 (B,N,C)   2MB
static constexpr size_t OFF_QQ   = 14 * MB_;             // f32 (B,N)
static constexpr size_t OFF_KK   = 14 * MB_ + 16 * 1024; // f32 (B,N)
// old path: fdh fp16 (B,N,N) 16MB at this offset; new path: fsd uint (B,N,N) 32MB
static constexpr size_t OFF_FDH  = 14 * MB_ + 64 * 1024;
static constexpr size_t OFF_FSD  = 14 * MB_ + 64 * 1024;
// old-path (47MB) tail
static constexpr size_t OFF_CTXS = 31 * MB_;
static constexpr size_t OFF_CTXD = 35 * MB_;
static constexpr size_t OFF_CSLN = 39 * MB_;
static constexpr size_t OFF_CDLN = 41 * MB_;
static constexpr size_t OFF_X1T  = 43 * MB_;
static constexpr size_t WS_NEED  = 47 * MB_;
// new-path (63MB) tail
static constexpr size_t OFF2_CTXS = 47 * MB_;
static constexpr size_t OFF2_CTXD = 51 * MB_;
static constexpr size_t OFF2_CSLN = 55 * MB_;
static constexpr size_t OFF2_CDLN = 57 * MB_;
static constexpr size_t OFF2_X1T  = 59 * MB_;
static constexpr size_t WS_NEED2  = 63 * MB_;

__device__ __forceinline__ float rfl(float x){
  return __uint_as_float(__builtin_amdgcn_readfirstlane(__float_as_uint(x)));
}
__device__ __forceinline__ bf16x8 cvt8(const float* p){
  float4 a = *reinterpret_cast<const float4*>(p);
  float4 c = *reinterpret_cast<const float4*>(p + 4);
  bf16x8 r;
  r[0]=(__bf16)a.x; r[1]=(__bf16)a.y; r[2]=(__bf16)a.z; r[3]=(__bf16)a.w;
  r[4]=(__bf16)c.x; r[5]=(__bf16)c.y; r[6]=(__bf16)c.z; r[7]=(__bf16)c.w;
  return r;
}
__device__ __forceinline__ unsigned int packh2(float lo, float hi){
  f16x2 h; h[0] = (_Float16)lo; h[1] = (_Float16)hi;
  return __builtin_bit_cast(unsigned int, h);
}
__device__ __forceinline__ void unpackh2(unsigned int u, float& lo, float& hi){
  f16x2 h = __builtin_bit_cast(f16x2, u);
  lo = (float)h[0]; hi = (float)h[1];
}

// ---- LN(featA) over channels -> fanT bf16 (B,N,C) ---------------------------
__global__ __launch_bounds__(256) void lnA_pack(const float* __restrict__ featA,
    __bf16* __restrict__ fanT, const float* __restrict__ gam, const float* __restrict__ bet){
  int b = blockIdx.y, n0 = blockIdx.x * 32;
  int t = threadIdx.x, nl = t & 31, cg = t >> 5;
  __shared__ float tile[256][33];
  __shared__ float red1[8][32], red2[8][32], mus[32], rss[32];
  __shared__ float gsh[256], bsh[256];
  gsh[t] = gam[t]; bsh[t] = bet[t];
  #pragma unroll
  for (int i = 0; i < 32; i++){
    int c = cg * 32 + i;
    tile[c][nl] = featA[((size_t)(b * C_ + c)) * N_ + n0 + nl];
  }
  __syncthreads();
  float s1 = 0.f, s2 = 0.f;
  #pragma unroll
  for (int i = 0; i < 32; i++){
    float v = tile[cg * 32 + i][nl];
    s1 += v; s2 += v * v;
  }
  red1[cg][nl] = s1; red2[cg][nl] = s2;
  __syncthreads();
  if (t < 32){
    float a = 0.f, q = 0.f;
    #pragma unroll
    for (int i = 0; i < 8; i++){ a += red1[i][t]; q += red2[i][t]; }
    float m = a / (float)C_;
    mus[t] = m; rss[t] = rsqrtf(q / (float)C_ - m * m + EPSf);
  }
  __syncthreads();
  float mu = mus[nl], rs = rss[nl];
  size_t obase = ((size_t)(b * N_ + n0 + nl)) * C_;
  #pragma unroll
  for (int i = 0; i < 32; i++){
    int c = cg * 32 + i;
    fanT[obase + c] = (__bf16)((tile[c][nl] - mu) * rs * gsh[c] + bsh[c]);
  }
}

// ---- featB (B,C,N) fp32 -> fbT (B,N,C) bf16 ---------------------------------
__global__ __launch_bounds__(256) void packT_kernel(const float* __restrict__ featB,
    __bf16* __restrict__ fbT){
  int b = blockIdx.z, c0 = blockIdx.y * 64, n0 = blockIdx.x * 64;
  int t = threadIdx.x;
  __shared__ float tile[64][65];
  int cl = t >> 6, nl = t & 63;
  #pragma unroll
  for (int i = 0; i < 16; i++)
    tile[i * 4 + cl][nl] = featB[((size_t)(b * C_ + c0 + i * 4 + cl)) * N_ + n0 + nl];
  __syncthreads();
  int nr = t >> 2, cc = (t & 3) * 16;
  alignas(16) __bf16 tmp[16];
  #pragma unroll
  for (int j = 0; j < 16; j++) tmp[j] = (__bf16)tile[cc + j][nr];
  size_t d = ((size_t)(b * N_ + n0 + nr)) * C_ + c0 + cc;
  *reinterpret_cast<uint4*>(&fbT[d])     = *reinterpret_cast<uint4*>(&tmp[0]);
  *reinterpret_cast<uint4*>(&fbT[d + 8]) = *reinterpret_cast<uint4*>(&tmp[8]);
}

// ---- 5 projection GEMMs, bf16 MFMA -----------------------------------------
__global__ __launch_bounds__(256) void proj_mfma(const __bf16* __restrict__ fanT,
    const __bf16* __restrict__ fbT, __bf16* __restrict__ wsh, int vfp16,
    const float* __restrict__ qw, const float* __restrict__ qb,
    const float* __restrict__ kw, const float* __restrict__ kb,
    const float* __restrict__ vw, const float* __restrict__ vb,
    const float* __restrict__ qdw, const float* __restrict__ qdb,
    const float* __restrict__ kdw, const float* __restrict__ kdb){
  const int p = blockIdx.z % 5, b = blockIdx.z / 5;
  const int t = threadIdx.x, w = t >> 6, lane = t & 63, ln = lane & 15, g = lane >> 4;
  const float *W, *bias;
  const __bf16* X;
  __bf16* Y;
  if (p == 0)      { W = qw;  bias = qb;  X = fanT; Y = wsh + (OFF_QPK - OFF_FANT) / 2; }
  else if (p == 1) { W = kw;  bias = kb;  X = fbT;  Y = wsh + (OFF_KPK - OFF_FANT) / 2; }
  else if (p == 2) { W = vw;  bias = vb;  X = fbT;  Y = wsh + (OFF_VPK - OFF_FANT) / 2; }
  else if (p == 3) { W = qdw; bias = qdb; X = fanT; Y = wsh + (OFF_QDT - OFF_FANT) / 2; }
  else             { W = kdw; bias = kdb; X = fbT;  Y = wsh + (OFF_KDT - OFF_FANT) / 2; }

  f32x4 acc[4];
  #pragma unroll
  for (int i = 0; i < 4; i++) acc[i] = (f32x4){0.f, 0.f, 0.f, 0.f};

  if (p != 2){
    const int n0w = blockIdx.x * 64 + w * 16, o0 = blockIdx.y * 64;
    #pragma unroll
    for (int ks = 0; ks < 8; ks++){
      bf16x8 af = *reinterpret_cast<const bf16x8*>(
          &X[((size_t)(b * N_ + n0w + ln)) * C_ + ks * 32 + g * 8]);
      #pragma unroll
      for (int ot = 0; ot < 4; ot++){
        bf16x8 bf = cvt8(&W[(size_t)(o0 + ot * 16 + ln) * C_ + ks * 32 + g * 8]);
        acc[ot] = __builtin_amdgcn_mfma_f32_16x16x32_bf16(af, bf, acc[ot], 0, 0, 0);
      }
    }
    const float inv = 0.17677669529663687f;
    #pragma unroll
    for (int ot = 0; ot < 4; ot++){
      int o = o0 + ot * 16 + ln;
      float bz = bias[o];
      #pragma unroll
      for (int r = 0; r < 4; r++){
        int n = n0w + g * 4 + r;
        float val = acc[ot][r] + bz;
        if (p == 0){
          val *= inv;
          Y[(((size_t)(b * H_ + (o >> 5))) * N_ + n) * HD_ + (o & 31)] = (__bf16)val;
        } else if (p == 1){
          Y[(((size_t)(b * H_ + (o >> 5))) * N_ + n) * HD_ + (o & 31)] = (__bf16)val;
        } else {
          Y[((size_t)(b * N_ + n)) * C_ + o] = (__bf16)val;
        }
      }
    }
  } else {
    const int o0w = blockIdx.y * 64 + w * 16, n0 = blockIdx.x * 64;
    #pragma unroll
    for (int ks = 0; ks < 8; ks++){
      bf16x8 af = cvt8(&W[(size_t)(o0w + ln) * C_ + ks * 32 + g * 8]);
      #pragma unroll
      for (int nt = 0; nt < 4; nt++){
        bf16x8 bf = *reinterpret_cast<const bf16x8*>(
            &X[((size_t)(b * N_ + n0 + nt * 16 + ln)) * C_ + ks * 32 + g * 8]);
        acc[nt] = __builtin_amdgcn_mfma_f32_16x16x32_bf16(af, bf, acc[nt], 0, 0, 0);
      }
    }
    float bz[4];
    #pragma unroll
    for (int r = 0; r < 4; r++) bz[r] = vb[o0w + g * 4 + r];
    #pragma unroll
    for (int nt = 0; nt < 4; nt++)
      #pragma unroll
      for (int r = 0; r < 4; r++){
        int o = o0w + g * 4 + r, n = n0 + nt * 16 + ln;
        size_t idx = ((size_t)(b * C_ + o)) * N_ + n;
        float val = acc[nt][r] + bz[r];
        if (vfp16) ((_Float16*)Y)[idx] = (_Float16)val;
        else       Y[idx] = (__bf16)val;
      }
  }
}

// ---- row norms from bf16 qdT/kdT -------------------------------------------
__global__ __launch_bounds__(256) void norms_b(const __bf16* __restrict__ qdT,
    const __bf16* __restrict__ kdT, float* __restrict__ qq, float* __restrict__ kk){
  int b = blockIdx.y, n = blockIdx.x * 64 + (threadIdx.x >> 2), part = threadIdx.x & 3;
  size_t base = ((size_t)(b * N_ + n)) * C_ + part * 64;
  float s1 = 0.f, s2 = 0.f;
  #pragma unroll
  for (int i = 0; i < 8; i++){
    bf16x8 a = *reinterpret_cast<const bf16x8*>(&qdT[base + i * 8]);
    bf16x8 d = *reinterpret_cast<const bf16x8*>(&kdT[base + i * 8]);
    #pragma unroll
    for (int j = 0; j < 8; j++){
      float fa = (float)a[j]; s1 += fa * fa;
      float fd = (float)d[j]; s2 += fd * fd;
    }
  }
  s1 += __shfl_xor(s1, 1); s1 += __shfl_xor(s1, 2);
  s2 += __shfl_xor(s2, 1); s2 += __shfl_xor(s2, 2);
  if (part == 0){ qq[b * N_ + n] = s1; kk[b * N_ + n] = s2; }
}

// ---- NEW: feature-dist + spatial-dist -> fsd packed f16x2 (B,N,N) ----------
__global__ __launch_bounds__(256) void pairdist_mfma(const __bf16* __restrict__ qdT,
    const __bf16* __restrict__ kdT, const float* __restrict__ qq,
    const float* __restrict__ kk, const float* __restrict__ xyzA,
    const float* __restrict__ xyzB, unsigned int* __restrict__ fsd){
  const int t = threadIdx.x, w = t >> 6, lane = t & 63, ln = lane & 15, g = lane >> 4;
  const int b = blockIdx.z, n0 = blockIdx.y * 64, n0w = n0 + w * 16, m0 = blockIdx.x * 64;
  __shared__ float4 xa[64], xb[64];
  __shared__ unsigned int sbl[4][16][68];

  if (t < 64){
    const float* p = &xyzA[((size_t)(b * N_ + n0 + t)) * 3];
    xa[t] = make_float4(p[0], p[1], p[2], 0.f);
  } else if (t < 128){
    const float* p = &xyzB[((size_t)(b * N_ + m0 + t - 64)) * 3];
    xb[t - 64] = make_float4(p[0], p[1], p[2], 0.f);
  }
  bf16x8 qfr[8];
  #pragma unroll
  for (int ks = 0; ks < 8; ks++)
    qfr[ks] = *reinterpret_cast<const bf16x8*>(
        &qdT[((size_t)(b * N_ + n0w + ln)) * C_ + ks * 32 + g * 8]);
  float qqv[4];
  #pragma unroll
  for (int r = 0; r < 4; r++) qqv[r] = qq[b * N_ + n0w + g * 4 + r];
  __syncthreads();
  float4 xav[4];
  #pragma unroll
  for (int r = 0; r < 4; r++) xav[r] = xa[w * 16 + g * 4 + r];

  #pragma unroll
  for (int mt = 0; mt < 4; mt++){
    f32x4 a = (f32x4){0.f, 0.f, 0.f, 0.f};
    #pragma unroll
    for (int ks = 0; ks < 8; ks++){
      bf16x8 kfr = *reinterpret_cast<const bf16x8*>(
          &kdT[((size_t)(b * N_ + m0 + mt * 16 + ln)) * C_ + ks * 32 + g * 8]);
      a = __builtin_amdgcn_mfma_f32_16x16x32_bf16(qfr[ks], kfr, a, 0, 0, 0);
    }
    float kkv = kk[b * N_ + m0 + mt * 16 + ln];
    float4 xbv = xb[mt * 16 + ln];
    #pragma unroll
    for (int r = 0; r < 4; r++){
      float d2 = qqv[r] + kkv - 2.f * a[r];
      float fd = sqrtf(fmaxf(d2, 0.f));
      float dx = xav[r].x - xbv.x, dy = xav[r].y - xbv.y, dz = xav[r].z - xbv.z;
      float sd = sqrtf(dx * dx + dy * dy + dz * dz);
      sbl[w][g * 4 + r][mt * 16 + ln] = packh2(fd, sd);
    }
  }
  // per-wave readback (wave-private slice, no block barrier needed)
  #pragma unroll
  for (int it = 0; it < 4; it++){
    int row = it * 4 + (lane >> 4), cq = lane & 15;
    uint4 v = *reinterpret_cast<const uint4*>(&sbl[w][row][cq * 4]);
    *reinterpret_cast<uint4*>(&fsd[((size_t)(b * N_ + n0w + row)) * N_ + m0 + cq * 4]) = v;
  }
}

// ---- NEW: fused dual-path flash attention, barrier-free, in-register P ------
__global__ __launch_bounds__(256) void dual_attn2(
    const __bf16* __restrict__ qpk, const __bf16* __restrict__ kpk,
    const _Float16* __restrict__ vph, const unsigned int* __restrict__ fsd,
    const float* __restrict__ sbw1, const float* __restrict__ sbg, const float* __restrict__ sbb,
    const float* __restrict__ sbm, const float* __restrict__ sbv,
    const float* __restrict__ sbw2, const float* __restrict__ sbb2,
    float* __restrict__ ctxsT, float* __restrict__ ctxdT){
  const int t = threadIdx.x, w = t >> 6, lane = t & 63, ln = lane & 15, g = lane >> 4;
  const int h = blockIdx.y, b = blockIdx.z;
  const int nbase = blockIdx.x * 64 + w * 16;
  const int n = nbase + ln;

  float Ac[4], Bc[4], W2h[4];
  #pragma unroll
  for (int j = 0; j < 4; j++){
    float rs = rsqrtf(sbv[j] + EPSf);
    Ac[j]  = rfl(-sbw1[j] * rs * sbg[j]);
    Bc[j]  = rfl(-sbm[j] * rs * sbg[j] + sbb[j]);
    W2h[j] = rfl(sbw2[h * 4 + j]);
  }
  float C0 = rfl(sbb2[h]);

  bf16x8 qf = *reinterpret_cast<const bf16x8*>(
      &qpk[(((size_t)(b * H_ + h)) * N_ + n) * HD_ + g * 8]);
  const unsigned int* fsdrow = &fsd[((size_t)(b * N_ + n)) * N_];
  const _Float16* vbase = &vph[((size_t)(b * C_ + h * HD_)) * N_];

  f32x4 os[2], od[2];
  #pragma unroll
  for (int i = 0; i < 2; i++){ os[i] = (f32x4){0.f,0.f,0.f,0.f}; od[i] = (f32x4){0.f,0.f,0.f,0.f}; }
  float ms = -3e38f, ls = 0.f, md = -3e38f, ld = 0.f;

  for (int m0 = 0; m0 < N_; m0 += 64){
    // swapped QK^T: lane(ln,g) gets S[n=ln][m = m0+mt*16+g*4+r]
    f32x4 sa[4];
    #pragma unroll
    for (int mt = 0; mt < 4; mt++){
      bf16x8 kf = *reinterpret_cast<const bf16x8*>(
          &kpk[(((size_t)(b * H_ + h)) * N_ + m0 + mt * 16 + ln) * HD_ + g * 8]);
      f32x4 z = (f32x4){0.f, 0.f, 0.f, 0.f};
      sa[mt] = __builtin_amdgcn_mfma_f32_16x16x32_bf16(kf, qf, z, 0, 0, 0);
    }
    float sv[16], dv[16];
    float mxs = -3e38f, mxd = -3e38f;
    #pragma unroll
    for (int mt = 0; mt < 4; mt++){
      uint4 fu = *reinterpret_cast<const uint4*>(&fsdrow[m0 + mt * 16 + g * 4]);
      #pragma unroll
      for (int r = 0; r < 4; r++){
        unsigned int uu = (r == 0) ? fu.x : (r == 1) ? fu.y : (r == 2) ? fu.z : fu.w;
        float fd, sd;
        unpackh2(uu, fd, sd);
        float u0 = fmaxf(fmaf(Ac[0], sd, Bc[0]), 0.f);
        float u1 = fmaxf(fmaf(Ac[1], sd, Bc[1]), 0.f);
        float u2 = fmaxf(fmaf(Ac[2], sd, Bc[2]), 0.f);
        float u3 = fmaxf(fmaf(Ac[3], sd, Bc[3]), 0.f);
        float bias = C0 + W2h[0] * u0 + W2h[1] * u1 + W2h[2] * u2 + W2h[3] * u3;
        float s = sa[mt][r] + bias;
        float d = fd + bias;
        sv[mt * 4 + r] = s; dv[mt * 4 + r] = d;
        mxs = fmaxf(mxs, s); mxd = fmaxf(mxd, d);
      }
    }
    mxs = fmaxf(mxs, __shfl_xor(mxs, 16)); mxs = fmaxf(mxs, __shfl_xor(mxs, 32));
    mxd = fmaxf(mxd, __shfl_xor(mxd, 16)); mxd = fmaxf(mxd, __shfl_xor(mxd, 32));
    float nms = fmaxf(ms, mxs), als = __expf(ms - nms);
    float nmd = fmaxf(md, mxd), ald = __expf(md - nmd);
    f16x4 pAs[4], pAd[4];
    float pss = 0.f, psd = 0.f;
    #pragma unroll
    for (int mt = 0; mt < 4; mt++)
      #pragma unroll
      for (int r = 0; r < 4; r++){
        float pv = __expf(sv[mt * 4 + r] - nms); pss += pv; pAs[mt][r] = (_Float16)pv;
        float qv = __expf(dv[mt * 4 + r] - nmd); psd += qv; pAd[mt][r] = (_Float16)qv;
      }
    pss += __shfl_xor(pss, 16); pss += __shfl_xor(pss, 32);
    psd += __shfl_xor(psd, 16); psd += __shfl_xor(psd, 32);
    ls = ls * als + pss; ms = nms;
    ld = ld * ald + psd; md = nmd;
    // O rows are n' = g*4+r -> fetch that row's rescale factor from lane n'
    float alsr[4], aldr[4];
    #pragma unroll
    for (int r = 0; r < 4; r++){
      alsr[r] = __shfl(als, g * 4 + r);
      aldr[r] = __shfl(ald, g * 4 + r);
    }
    #pragma unroll
    for (int dt = 0; dt < 2; dt++)
      #pragma unroll
      for (int r = 0; r < 4; r++){ os[dt][r] *= alsr[r]; od[dt][r] *= aldr[r]; }
    // PV: P is already the 16x16x16 A-fragment; V fragments from fp16 (B,C,N)
    #pragma unroll
    for (int mt = 0; mt < 4; mt++){
      #pragma unroll
      for (int dt = 0; dt < 2; dt++){
        f16x4 vf = *reinterpret_cast<const f16x4*>(
            &vbase[(size_t)(dt * 16 + ln) * N_ + m0 + mt * 16 + g * 4]);
        os[dt] = __builtin_amdgcn_mfma_f32_16x16x16f16(pAs[mt], vf, os[dt], 0, 0, 0);
        od[dt] = __builtin_amdgcn_mfma_f32_16x16x16f16(pAd[mt], vf, od[dt], 0, 0, 0);
      }
    }
  }
  float is = 1.f / ls, idd = 1.f / ld;
  float isr[4], idr[4];
  #pragma unroll
  for (int r = 0; r < 4; r++){
    isr[r] = __shfl(is, g * 4 + r);
    idr[r] = __shfl(idd, g * 4 + r);
  }
  #pragma unroll
  for (int dt = 0; dt < 2; dt++)
    #pragma unroll
    for (int r = 0; r < 4; r++){
      int nn = nbase + g * 4 + r;
      int ch = h * HD_ + dt * 16 + ln;
      size_t base = ((size_t)(b * N_ + nn)) * C_ + ch;
      ctxsT[base] = os[dt][r] * isr[r];
      ctxdT[base] = od[dt][r] * idr[r];
    }
}

// ================= old-path kernels (ws-size fallback, round-3 exact) =======
__global__ __launch_bounds__(256) void fdist_mfma(const __bf16* __restrict__ qdT,
    const __bf16* __restrict__ kdT, const float* __restrict__ qq,
    const float* __restrict__ kk, _Float16* __restrict__ fdh){
  const int t = threadIdx.x, w = t >> 6, lane = t & 63, ln = lane & 15, g = lane >> 4;
  const int b = blockIdx.z, n0 = blockIdx.y * 64 + w * 16, m0 = blockIdx.x * 64;
  __shared__ _Float16 sbl[4][16][68];

  bf16x8 qfr[8];
  #pragma unroll
  for (int ks = 0; ks < 8; ks++)
    qfr[ks] = *reinterpret_cast<const bf16x8*>(
        &qdT[((size_t)(b * N_ + n0 + ln)) * C_ + ks * 32 + g * 8]);
  float qqv[4];
  #pragma unroll
  for (int r = 0; r < 4; r++) qqv[r] = qq[b * N_ + n0 + g * 4 + r];

  #pragma unroll
  for (int mt = 0; mt < 4; mt++){
    f32x4 a = (f32x4){0.f, 0.f, 0.f, 0.f};
    #pragma unroll
    for (int ks = 0; ks < 8; ks++){
      bf16x8 kfr = *reinterpret_cast<const bf16x8*>(
          &kdT[((size_t)(b * N_ + m0 + mt * 16 + ln)) * C_ + ks * 32 + g * 8]);
      a = __builtin_amdgcn_mfma_f32_16x16x32_bf16(qfr[ks], kfr, a, 0, 0, 0);
    }
    float kkv = kk[b * N_ + m0 + mt * 16 + ln];
    #pragma unroll
    for (int r = 0; r < 4; r++){
      float d2 = qqv[r] + kkv - 2.f * a[r];
      sbl[w][g * 4 + r][mt * 16 + ln] = (_Float16)sqrtf(fmaxf(d2, 0.f));
    }
  }
  __syncthreads();
  #pragma unroll
  for (int it = 0; it < 8; it++){
    int row = (lane >> 5) + it * 2, colu = lane & 31;
    unsigned int u = *reinterpret_cast<const unsigned int*>(&sbl[w][row][colu * 2]);
    *reinterpret_cast<unsigned int*>(&fdh[((size_t)(b * N_ + n0 + row)) * N_ + m0 + colu * 2]) = u;
  }
}

__global__ __launch_bounds__(256) void dual_attn(
    const __bf16* __restrict__ qpk, const __bf16* __restrict__ kpk, const __bf16* __restrict__ vpk,
    const _Float16* __restrict__ fdh,
    const float* __restrict__ xyzA, const float* __restrict__ xyzB,
    const float* __restrict__ sbw1, const float* __restrict__ sbg, const float* __restrict__ sbb,
    const float* __restrict__ sbm, const float* __restrict__ sbv,
    const float* __restrict__ sbw2, const float* __restrict__ sbb2,
    float* __restrict__ ctxsT, float* __restrict__ ctxdT){
  const int t = threadIdx.x, w = t >> 6, lane = t & 63, ln = lane & 15, g = lane >> 4;
  const int h = blockIdx.y, b = blockIdx.z;
  const int nbase = blockIdx.x * 64 + w * 16;
  const int n = nbase + ln;

  float Ac[4], Bc[4], W2h[4];
  #pragma unroll
  for (int j = 0; j < 4; j++){
    float rs = rsqrtf(sbv[j] + EPSf);
    Ac[j]  = rfl(-sbw1[j] * rs * sbg[j]);
    Bc[j]  = rfl(-sbm[j] * rs * sbg[j] + sbb[j]);
    W2h[j] = rfl(sbw2[h * 4 + j]);
  }
  float C0 = rfl(sbb2[h]);

  bf16x8 qf = *reinterpret_cast<const bf16x8*>(
      &qpk[(((size_t)(b * H_ + h)) * N_ + n) * HD_ + g * 8]);
  float ax = xyzA[((size_t)(b * N_ + n)) * 3 + 0];
  float ay = xyzA[((size_t)(b * N_ + n)) * 3 + 1];
  float az = xyzA[((size_t)(b * N_ + n)) * 3 + 2];
  const _Float16* fdrow = &fdh[((size_t)(b * N_ + n)) * N_];

  f32x4 os[2], od[2];
  #pragma unroll
  for (int i = 0; i < 2; i++){ os[i] = (f32x4){0.f,0.f,0.f,0.f}; od[i] = (f32x4){0.f,0.f,0.f,0.f}; }
  float ms = -3e38f, ls = 0.f, md = -3e38f, ld = 0.f;

  __shared__ __align__(16) float ss[4][16][68];
  __shared__ float4 xbb[4][64];

  for (int m0 = 0; m0 < N_; m0 += 64){
    __syncthreads();
    {
      const float* xp = &xyzB[((size_t)(b * N_ + m0 + lane)) * 3];
      xbb[w][lane] = make_float4(xp[0], xp[1], xp[2], 0.f);
    }
    f32x4 sa[4];
    #pragma unroll
    for (int i = 0; i < 4; i++) sa[i] = (f32x4){0.f, 0.f, 0.f, 0.f};
    #pragma unroll
    for (int mt = 0; mt < 4; mt++){
      bf16x8 kf = *reinterpret_cast<const bf16x8*>(
          &kpk[(((size_t)(b * H_ + h)) * N_ + m0 + mt * 16 + ln) * HD_ + g * 8]);
      sa[mt] = __builtin_amdgcn_mfma_f32_16x16x32_bf16(qf, kf, sa[mt], 0, 0, 0);
    }
    #pragma unroll
    for (int mt = 0; mt < 4; mt++)
      #pragma unroll
      for (int r = 0; r < 4; r++)
        ss[w][g * 4 + r][mt * 16 + ln] = sa[mt][r];
    __syncthreads();

    #pragma unroll
    for (int kh = 0; kh < 2; kh++){
      float s8[8], d8[8];
      {
        float4 A4 = *reinterpret_cast<const float4*>(&ss[w][ln][kh * 32 + g * 8]);
        float4 B4 = *reinterpret_cast<const float4*>(&ss[w][ln][kh * 32 + g * 8 + 4]);
        s8[0]=A4.x; s8[1]=A4.y; s8[2]=A4.z; s8[3]=A4.w;
        s8[4]=B4.x; s8[5]=B4.y; s8[6]=B4.z; s8[7]=B4.w;
      }
      f16x8 fv = *reinterpret_cast<const f16x8*>(&fdrow[m0 + kh * 32 + g * 8]);
      float mxs = -3e38f, mxd = -3e38f;
      #pragma unroll
      for (int j = 0; j < 8; j++){
        float4 xk = xbb[w][kh * 32 + g * 8 + j];
        float dx = ax - xk.x, dy = ay - xk.y, dz = az - xk.z;
        float sd = sqrtf(dx * dx + dy * dy + dz * dz);
        float bias = C0;
        #pragma unroll
        for (int u = 0; u < 4; u++)
          bias += W2h[u] * fmaxf(fmaf(Ac[u], sd, Bc[u]), 0.f);
        s8[j] += bias;
        d8[j] = (float)fv[j] + bias;
        mxs = fmaxf(mxs, s8[j]);
        mxd = fmaxf(mxd, d8[j]);
      }
      mxs = fmaxf(mxs, __shfl_xor(mxs, 16)); mxs = fmaxf(mxs, __shfl_xor(mxs, 32));
      mxd = fmaxf(mxd, __shfl_xor(mxd, 16)); mxd = fmaxf(mxd, __shfl_xor(mxd, 32));
      float nms = fmaxf(ms, mxs), als = __expf(ms - nms);
      float nmd = fmaxf(md, mxd), ald = __expf(md - nmd);
      float pss = 0.f, psd = 0.f;
      bf16x8 pfs, pfd;
      #pragma unroll
      for (int j = 0; j < 8; j++){
        float pv = __expf(s8[j] - nms); pss += pv; pfs[j] = (__bf16)pv;
        float qv = __expf(d8[j] - nmd); psd += qv; pfd[j] = (__bf16)qv;
      }
      pss += __shfl_xor(pss, 16); pss += __shfl_xor(pss, 32);
      psd += __shfl_xor(psd, 16); psd += __shfl_xor(psd, 32);
      ls = ls * als + pss; ms = nms;
      ld = ld * ald + psd; md = nmd;
      os[0] *= als; os[1] *= als; od[0] *= ald; od[1] *= ald;
      #pragma unroll
      for (int dt = 0; dt < 2; dt++){
        bf16x8 vf = *reinterpret_cast<const bf16x8*>(
            &vpk[((size_t)(b * C_ + h * HD_ + dt * 16 + ln)) * N_ + m0 + kh * 32 + g * 8]);
        os[dt] = __builtin_amdgcn_mfma_f32_16x16x32_bf16(vf, pfs, os[dt], 0, 0, 0);
        od[dt] = __builtin_amdgcn_mfma_f32_16x16x32_bf16(vf, pfd, od[dt], 0, 0, 0);
      }
    }
  }
  float is = 1.f / ls, idv = 1.f / ld;
  #pragma unroll
  for (int dt = 0; dt < 2; dt++)
    #pragma unroll
    for (int r = 0; r < 4; r++){
      int ch = h * HD_ + dt * 16 + g * 4 + r;
      size_t base = ((size_t)(b * N_ + n)) * C_ + ch;
      ctxsT[base] = os[dt][r] * is;
      ctxdT[base] = od[dt][r] * idv;
    }
}

// ---- LN of ctx (rows contiguous) -> bf16 ------------------------------------
__global__ __launch_bounds__(256) void ln_ctx(const float* __restrict__ ctxsT,
    const float* __restrict__ ctxdT, __bf16* __restrict__ csLN, __bf16* __restrict__ cdLN,
    const float* __restrict__ lsg, const float* __restrict__ lsb,
    const float* __restrict__ ldg, const float* __restrict__ ldb){
  const float* src = blockIdx.y ? ctxdT : ctxsT;
  __bf16* dst = blockIdx.y ? cdLN : csLN;
  const float* gg = blockIdx.y ? ldg : lsg;
  const float* bb = blockIdx.y ? ldb : lsb;
  int w = threadIdx.x >> 6, lane = threadIdx.x & 63;
  size_t row = (size_t)blockIdx.x * 4 + w;
  float4 v = *reinterpret_cast<const float4*>(&src[row * C_ + lane * 4]);
  float s1 = v.x + v.y + v.z + v.w;
  float s2 = v.x * v.x + v.y * v.y + v.z * v.z + v.w * v.w;
  #pragma unroll
  for (int off = 1; off < 64; off <<= 1){
    s1 += __shfl_xor(s1, off);
    s2 += __shfl_xor(s2, off);
  }
  float m = s1 / (float)C_;
  float rs = rsqrtf(s2 / (float)C_ - m * m + EPSf);
  float4 g4 = *reinterpret_cast<const float4*>(&gg[lane * 4]);
  float4 b4 = *reinterpret_cast<const float4*>(&bb[lane * 4]);
  alignas(8) __bf16 o4[4];
  o4[0] = (__bf16)((v.x - m) * rs * g4.x + b4.x);
  o4[1] = (__bf16)((v.y - m) * rs * g4.y + b4.y);
  o4[2] = (__bf16)((v.z - m) * rs * g4.z + b4.z);
  o4[3] = (__bf16)((v.w - m) * rs * g4.w + b4.w);
  *reinterpret_cast<uint2*>(&dst[row * C_ + lane * 4]) = *reinterpret_cast<uint2*>(o4);
}

// ---- fusion stage 1 ---------------------------------------------------------
__global__ __launch_bounds__(256) void fusion1_mfma(const __bf16* __restrict__ fanT,
    const __bf16* __restrict__ csLN, const __bf16* __restrict__ cdLN,
    __bf16* __restrict__ X1T, const float* __restrict__ fw1,
    const float* __restrict__ fbg, const float* __restrict__ fbb,
    const float* __restrict__ fbm, const float* __restrict__ fbv){
  const int t = threadIdx.x, w = t >> 6, lane = t & 63, ln = lane & 15, g = lane >> 4;
  const int b = blockIdx.z, o0 = blockIdx.y * 64, n0w = blockIdx.x * 64 + w * 16;
  f32x4 acc[4];
  #pragma unroll
  for (int i = 0; i < 4; i++) acc[i] = (f32x4){0.f, 0.f, 0.f, 0.f};
  const __bf16* segs[3] = {fanT, csLN, cdLN};
  #pragma unroll
  for (int ks = 0; ks < 24; ks++){
    const __bf16* base = segs[ks >> 3];
    int coff = (ks & 7) * 32 + g * 8;
    bf16x8 af = *reinterpret_cast<const bf16x8*>(
        &base[((size_t)(b * N_ + n0w + ln)) * C_ + coff]);
    #pragma unroll
    for (int ot = 0; ot < 4; ot++){
      bf16x8 bf = cvt8(&fw1[(size_t)(o0 + ot * 16 + ln) * (3 * C_) + ks * 32 + g * 8]);
      acc[ot] = __builtin_amdgcn_mfma_f32_16x16x32_bf16(af, bf, acc[ot], 0, 0, 0);
    }
  }
  #pragma unroll
  for (int ot = 0; ot < 4; ot++){
    int o = o0 + ot * 16 + ln;
    float mn = fbm[o], rs = rsqrtf(fbv[o] + EPSf), gg = fbg[o], be = fbb[o];
    #pragma unroll
    for (int r = 0; r < 4; r++){
      int n = n0w + g * 4 + r;
      float x = (acc[ot][r] - mn) * rs * gg + be;
      X1T[((size_t)(b * N_ + n)) * (2 * C_) + o] = (__bf16)fmaxf(x, 0.f);
    }
  }
}

// ---- fusion stage 2 ---------------------------------------------------------
__global__ __launch_bounds__(256) void fusion2_mfma(const __bf16* __restrict__ X1T,
    const float* __restrict__ fw2, const float* __restrict__ fb2,
    const float* __restrict__ featA, float* __restrict__ out){
  const int t = threadIdx.x, w = t >> 6, lane = t & 63, ln = lane & 15, g = lane >> 4;
  const int b = blockIdx.z, o0w = blockIdx.y * 64 + w * 16, n0 = blockIdx.x * 64;
  f32x4 acc[4];
  #pragma unroll
  for (int i = 0; i < 4; i++) acc[i] = (f32x4){0.f, 0.f, 0.f, 0.f};
  #pragma unroll
  for (int ks = 0; ks < 16; ks++){
    bf16x8 af = cvt8(&fw2[(size_t)(o0w + ln) * (2 * C_) + ks * 32 + g * 8]);
    #pragma unroll
    for (int nt = 0; nt < 4; nt++){
      bf16x8 bf = *reinterpret_cast<const bf16x8*>(
          &X1T[((size_t)(b * N_ + n0 + nt * 16 + ln)) * (2 * C_) + ks * 32 + g * 8]);
      acc[nt] = __builtin_amdgcn_mfma_f32_16x16x32_bf16(af, bf, acc[nt], 0, 0, 0);
    }
  }
  float bz[4];
  #pragma unroll
  for (int r = 0; r < 4; r++) bz[r] = fb2[o0w + g * 4 + r];
  #pragma unroll
  for (int nt = 0; nt < 4; nt++)
    #pragma unroll
    for (int r = 0; r < 4; r++){
      int o = o0w + g * 4 + r, n = n0 + nt * 16 + ln;
      size_t oi = ((size_t)(b * C_ + o)) * N_ + n;
      out[oi] = acc[nt][r] + bz[r] + featA[oi];
    }
}

extern "C" void kernel_launch(void* const* d_in, const int* in_sizes, int n_in,
                              void* d_out, int out_size, void* d_ws, size_t ws_size,
                              hipStream_t stream){
  (void)in_sizes; (void)n_in; (void)out_size;
  if (ws_size < WS_NEED) return;

  const float* xyzA  = (const float*)d_in[0];
  const float* featA = (const float*)d_in[1];
  const float* xyzB  = (const float*)d_in[2];
  const float* featB = (const float*)d_in[3];
  const float* qw  = (const float*)d_in[4];   const float* qb  = (const float*)d_in[5];
  const float* kw  = (const float*)d_in[6];   const float* kb  = (const float*)d_in[7];
  const float* vw  = (const float*)d_in[8];   const float* vb  = (const float*)d_in[9];
  const float* sbw1= (const float*)d_in[10];  const float* sbg = (const float*)d_in[11];
  const float* sbb = (const float*)d_in[12];  const float* sbm = (const float*)d_in[13];
  const float* sbv = (const float*)d_in[14];  const float* sbw2= (const float*)d_in[15];
  const float* sbb2= (const float*)d_in[16];
  const float* qdw = (const float*)d_in[17];  const float* qdb = (const float*)d_in[18];
  const float* kdw = (const float*)d_in[19];  const float* kdb = (const float*)d_in[20];
  const float* ling= (const float*)d_in[21];  const float* linb= (const float*)d_in[22];
  const float* lsg = (const float*)d_in[23];  const float* lsb = (const float*)d_in[24];
  const float* ldg = (const float*)d_in[25];  const float* ldb = (const float*)d_in[26];
  const float* fw1 = (const float*)d_in[27];  const float* fbg = (const float*)d_in[28];
  const float* fbb = (const float*)d_in[29];  const float* fbm = (const float*)d_in[30];
  const float* fbv = (const float*)d_in[31];  const float* fw2 = (const float*)d_in[32];
  const float* fb2 = (const float*)d_in[33];

  char* ws = (char*)d_ws;
  __bf16*   fanT = (__bf16*)(ws + OFF_FANT);
  __bf16*   fbT  = (__bf16*)(ws + OFF_FBT);
  __bf16*   qpk  = (__bf16*)(ws + OFF_QPK);
  __bf16*   kpk  = (__bf16*)(ws + OFF_KPK);
  __bf16*   qdT  = (__bf16*)(ws + OFF_QDT);
  __bf16*   kdT  = (__bf16*)(ws + OFF_KDT);
  float*    qq   = (float*)(ws + OFF_QQ);
  float*    kk   = (float*)(ws + OFF_KK);
  float*    out  = (float*)d_out;

  bool big = (ws_size >= WS_NEED2);

  lnA_pack<<<dim3(N_ / 32, B_), 256, 0, stream>>>(featA, fanT, ling, linb);
  packT_kernel<<<dim3(N_ / 64, C_ / 64, B_), 256, 0, stream>>>(featB, fbT);
  proj_mfma<<<dim3(N_ / 64, C_ / 64, 5 * B_), 256, 0, stream>>>(
      fanT, fbT, fanT, big ? 1 : 0, qw, qb, kw, kb, vw, vb, qdw, qdb, kdw, kdb);
  norms_b<<<dim3(N_ / 64, B_), 256, 0, stream>>>(qdT, kdT, qq, kk);

  if (big){
    _Float16*     vph  = (_Float16*)(ws + OFF_VPK);
    unsigned int* fsd  = (unsigned int*)(ws + OFF_FSD);
    float*  ctxsT = (float*)(ws + OFF2_CTXS);
    float*  ctxdT = (float*)(ws + OFF2_CTXD);
    __bf16* csLN  = (__bf16*)(ws + OFF2_CSLN);
    __bf16* cdLN  = (__bf16*)(ws + OFF2_CDLN);
    __bf16* X1T   = (__bf16*)(ws + OFF2_X1T);
    pairdist_mfma<<<dim3(N_ / 64, N_ / 64, B_), 256, 0, stream>>>(
        qdT, kdT, qq, kk, xyzA, xyzB, fsd);
    dual_attn2<<<dim3(N_ / 64, H_, B_), 256, 0, stream>>>(
        qpk, kpk, vph, fsd, sbw1, sbg, sbb, sbm, sbv, sbw2, sbb2, ctxsT, ctxdT);
    ln_ctx<<<dim3(B_ * N_ / 4, 2), 256, 0, stream>>>(
        ctxsT, ctxdT, csLN, cdLN, lsg, lsb, ldg, ldb);
    fusion1_mfma<<<dim3(N_ / 64, (2 * C_) / 64, B_), 256, 0, stream>>>(
        fanT, csLN, cdLN, X1T, fw1, fbg, fbb, fbm, fbv);
    fusion2_mfma<<<dim3(N_ / 64, C_ / 64, B_), 256, 0, stream>>>(
        X1T, fw2, fb2, featA, out);
  } else {
    __bf16*   vpk  = (__bf16*)(ws + OFF_VPK);
    _Float16* fdh  = (_Float16*)(ws + OFF_FDH);
    float*  ctxsT = (float*)(ws + OFF_CTXS);
    float*  ctxdT = (float*)(ws + OFF_CTXD);
    __bf16* csLN  = (__bf16*)(ws + OFF_CSLN);
    __bf16* cdLN  = (__bf16*)(ws + OFF_CDLN);
    __bf16* X1T   = (__bf16*)(ws + OFF_X1T);
    fdist_mfma<<<dim3(N_ / 64, N_ / 64, B_), 256, 0, stream>>>(qdT, kdT, qq, kk, fdh);
    dual_attn<<<dim3(N_ / 64, H_, B_), 256, 0, stream>>>(
        qpk, kpk, vpk, fdh, xyzA, xyzB,
        sbw1, sbg, sbb, sbm, sbv, sbw2, sbb2, ctxsT, ctxdT);
    ln_ctx<<<dim3(B_ * N_ / 4, 2), 256, 0, stream>>>(
        ctxsT, ctxdT, csLN, cdLN, lsg, lsb, ldg, ldb);
    fusion1_mfma<<<dim3(N_ / 64, (2 * C_) / 64, B_), 256, 0, stream>>>(
        fanT, csLN, cdLN, X1T, fw1, fbg, fbb, fbm, fbv);
    fusion2_mfma<<<dim3(N_ / 64, C_ / 64, B_), 256, 0, stream>>>(
        X1T, fw2, fb2, featA, out);
  }
}

// Round 5
// 270.883 us; speedup vs baseline: 4.2697x; 1.0746x over previous
//
#include <hip/hip_runtime.h>

#define B_ 2
#define N_ 2048
#define C_ 256
#define H_ 8
#define HD_ 32
#define EPSf 1e-5f

typedef __bf16   bf16x8 __attribute__((ext_vector_type(8)));
typedef float    f32x4  __attribute__((ext_vector_type(4)));
typedef _Float16 f16x8  __attribute__((ext_vector_type(8)));
typedef _Float16 f16x4  __attribute__((ext_vector_type(4)));
typedef _Float16 f16x2  __attribute__((ext_vector_type(2)));

// ---- workspace layout (byte offsets) ---------------------------------------
static constexpr size_t MB_ = 1024 * 1024;
static constexpr size_t OFF_FANT = 0;                    // bf16 (B,N,C)   2MB
static constexpr size_t OFF_FBT  = 2 * MB_;              // bf16 (B,N,C)   2MB
static constexpr size_t OFF_QPK  = 4 * MB_;              // bf16 (B,H,N,HD) 2MB
static constexpr size_t OFF_KPK  = 6 * MB_;              // bf16 (B,H,N,HD) 2MB
static constexpr size_t OFF_VPK  = 8 * MB_;              // bf16/f16 (B,C,N) 2MB
static constexpr size_t OFF_QDT  = 10 * MB_;             // bf16 (B,N,C)   2MB
static constexpr size_t OFF_KDT  = 12 * MB_;             // bf16 (B,N,C)   2MB
static constexpr size_t OFF_QQ   = 14 * MB_;             // f32 (B,N)
static constexpr size_t OFF_KK   = 14 * MB_ + 16 * 1024; // f32 (B,N)
static constexpr size_t OFF_FDH  = 14 * MB_ + 64 * 1024; // old path fp16 (B,N,N)
static constexpr size_t OFF_FSD  = 14 * MB_ + 64 * 1024; // new path uint (B,N,N) 32MB -> ends 46.06MB
// old-path (47MB) tail
static constexpr size_t OFF_CTXS = 31 * MB_;
static constexpr size_t OFF_CTXD = 35 * MB_;
static constexpr size_t OFF_CSLN = 39 * MB_;
static constexpr size_t OFF_CDLN = 41 * MB_;
static constexpr size_t OFF_X1T  = 43 * MB_;
static constexpr size_t WS_NEED  = 47 * MB_;
// new-path (63MB): partials + stats after fsd; LN/X1T overlay the dead fsd region
static constexpr size_t OFF2_PART  = 47 * MB_;  // f16 [path2][split2][B][N][C] = 8MB -> 47..55
static constexpr size_t OFF2_STATM = 55 * MB_;  // f32 [path2][split2][B][H][N] = 1MB -> 55..56
static constexpr size_t OFF2_STATL = 56 * MB_;  // f32 same                      -> 56..57
static constexpr size_t OFF2_CSLN  = 15 * MB_;  // bf16 (B,N,C) 2MB (overlay fsd)
static constexpr size_t OFF2_CDLN  = 17 * MB_;  // bf16 (B,N,C) 2MB (overlay fsd)
static constexpr size_t OFF2_X1T   = 19 * MB_;  // bf16 (B,N,2C) 4MB (overlay fsd)
static constexpr size_t WS_NEED2   = 63 * MB_;

__device__ __forceinline__ float rfl(float x){
  return __uint_as_float(__builtin_amdgcn_readfirstlane(__float_as_uint(x)));
}
__device__ __forceinline__ bf16x8 cvt8(const float* p){
  float4 a = *reinterpret_cast<const float4*>(p);
  float4 c = *reinterpret_cast<const float4*>(p + 4);
  bf16x8 r;
  r[0]=(__bf16)a.x; r[1]=(__bf16)a.y; r[2]=(__bf16)a.z; r[3]=(__bf16)a.w;
  r[4]=(__bf16)c.x; r[5]=(__bf16)c.y; r[6]=(__bf16)c.z; r[7]=(__bf16)c.w;
  return r;
}
__device__ __forceinline__ unsigned int packh2(float lo, float hi){
  f16x2 h; h[0] = (_Float16)lo; h[1] = (_Float16)hi;
  return __builtin_bit_cast(unsigned int, h);
}
__device__ __forceinline__ void unpackh2(unsigned int u, float& lo, float& hi){
  f16x2 h = __builtin_bit_cast(f16x2, u);
  lo = (float)h[0]; hi = (float)h[1];
}

// ---- LN(featA) over channels -> fanT bf16 (B,N,C) ---------------------------
__global__ __launch_bounds__(256) void lnA_pack(const float* __restrict__ featA,
    __bf16* __restrict__ fanT, const float* __restrict__ gam, const float* __restrict__ bet){
  int b = blockIdx.y, n0 = blockIdx.x * 32;
  int t = threadIdx.x, nl = t & 31, cg = t >> 5;
  __shared__ float tile[256][33];
  __shared__ float red1[8][32], red2[8][32], mus[32], rss[32];
  __shared__ float gsh[256], bsh[256];
  gsh[t] = gam[t]; bsh[t] = bet[t];
  #pragma unroll
  for (int i = 0; i < 32; i++){
    int c = cg * 32 + i;
    tile[c][nl] = featA[((size_t)(b * C_ + c)) * N_ + n0 + nl];
  }
  __syncthreads();
  float s1 = 0.f, s2 = 0.f;
  #pragma unroll
  for (int i = 0; i < 32; i++){
    float v = tile[cg * 32 + i][nl];
    s1 += v; s2 += v * v;
  }
  red1[cg][nl] = s1; red2[cg][nl] = s2;
  __syncthreads();
  if (t < 32){
    float a = 0.f, q = 0.f;
    #pragma unroll
    for (int i = 0; i < 8; i++){ a += red1[i][t]; q += red2[i][t]; }
    float m = a / (float)C_;
    mus[t] = m; rss[t] = rsqrtf(q / (float)C_ - m * m + EPSf);
  }
  __syncthreads();
  float mu = mus[nl], rs = rss[nl];
  size_t obase = ((size_t)(b * N_ + n0 + nl)) * C_;
  #pragma unroll
  for (int i = 0; i < 32; i++){
    int c = cg * 32 + i;
    fanT[obase + c] = (__bf16)((tile[c][nl] - mu) * rs * gsh[c] + bsh[c]);
  }
}

// ---- featB (B,C,N) fp32 -> fbT (B,N,C) bf16 ---------------------------------
__global__ __launch_bounds__(256) void packT_kernel(const float* __restrict__ featB,
    __bf16* __restrict__ fbT){
  int b = blockIdx.z, c0 = blockIdx.y * 64, n0 = blockIdx.x * 64;
  int t = threadIdx.x;
  __shared__ float tile[64][65];
  int cl = t >> 6, nl = t & 63;
  #pragma unroll
  for (int i = 0; i < 16; i++)
    tile[i * 4 + cl][nl] = featB[((size_t)(b * C_ + c0 + i * 4 + cl)) * N_ + n0 + nl];
  __syncthreads();
  int nr = t >> 2, cc = (t & 3) * 16;
  alignas(16) __bf16 tmp[16];
  #pragma unroll
  for (int j = 0; j < 16; j++) tmp[j] = (__bf16)tile[cc + j][nr];
  size_t d = ((size_t)(b * N_ + n0 + nr)) * C_ + c0 + cc;
  *reinterpret_cast<uint4*>(&fbT[d])     = *reinterpret_cast<uint4*>(&tmp[0]);
  *reinterpret_cast<uint4*>(&fbT[d + 8]) = *reinterpret_cast<uint4*>(&tmp[8]);
}

// ---- 5 projection GEMMs, bf16 MFMA -----------------------------------------
__global__ __launch_bounds__(256) void proj_mfma(const __bf16* __restrict__ fanT,
    const __bf16* __restrict__ fbT, __bf16* __restrict__ wsh, int vfp16,
    const float* __restrict__ qw, const float* __restrict__ qb,
    const float* __restrict__ kw, const float* __restrict__ kb,
    const float* __restrict__ vw, const float* __restrict__ vb,
    const float* __restrict__ qdw, const float* __restrict__ qdb,
    const float* __restrict__ kdw, const float* __restrict__ kdb){
  const int p = blockIdx.z % 5, b = blockIdx.z / 5;
  const int t = threadIdx.x, w = t >> 6, lane = t & 63, ln = lane & 15, g = lane >> 4;
  const float *W, *bias;
  const __bf16* X;
  __bf16* Y;
  if (p == 0)      { W = qw;  bias = qb;  X = fanT; Y = wsh + (OFF_QPK - OFF_FANT) / 2; }
  else if (p == 1) { W = kw;  bias = kb;  X = fbT;  Y = wsh + (OFF_KPK - OFF_FANT) / 2; }
  else if (p == 2) { W = vw;  bias = vb;  X = fbT;  Y = wsh + (OFF_VPK - OFF_FANT) / 2; }
  else if (p == 3) { W = qdw; bias = qdb; X = fanT; Y = wsh + (OFF_QDT - OFF_FANT) / 2; }
  else             { W = kdw; bias = kdb; X = fbT;  Y = wsh + (OFF_KDT - OFF_FANT) / 2; }

  f32x4 acc[4];
  #pragma unroll
  for (int i = 0; i < 4; i++) acc[i] = (f32x4){0.f, 0.f, 0.f, 0.f};

  if (p != 2){
    const int n0w = blockIdx.x * 64 + w * 16, o0 = blockIdx.y * 64;
    #pragma unroll
    for (int ks = 0; ks < 8; ks++){
      bf16x8 af = *reinterpret_cast<const bf16x8*>(
          &X[((size_t)(b * N_ + n0w + ln)) * C_ + ks * 32 + g * 8]);
      #pragma unroll
      for (int ot = 0; ot < 4; ot++){
        bf16x8 bf = cvt8(&W[(size_t)(o0 + ot * 16 + ln) * C_ + ks * 32 + g * 8]);
        acc[ot] = __builtin_amdgcn_mfma_f32_16x16x32_bf16(af, bf, acc[ot], 0, 0, 0);
      }
    }
    const float inv = 0.17677669529663687f;
    #pragma unroll
    for (int ot = 0; ot < 4; ot++){
      int o = o0 + ot * 16 + ln;
      float bz = bias[o];
      #pragma unroll
      for (int r = 0; r < 4; r++){
        int n = n0w + g * 4 + r;
        float val = acc[ot][r] + bz;
        if (p == 0){
          val *= inv;
          Y[(((size_t)(b * H_ + (o >> 5))) * N_ + n) * HD_ + (o & 31)] = (__bf16)val;
        } else if (p == 1){
          Y[(((size_t)(b * H_ + (o >> 5))) * N_ + n) * HD_ + (o & 31)] = (__bf16)val;
        } else {
          Y[((size_t)(b * N_ + n)) * C_ + o] = (__bf16)val;
        }
      }
    }
  } else {
    const int o0w = blockIdx.y * 64 + w * 16, n0 = blockIdx.x * 64;
    #pragma unroll
    for (int ks = 0; ks < 8; ks++){
      bf16x8 af = cvt8(&W[(size_t)(o0w + ln) * C_ + ks * 32 + g * 8]);
      #pragma unroll
      for (int nt = 0; nt < 4; nt++){
        bf16x8 bf = *reinterpret_cast<const bf16x8*>(
            &X[((size_t)(b * N_ + n0 + nt * 16 + ln)) * C_ + ks * 32 + g * 8]);
        acc[nt] = __builtin_amdgcn_mfma_f32_16x16x32_bf16(af, bf, acc[nt], 0, 0, 0);
      }
    }
    float bz[4];
    #pragma unroll
    for (int r = 0; r < 4; r++) bz[r] = vb[o0w + g * 4 + r];
    #pragma unroll
    for (int nt = 0; nt < 4; nt++)
      #pragma unroll
      for (int r = 0; r < 4; r++){
        int o = o0w + g * 4 + r, n = n0 + nt * 16 + ln;
        size_t idx = ((size_t)(b * C_ + o)) * N_ + n;
        float val = acc[nt][r] + bz[r];
        if (vfp16) ((_Float16*)Y)[idx] = (_Float16)val;
        else       Y[idx] = (__bf16)val;
      }
  }
}

// ---- row norms from bf16 qdT/kdT -------------------------------------------
__global__ __launch_bounds__(256) void norms_b(const __bf16* __restrict__ qdT,
    const __bf16* __restrict__ kdT, float* __restrict__ qq, float* __restrict__ kk){
  int b = blockIdx.y, n = blockIdx.x * 64 + (threadIdx.x >> 2), part = threadIdx.x & 3;
  size_t base = ((size_t)(b * N_ + n)) * C_ + part * 64;
  float s1 = 0.f, s2 = 0.f;
  #pragma unroll
  for (int i = 0; i < 8; i++){
    bf16x8 a = *reinterpret_cast<const bf16x8*>(&qdT[base + i * 8]);
    bf16x8 d = *reinterpret_cast<const bf16x8*>(&kdT[base + i * 8]);
    #pragma unroll
    for (int j = 0; j < 8; j++){
      float fa = (float)a[j]; s1 += fa * fa;
      float fd = (float)d[j]; s2 += fd * fd;
    }
  }
  s1 += __shfl_xor(s1, 1); s1 += __shfl_xor(s1, 2);
  s2 += __shfl_xor(s2, 1); s2 += __shfl_xor(s2, 2);
  if (part == 0){ qq[b * N_ + n] = s1; kk[b * N_ + n] = s2; }
}

// ---- feature-dist + spatial-dist -> fsd packed f16x2 (B,N,N) ---------------
__global__ __launch_bounds__(256) void pairdist_mfma(const __bf16* __restrict__ qdT,
    const __bf16* __restrict__ kdT, const float* __restrict__ qq,
    const float* __restrict__ kk, const float* __restrict__ xyzA,
    const float* __restrict__ xyzB, unsigned int* __restrict__ fsd){
  const int t = threadIdx.x, w = t >> 6, lane = t & 63, ln = lane & 15, g = lane >> 4;
  const int b = blockIdx.z, n0 = blockIdx.y * 64, n0w = n0 + w * 16, m0 = blockIdx.x * 64;
  __shared__ float4 xa[64], xb[64];
  __shared__ unsigned int sbl[4][16][68];

  if (t < 64){
    const float* p = &xyzA[((size_t)(b * N_ + n0 + t)) * 3];
    xa[t] = make_float4(p[0], p[1], p[2], 0.f);
  } else if (t < 128){
    const float* p = &xyzB[((size_t)(b * N_ + m0 + t - 64)) * 3];
    xb[t - 64] = make_float4(p[0], p[1], p[2], 0.f);
  }
  bf16x8 qfr[8];
  #pragma unroll
  for (int ks = 0; ks < 8; ks++)
    qfr[ks] = *reinterpret_cast<const bf16x8*>(
        &qdT[((size_t)(b * N_ + n0w + ln)) * C_ + ks * 32 + g * 8]);
  float qqv[4];
  #pragma unroll
  for (int r = 0; r < 4; r++) qqv[r] = qq[b * N_ + n0w + g * 4 + r];
  __syncthreads();
  float4 xav[4];
  #pragma unroll
  for (int r = 0; r < 4; r++) xav[r] = xa[w * 16 + g * 4 + r];

  #pragma unroll
  for (int mt = 0; mt < 4; mt++){
    f32x4 a = (f32x4){0.f, 0.f, 0.f, 0.f};
    #pragma unroll
    for (int ks = 0; ks < 8; ks++){
      bf16x8 kfr = *reinterpret_cast<const bf16x8*>(
          &kdT[((size_t)(b * N_ + m0 + mt * 16 + ln)) * C_ + ks * 32 + g * 8]);
      a = __builtin_amdgcn_mfma_f32_16x16x32_bf16(qfr[ks], kfr, a, 0, 0, 0);
    }
    float kkv = kk[b * N_ + m0 + mt * 16 + ln];
    float4 xbv = xb[mt * 16 + ln];
    #pragma unroll
    for (int r = 0; r < 4; r++){
      float d2 = qqv[r] + kkv - 2.f * a[r];
      float fd = sqrtf(fmaxf(d2, 0.f));
      float dx = xav[r].x - xbv.x, dy = xav[r].y - xbv.y, dz = xav[r].z - xbv.z;
      float sd = sqrtf(dx * dx + dy * dy + dz * dz);
      sbl[w][g * 4 + r][mt * 16 + ln] = packh2(fd, sd);
    }
  }
  #pragma unroll
  for (int it = 0; it < 4; it++){
    int row = it * 4 + (lane >> 4), cq = lane & 15;
    uint4 v = *reinterpret_cast<const uint4*>(&sbl[w][row][cq * 4]);
    *reinterpret_cast<uint4*>(&fsd[((size_t)(b * N_ + n0w + row)) * N_ + m0 + cq * 4]) = v;
  }
}

// ---- NEW: dual-path flash attention, m-split + prefetch, partial outputs ----
struct TileRegs { uint4 fu[4]; bf16x8 kf[4]; };

__device__ __forceinline__ void load_tile(TileRegs& T, const __bf16* kbase,
    const unsigned int* fsdrow, int m0, int ln, int g){
  #pragma unroll
  for (int mt = 0; mt < 4; mt++){
    T.fu[mt] = *reinterpret_cast<const uint4*>(&fsdrow[m0 + mt * 16 + g * 4]);
    T.kf[mt] = *reinterpret_cast<const bf16x8*>(&kbase[(size_t)(m0 + mt * 16 + ln) * HD_ + g * 8]);
  }
}

__device__ __forceinline__ void compute_tile(const TileRegs& T,
    const _Float16* vbase, int m0, int ln, int g, bf16x8 qf,
    const float* Ac, const float* Bc, const float* W2h, float C0,
    f32x4* os, f32x4* od, float& ms, float& ls, float& md, float& ld){
  f32x4 sa[4];
  #pragma unroll
  for (int mt = 0; mt < 4; mt++){
    f32x4 z = (f32x4){0.f, 0.f, 0.f, 0.f};
    sa[mt] = __builtin_amdgcn_mfma_f32_16x16x32_bf16(T.kf[mt], qf, z, 0, 0, 0);
  }
  // V loads issued early; consumed at the end of the tile
  f16x4 vf[2][4];
  #pragma unroll
  for (int mt = 0; mt < 4; mt++)
    #pragma unroll
    for (int dt = 0; dt < 2; dt++)
      vf[dt][mt] = *reinterpret_cast<const f16x4*>(
          &vbase[(size_t)(dt * 16 + ln) * N_ + m0 + mt * 16 + g * 4]);
  f32x4 dvv[4];
  float mxs = -3e38f, mxd = -3e38f;
  #pragma unroll
  for (int mt = 0; mt < 4; mt++){
    #pragma unroll
    for (int r = 0; r < 4; r++){
      unsigned int uu = (r == 0) ? T.fu[mt].x : (r == 1) ? T.fu[mt].y
                      : (r == 2) ? T.fu[mt].z : T.fu[mt].w;
      float fd, sd;
      unpackh2(uu, fd, sd);
      float u0 = fmaxf(fmaf(Ac[0], sd, Bc[0]), 0.f);
      float u1 = fmaxf(fmaf(Ac[1], sd, Bc[1]), 0.f);
      float u2 = fmaxf(fmaf(Ac[2], sd, Bc[2]), 0.f);
      float u3 = fmaxf(fmaf(Ac[3], sd, Bc[3]), 0.f);
      float bias = C0 + W2h[0] * u0 + W2h[1] * u1 + W2h[2] * u2 + W2h[3] * u3;
      float s = sa[mt][r] + bias;
      float d = fd + bias;
      sa[mt][r] = s; dvv[mt][r] = d;
      mxs = fmaxf(mxs, s); mxd = fmaxf(mxd, d);
    }
  }
  mxs = fmaxf(mxs, __shfl_xor(mxs, 16)); mxs = fmaxf(mxs, __shfl_xor(mxs, 32));
  mxd = fmaxf(mxd, __shfl_xor(mxd, 16)); mxd = fmaxf(mxd, __shfl_xor(mxd, 32));
  float nms = fmaxf(ms, mxs), als = __expf(ms - nms);
  float nmd = fmaxf(md, mxd), ald = __expf(md - nmd);
  f16x4 pAs[4], pAd[4];
  float pss = 0.f, psd = 0.f;
  #pragma unroll
  for (int mt = 0; mt < 4; mt++)
    #pragma unroll
    for (int r = 0; r < 4; r++){
      float pv = __expf(sa[mt][r] - nms); pss += pv; pAs[mt][r] = (_Float16)pv;
      float qv = __expf(dvv[mt][r] - nmd); psd += qv; pAd[mt][r] = (_Float16)qv;
    }
  pss += __shfl_xor(pss, 16); pss += __shfl_xor(pss, 32);
  psd += __shfl_xor(psd, 16); psd += __shfl_xor(psd, 32);
  ls = ls * als + pss; ms = nms;
  ld = ld * ald + psd; md = nmd;
  float alsr[4], aldr[4];
  #pragma unroll
  for (int r = 0; r < 4; r++){
    alsr[r] = __shfl(als, g * 4 + r);
    aldr[r] = __shfl(ald, g * 4 + r);
  }
  #pragma unroll
  for (int dt = 0; dt < 2; dt++)
    #pragma unroll
    for (int r = 0; r < 4; r++){ os[dt][r] *= alsr[r]; od[dt][r] *= aldr[r]; }
  #pragma unroll
  for (int mt = 0; mt < 4; mt++)
    #pragma unroll
    for (int dt = 0; dt < 2; dt++){
      os[dt] = __builtin_amdgcn_mfma_f32_16x16x16f16(pAs[mt], vf[dt][mt], os[dt], 0, 0, 0);
      od[dt] = __builtin_amdgcn_mfma_f32_16x16x16f16(pAd[mt], vf[dt][mt], od[dt], 0, 0, 0);
    }
}

__global__ __launch_bounds__(256) void dual_attn3(
    const __bf16* __restrict__ qpk, const __bf16* __restrict__ kpk,
    const _Float16* __restrict__ vph, const unsigned int* __restrict__ fsd,
    const float* __restrict__ sbw1, const float* __restrict__ sbg, const float* __restrict__ sbb,
    const float* __restrict__ sbm, const float* __restrict__ sbv,
    const float* __restrict__ sbw2, const float* __restrict__ sbb2,
    _Float16* __restrict__ partO, float* __restrict__ statM, float* __restrict__ statL){
  const int t = threadIdx.x, w = t >> 6, lane = t & 63, ln = lane & 15, g = lane >> 4;
  const int h = blockIdx.y;
  const int b = blockIdx.z >> 1, split = blockIdx.z & 1;
  const int nbase = blockIdx.x * 64 + w * 16;
  const int n = nbase + ln;
  const int mstart = split * (N_ / 2);

  float Ac[4], Bc[4], W2h[4];
  #pragma unroll
  for (int j = 0; j < 4; j++){
    float rs = rsqrtf(sbv[j] + EPSf);
    Ac[j]  = rfl(-sbw1[j] * rs * sbg[j]);
    Bc[j]  = rfl(-sbm[j] * rs * sbg[j] + sbb[j]);
    W2h[j] = rfl(sbw2[h * 4 + j]);
  }
  float C0 = rfl(sbb2[h]);

  bf16x8 qf = *reinterpret_cast<const bf16x8*>(
      &qpk[(((size_t)(b * H_ + h)) * N_ + n) * HD_ + g * 8]);
  const unsigned int* fsdrow = &fsd[((size_t)(b * N_ + n)) * N_];
  const __bf16* kbase = &kpk[(((size_t)(b * H_ + h)) * N_) * HD_];
  const _Float16* vbase = &vph[((size_t)(b * C_ + h * HD_)) * N_];

  f32x4 os[2], od[2];
  #pragma unroll
  for (int i = 0; i < 2; i++){ os[i] = (f32x4){0.f,0.f,0.f,0.f}; od[i] = (f32x4){0.f,0.f,0.f,0.f}; }
  float ms = -3e38f, ls = 0.f, md = -3e38f, ld = 0.f;

  TileRegs TA, TB;
  load_tile(TA, kbase, fsdrow, mstart, ln, g);
  for (int i = 0; i < 16; i += 2){
    int m0 = mstart + i * 64;
    load_tile(TB, kbase, fsdrow, m0 + 64, ln, g);
    compute_tile(TA, vbase, m0, ln, g, qf, Ac, Bc, W2h, C0, os, od, ms, ls, md, ld);
    if (i + 2 < 16) load_tile(TA, kbase, fsdrow, m0 + 128, ln, g);
    compute_tile(TB, vbase, m0 + 64, ln, g, qf, Ac, Bc, W2h, C0, os, od, ms, ls, md, ld);
  }

  // write locally-normalized partials (f16) + stats
  float is = 1.f / ls, idd = 1.f / ld;
  float isr[4], idr[4];
  #pragma unroll
  for (int r = 0; r < 4; r++){
    isr[r] = __shfl(is, g * 4 + r);
    idr[r] = __shfl(idd, g * 4 + r);
  }
  #pragma unroll
  for (int dt = 0; dt < 2; dt++)
    #pragma unroll
    for (int r = 0; r < 4; r++){
      int nn = nbase + g * 4 + r;
      int ch = h * HD_ + dt * 16 + ln;
      size_t p0 = (((size_t)(0 * 2 + split) * B_ + b) * N_ + nn) * C_ + ch;
      size_t p1 = (((size_t)(2 + split) * B_ + b) * N_ + nn) * C_ + ch;
      partO[p0] = (_Float16)(os[dt][r] * isr[r]);
      partO[p1] = (_Float16)(od[dt][r] * idr[r]);
    }
  if (lane < 16){
    int nn = nbase + lane;
    size_t s0 = (((size_t)(0 * 2 + split) * B_ + b) * H_ + h) * N_ + nn;
    size_t s1 = (((size_t)(2 + split) * B_ + b) * H_ + h) * N_ + nn;
    statM[s0] = ms; statL[s0] = ls;
    statM[s1] = md; statL[s1] = ld;
  }
}

// ---- combine m-splits + LN -> bf16 ------------------------------------------
__global__ __launch_bounds__(256) void combine_ln(
    const _Float16* __restrict__ partO, const float* __restrict__ statM,
    const float* __restrict__ statL, __bf16* __restrict__ csLN, __bf16* __restrict__ cdLN,
    const float* __restrict__ lsg, const float* __restrict__ lsb,
    const float* __restrict__ ldg, const float* __restrict__ ldb){
  const int path = blockIdx.y;
  const int w = threadIdx.x >> 6, lane = threadIdx.x & 63;
  const size_t row = (size_t)blockIdx.x * 4 + w;    // b*N + n
  const int b = (int)(row >> 11), n = (int)(row & (N_ - 1));
  const int h = lane >> 3;
  const float* gg = path ? ldg : lsg;
  const float* bb = path ? ldb : lsb;
  __bf16* dst = path ? cdLN : csLN;

  size_t pb0 = (((size_t)(path * 2 + 0) * B_ + b) * N_ + n) * C_ + lane * 4;
  size_t pb1 = (((size_t)(path * 2 + 1) * B_ + b) * N_ + n) * C_ + lane * 4;
  f16x4 p0 = *reinterpret_cast<const f16x4*>(&partO[pb0]);
  f16x4 p1 = *reinterpret_cast<const f16x4*>(&partO[pb1]);
  size_t sb0 = (((size_t)(path * 2 + 0) * B_ + b) * H_ + h) * N_ + n;
  size_t sb1 = (((size_t)(path * 2 + 1) * B_ + b) * H_ + h) * N_ + n;
  float m0 = statM[sb0], l0 = statL[sb0];
  float m1 = statM[sb1], l1 = statL[sb1];
  float M = fmaxf(m0, m1);
  float w0 = l0 * __expf(m0 - M), w1 = l1 * __expf(m1 - M);
  float inv = 1.f / (w0 + w1);
  float o[4];
  #pragma unroll
  for (int j = 0; j < 4; j++)
    o[j] = (w0 * (float)p0[j] + w1 * (float)p1[j]) * inv;

  float s1 = o[0] + o[1] + o[2] + o[3];
  float s2 = o[0]*o[0] + o[1]*o[1] + o[2]*o[2] + o[3]*o[3];
  #pragma unroll
  for (int off = 1; off < 64; off <<= 1){
    s1 += __shfl_xor(s1, off);
    s2 += __shfl_xor(s2, off);
  }
  float mu = s1 / (float)C_;
  float rs = rsqrtf(s2 / (float)C_ - mu * mu + EPSf);
  float4 g4 = *reinterpret_cast<const float4*>(&gg[lane * 4]);
  float4 b4 = *reinterpret_cast<const float4*>(&bb[lane * 4]);
  alignas(8) __bf16 o4[4];
  o4[0] = (__bf16)((o[0] - mu) * rs * g4.x + b4.x);
  o4[1] = (__bf16)((o[1] - mu) * rs * g4.y + b4.y);
  o4[2] = (__bf16)((o[2] - mu) * rs * g4.z + b4.z);
  o4[3] = (__bf16)((o[3] - mu) * rs * g4.w + b4.w);
  *reinterpret_cast<uint2*>(&dst[row * C_ + lane * 4]) = *reinterpret_cast<uint2*>(o4);
}

// ================= old-path kernels (ws-size fallback, round-3 exact) =======
__global__ __launch_bounds__(256) void fdist_mfma(const __bf16* __restrict__ qdT,
    const __bf16* __restrict__ kdT, const float* __restrict__ qq,
    const float* __restrict__ kk, _Float16* __restrict__ fdh){
  const int t = threadIdx.x, w = t >> 6, lane = t & 63, ln = lane & 15, g = lane >> 4;
  const int b = blockIdx.z, n0 = blockIdx.y * 64 + w * 16, m0 = blockIdx.x * 64;
  __shared__ _Float16 sbl[4][16][68];

  bf16x8 qfr[8];
  #pragma unroll
  for (int ks = 0; ks < 8; ks++)
    qfr[ks] = *reinterpret_cast<const bf16x8*>(
        &qdT[((size_t)(b * N_ + n0 + ln)) * C_ + ks * 32 + g * 8]);
  float qqv[4];
  #pragma unroll
  for (int r = 0; r < 4; r++) qqv[r] = qq[b * N_ + n0 + g * 4 + r];

  #pragma unroll
  for (int mt = 0; mt < 4; mt++){
    f32x4 a = (f32x4){0.f, 0.f, 0.f, 0.f};
    #pragma unroll
    for (int ks = 0; ks < 8; ks++){
      bf16x8 kfr = *reinterpret_cast<const bf16x8*>(
          &kdT[((size_t)(b * N_ + m0 + mt * 16 + ln)) * C_ + ks * 32 + g * 8]);
      a = __builtin_amdgcn_mfma_f32_16x16x32_bf16(qfr[ks], kfr, a, 0, 0, 0);
    }
    float kkv = kk[b * N_ + m0 + mt * 16 + ln];
    #pragma unroll
    for (int r = 0; r < 4; r++){
      float d2 = qqv[r] + kkv - 2.f * a[r];
      sbl[w][g * 4 + r][mt * 16 + ln] = (_Float16)sqrtf(fmaxf(d2, 0.f));
    }
  }
  __syncthreads();
  #pragma unroll
  for (int it = 0; it < 8; it++){
    int row = (lane >> 5) + it * 2, colu = lane & 31;
    unsigned int u = *reinterpret_cast<const unsigned int*>(&sbl[w][row][colu * 2]);
    *reinterpret_cast<unsigned int*>(&fdh[((size_t)(b * N_ + n0 + row)) * N_ + m0 + colu * 2]) = u;
  }
}

__global__ __launch_bounds__(256) void dual_attn(
    const __bf16* __restrict__ qpk, const __bf16* __restrict__ kpk, const __bf16* __restrict__ vpk,
    const _Float16* __restrict__ fdh,
    const float* __restrict__ xyzA, const float* __restrict__ xyzB,
    const float* __restrict__ sbw1, const float* __restrict__ sbg, const float* __restrict__ sbb,
    const float* __restrict__ sbm, const float* __restrict__ sbv,
    const float* __restrict__ sbw2, const float* __restrict__ sbb2,
    float* __restrict__ ctxsT, float* __restrict__ ctxdT){
  const int t = threadIdx.x, w = t >> 6, lane = t & 63, ln = lane & 15, g = lane >> 4;
  const int h = blockIdx.y, b = blockIdx.z;
  const int nbase = blockIdx.x * 64 + w * 16;
  const int n = nbase + ln;

  float Ac[4], Bc[4], W2h[4];
  #pragma unroll
  for (int j = 0; j < 4; j++){
    float rs = rsqrtf(sbv[j] + EPSf);
    Ac[j]  = rfl(-sbw1[j] * rs * sbg[j]);
    Bc[j]  = rfl(-sbm[j] * rs * sbg[j] + sbb[j]);
    W2h[j] = rfl(sbw2[h * 4 + j]);
  }
  float C0 = rfl(sbb2[h]);

  bf16x8 qf = *reinterpret_cast<const bf16x8*>(
      &qpk[(((size_t)(b * H_ + h)) * N_ + n) * HD_ + g * 8]);
  float ax = xyzA[((size_t)(b * N_ + n)) * 3 + 0];
  float ay = xyzA[((size_t)(b * N_ + n)) * 3 + 1];
  float az = xyzA[((size_t)(b * N_ + n)) * 3 + 2];
  const _Float16* fdrow = &fdh[((size_t)(b * N_ + n)) * N_];

  f32x4 os[2], od[2];
  #pragma unroll
  for (int i = 0; i < 2; i++){ os[i] = (f32x4){0.f,0.f,0.f,0.f}; od[i] = (f32x4){0.f,0.f,0.f,0.f}; }
  float ms = -3e38f, ls = 0.f, md = -3e38f, ld = 0.f;

  __shared__ __align__(16) float ss[4][16][68];
  __shared__ float4 xbb[4][64];

  for (int m0 = 0; m0 < N_; m0 += 64){
    __syncthreads();
    {
      const float* xp = &xyzB[((size_t)(b * N_ + m0 + lane)) * 3];
      xbb[w][lane] = make_float4(xp[0], xp[1], xp[2], 0.f);
    }
    f32x4 sa[4];
    #pragma unroll
    for (int i = 0; i < 4; i++) sa[i] = (f32x4){0.f, 0.f, 0.f, 0.f};
    #pragma unroll
    for (int mt = 0; mt < 4; mt++){
      bf16x8 kf = *reinterpret_cast<const bf16x8*>(
          &kpk[(((size_t)(b * H_ + h)) * N_ + m0 + mt * 16 + ln) * HD_ + g * 8]);
      sa[mt] = __builtin_amdgcn_mfma_f32_16x16x32_bf16(qf, kf, sa[mt], 0, 0, 0);
    }
    #pragma unroll
    for (int mt = 0; mt < 4; mt++)
      #pragma unroll
      for (int r = 0; r < 4; r++)
        ss[w][g * 4 + r][mt * 16 + ln] = sa[mt][r];
    __syncthreads();

    #pragma unroll
    for (int kh = 0; kh < 2; kh++){
      float s8[8], d8[8];
      {
        float4 A4 = *reinterpret_cast<const float4*>(&ss[w][ln][kh * 32 + g * 8]);
        float4 B4 = *reinterpret_cast<const float4*>(&ss[w][ln][kh * 32 + g * 8 + 4]);
        s8[0]=A4.x; s8[1]=A4.y; s8[2]=A4.z; s8[3]=A4.w;
        s8[4]=B4.x; s8[5]=B4.y; s8[6]=B4.z; s8[7]=B4.w;
      }
      f16x8 fv = *reinterpret_cast<const f16x8*>(&fdrow[m0 + kh * 32 + g * 8]);
      float mxs = -3e38f, mxd = -3e38f;
      #pragma unroll
      for (int j = 0; j < 8; j++){
        float4 xk = xbb[w][kh * 32 + g * 8 + j];
        float dx = ax - xk.x, dy = ay - xk.y, dz = az - xk.z;
        float sd = sqrtf(dx * dx + dy * dy + dz * dz);
        float bias = C0;
        #pragma unroll
        for (int u = 0; u < 4; u++)
          bias += W2h[u] * fmaxf(fmaf(Ac[u], sd, Bc[u]), 0.f);
        s8[j] += bias;
        d8[j] = (float)fv[j] + bias;
        mxs = fmaxf(mxs, s8[j]);
        mxd = fmaxf(mxd, d8[j]);
      }
      mxs = fmaxf(mxs, __shfl_xor(mxs, 16)); mxs = fmaxf(mxs, __shfl_xor(mxs, 32));
      mxd = fmaxf(mxd, __shfl_xor(mxd, 16)); mxd = fmaxf(mxd, __shfl_xor(mxd, 32));
      float nms = fmaxf(ms, mxs), als = __expf(ms - nms);
      float nmd = fmaxf(md, mxd), ald = __expf(md - nmd);
      float pss = 0.f, psd = 0.f;
      bf16x8 pfs, pfd;
      #pragma unroll
      for (int j = 0; j < 8; j++){
        float pv = __expf(s8[j] - nms); pss += pv; pfs[j] = (__bf16)pv;
        float qv = __expf(d8[j] - nmd); psd += qv; pfd[j] = (__bf16)qv;
      }
      pss += __shfl_xor(pss, 16); pss += __shfl_xor(pss, 32);
      psd += __shfl_xor(psd, 16); psd += __shfl_xor(psd, 32);
      ls = ls * als + pss; ms = nms;
      ld = ld * ald + psd; md = nmd;
      os[0] *= als; os[1] *= als; od[0] *= ald; od[1] *= ald;
      #pragma unroll
      for (int dt = 0; dt < 2; dt++){
        bf16x8 vf = *reinterpret_cast<const bf16x8*>(
            &vpk[((size_t)(b * C_ + h * HD_ + dt * 16 + ln)) * N_ + m0 + kh * 32 + g * 8]);
        os[dt] = __builtin_amdgcn_mfma_f32_16x16x32_bf16(vf, pfs, os[dt], 0, 0, 0);
        od[dt] = __builtin_amdgcn_mfma_f32_16x16x32_bf16(vf, pfd, od[dt], 0, 0, 0);
      }
    }
  }
  float is = 1.f / ls, idv = 1.f / ld;
  #pragma unroll
  for (int dt = 0; dt < 2; dt++)
    #pragma unroll
    for (int r = 0; r < 4; r++){
      int ch = h * HD_ + dt * 16 + g * 4 + r;
      size_t base = ((size_t)(b * N_ + n)) * C_ + ch;
      ctxsT[base] = os[dt][r] * is;
      ctxdT[base] = od[dt][r] * idv;
    }
}

// ---- LN of ctx (fallback path) ----------------------------------------------
__global__ __launch_bounds__(256) void ln_ctx(const float* __restrict__ ctxsT,
    const float* __restrict__ ctxdT, __bf16* __restrict__ csLN, __bf16* __restrict__ cdLN,
    const float* __restrict__ lsg, const float* __restrict__ lsb,
    const float* __restrict__ ldg, const float* __restrict__ ldb){
  const float* src = blockIdx.y ? ctxdT : ctxsT;
  __bf16* dst = blockIdx.y ? cdLN : csLN;
  const float* gg = blockIdx.y ? ldg : lsg;
  const float* bb = blockIdx.y ? ldb : lsb;
  int w = threadIdx.x >> 6, lane = threadIdx.x & 63;
  size_t row = (size_t)blockIdx.x * 4 + w;
  float4 v = *reinterpret_cast<const float4*>(&src[row * C_ + lane * 4]);
  float s1 = v.x + v.y + v.z + v.w;
  float s2 = v.x * v.x + v.y * v.y + v.z * v.z + v.w * v.w;
  #pragma unroll
  for (int off = 1; off < 64; off <<= 1){
    s1 += __shfl_xor(s1, off);
    s2 += __shfl_xor(s2, off);
  }
  float m = s1 / (float)C_;
  float rs = rsqrtf(s2 / (float)C_ - m * m + EPSf);
  float4 g4 = *reinterpret_cast<const float4*>(&gg[lane * 4]);
  float4 b4 = *reinterpret_cast<const float4*>(&bb[lane * 4]);
  alignas(8) __bf16 o4[4];
  o4[0] = (__bf16)((v.x - m) * rs * g4.x + b4.x);
  o4[1] = (__bf16)((v.y - m) * rs * g4.y + b4.y);
  o4[2] = (__bf16)((v.z - m) * rs * g4.z + b4.z);
  o4[3] = (__bf16)((v.w - m) * rs * g4.w + b4.w);
  *reinterpret_cast<uint2*>(&dst[row * C_ + lane * 4]) = *reinterpret_cast<uint2*>(o4);
}

// ---- fusion stage 1 ---------------------------------------------------------
__global__ __launch_bounds__(256) void fusion1_mfma(const __bf16* __restrict__ fanT,
    const __bf16* __restrict__ csLN, const __bf16* __restrict__ cdLN,
    __bf16* __restrict__ X1T, const float* __restrict__ fw1,
    const float* __restrict__ fbg, const float* __restrict__ fbb,
    const float* __restrict__ fbm, const float* __restrict__ fbv){
  const int t = threadIdx.x, w = t >> 6, lane = t & 63, ln = lane & 15, g = lane >> 4;
  const int b = blockIdx.z, o0 = blockIdx.y * 64, n0w = blockIdx.x * 64 + w * 16;
  f32x4 acc[4];
  #pragma unroll
  for (int i = 0; i < 4; i++) acc[i] = (f32x4){0.f, 0.f, 0.f, 0.f};
  const __bf16* segs[3] = {fanT, csLN, cdLN};
  #pragma unroll
  for (int ks = 0; ks < 24; ks++){
    const __bf16* base = segs[ks >> 3];
    int coff = (ks & 7) * 32 + g * 8;
    bf16x8 af = *reinterpret_cast<const bf16x8*>(
        &base[((size_t)(b * N_ + n0w + ln)) * C_ + coff]);
    #pragma unroll
    for (int ot = 0; ot < 4; ot++){
      bf16x8 bf = cvt8(&fw1[(size_t)(o0 + ot * 16 + ln) * (3 * C_) + ks * 32 + g * 8]);
      acc[ot] = __builtin_amdgcn_mfma_f32_16x16x32_bf16(af, bf, acc[ot], 0, 0, 0);
    }
  }
  #pragma unroll
  for (int ot = 0; ot < 4; ot++){
    int o = o0 + ot * 16 + ln;
    float mn = fbm[o], rs = rsqrtf(fbv[o] + EPSf), gg = fbg[o], be = fbb[o];
    #pragma unroll
    for (int r = 0; r < 4; r++){
      int n = n0w + g * 4 + r;
      float x = (acc[ot][r] - mn) * rs * gg + be;
      X1T[((size_t)(b * N_ + n)) * (2 * C_) + o] = (__bf16)fmaxf(x, 0.f);
    }
  }
}

// ---- fusion stage 2 ---------------------------------------------------------
__global__ __launch_bounds__(256) void fusion2_mfma(const __bf16* __restrict__ X1T,
    const float* __restrict__ fw2, const float* __restrict__ fb2,
    const float* __restrict__ featA, float* __restrict__ out){
  const int t = threadIdx.x, w = t >> 6, lane = t & 63, ln = lane & 15, g = lane >> 4;
  const int b = blockIdx.z, o0w = blockIdx.y * 64 + w * 16, n0 = blockIdx.x * 64;
  f32x4 acc[4];
  #pragma unroll
  for (int i = 0; i < 4; i++) acc[i] = (f32x4){0.f, 0.f, 0.f, 0.f};
  #pragma unroll
  for (int ks = 0; ks < 16; ks++){
    bf16x8 af = cvt8(&fw2[(size_t)(o0w + ln) * (2 * C_) + ks * 32 + g * 8]);
    #pragma unroll
    for (int nt = 0; nt < 4; nt++){
      bf16x8 bf = *reinterpret_cast<const bf16x8*>(
          &X1T[((size_t)(b * N_ + n0 + nt * 16 + ln)) * (2 * C_) + ks * 32 + g * 8]);
      acc[nt] = __builtin_amdgcn_mfma_f32_16x16x32_bf16(af, bf, acc[nt], 0, 0, 0);
    }
  }
  float bz[4];
  #pragma unroll
  for (int r = 0; r < 4; r++) bz[r] = fb2[o0w + g * 4 + r];
  #pragma unroll
  for (int nt = 0; nt < 4; nt++)
    #pragma unroll
    for (int r = 0; r < 4; r++){
      int o = o0w + g * 4 + r, n = n0 + nt * 16 + ln;
      size_t oi = ((size_t)(b * C_ + o)) * N_ + n;
      out[oi] = acc[nt][r] + bz[r] + featA[oi];
    }
}

extern "C" void kernel_launch(void* const* d_in, const int* in_sizes, int n_in,
                              void* d_out, int out_size, void* d_ws, size_t ws_size,
                              hipStream_t stream){
  (void)in_sizes; (void)n_in; (void)out_size;
  if (ws_size < WS_NEED) return;

  const float* xyzA  = (const float*)d_in[0];
  const float* featA = (const float*)d_in[1];
  const float* xyzB  = (const float*)d_in[2];
  const float* featB = (const float*)d_in[3];
  const float* qw  = (const float*)d_in[4];   const float* qb  = (const float*)d_in[5];
  const float* kw  = (const float*)d_in[6];   const float* kb  = (const float*)d_in[7];
  const float* vw  = (const float*)d_in[8];   const float* vb  = (const float*)d_in[9];
  const float* sbw1= (const float*)d_in[10];  const float* sbg = (const float*)d_in[11];
  const float* sbb = (const float*)d_in[12];  const float* sbm = (const float*)d_in[13];
  const float* sbv = (const float*)d_in[14];  const float* sbw2= (const float*)d_in[15];
  const float* sbb2= (const float*)d_in[16];
  const float* qdw = (const float*)d_in[17];  const float* qdb = (const float*)d_in[18];
  const float* kdw = (const float*)d_in[19];  const float* kdb = (const float*)d_in[20];
  const float* ling= (const float*)d_in[21];  const float* linb= (const float*)d_in[22];
  const float* lsg = (const float*)d_in[23];  const float* lsb = (const float*)d_in[24];
  const float* ldg = (const float*)d_in[25];  const float* ldb = (const float*)d_in[26];
  const float* fw1 = (const float*)d_in[27];  const float* fbg = (const float*)d_in[28];
  const float* fbb = (const float*)d_in[29];  const float* fbm = (const float*)d_in[30];
  const float* fbv = (const float*)d_in[31];  const float* fw2 = (const float*)d_in[32];
  const float* fb2 = (const float*)d_in[33];

  char* ws = (char*)d_ws;
  __bf16*   fanT = (__bf16*)(ws + OFF_FANT);
  __bf16*   fbT  = (__bf16*)(ws + OFF_FBT);
  __bf16*   qpk  = (__bf16*)(ws + OFF_QPK);
  __bf16*   kpk  = (__bf16*)(ws + OFF_KPK);
  __bf16*   qdT  = (__bf16*)(ws + OFF_QDT);
  __bf16*   kdT  = (__bf16*)(ws + OFF_KDT);
  float*    qq   = (float*)(ws + OFF_QQ);
  float*    kk   = (float*)(ws + OFF_KK);
  float*    out  = (float*)d_out;

  bool big = (ws_size >= WS_NEED2);

  lnA_pack<<<dim3(N_ / 32, B_), 256, 0, stream>>>(featA, fanT, ling, linb);
  packT_kernel<<<dim3(N_ / 64, C_ / 64, B_), 256, 0, stream>>>(featB, fbT);
  proj_mfma<<<dim3(N_ / 64, C_ / 64, 5 * B_), 256, 0, stream>>>(
      fanT, fbT, fanT, big ? 1 : 0, qw, qb, kw, kb, vw, vb, qdw, qdb, kdw, kdb);
  norms_b<<<dim3(N_ / 64, B_), 256, 0, stream>>>(qdT, kdT, qq, kk);

  if (big){
    _Float16*     vph  = (_Float16*)(ws + OFF_VPK);
    unsigned int* fsd  = (unsigned int*)(ws + OFF_FSD);
    _Float16* partO = (_Float16*)(ws + OFF2_PART);
    float*    statM = (float*)(ws + OFF2_STATM);
    float*    statL = (float*)(ws + OFF2_STATL);
    __bf16*   csLN  = (__bf16*)(ws + OFF2_CSLN);
    __bf16*   cdLN  = (__bf16*)(ws + OFF2_CDLN);
    __bf16*   X1T   = (__bf16*)(ws + OFF2_X1T);
    pairdist_mfma<<<dim3(N_ / 64, N_ / 64, B_), 256, 0, stream>>>(
        qdT, kdT, qq, kk, xyzA, xyzB, fsd);
    dual_attn3<<<dim3(N_ / 64, H_, B_ * 2), 256, 0, stream>>>(
        qpk, kpk, vph, fsd, sbw1, sbg, sbb, sbm, sbv, sbw2, sbb2,
        partO, statM, statL);
    combine_ln<<<dim3(B_ * N_ / 4, 2), 256, 0, stream>>>(
        partO, statM, statL, csLN, cdLN, lsg, lsb, ldg, ldb);
    fusion1_mfma<<<dim3(N_ / 64, (2 * C_) / 64, B_), 256, 0, stream>>>(
        fanT, csLN, cdLN, X1T, fw1, fbg, fbb, fbm, fbv);
    fusion2_mfma<<<dim3(N_ / 64, C_ / 64, B_), 256, 0, stream>>>(
        X1T, fw2, fb2, featA, out);
  } else {
    __bf16*   vpk  = (__bf16*)(ws + OFF_VPK);
    _Float16* fdh  = (_Float16*)(ws + OFF_FDH);
    float*  ctxsT = (float*)(ws + OFF_CTXS);
    float*  ctxdT = (float*)(ws + OFF_CTXD);
    __bf16* csLN  = (__bf16*)(ws + OFF_CSLN);
    __bf16* cdLN  = (__bf16*)(ws + OFF_CDLN);
    __bf16* X1T   = (__bf16*)(ws + OFF_X1T);
    fdist_mfma<<<dim3(N_ / 64, N_ / 64, B_), 256, 0, stream>>>(qdT, kdT, qq, kk, fdh);
    dual_attn<<<dim3(N_ / 64, H_, B_), 256, 0, stream>>>(
        qpk, kpk, vpk, fdh, xyzA, xyzB,
        sbw1, sbg, sbb, sbm, sbv, sbw2, sbb2, ctxsT, ctxdT);
    ln_ctx<<<dim3(B_ * N_ / 4, 2), 256, 0, stream>>>(
        ctxsT, ctxdT, csLN, cdLN, lsg, lsb, ldg, ldb);
    fusion1_mfma<<<dim3(N_ / 64, (2 * C_) / 64, B_), 256, 0, stream>>>(
        fanT, csLN, cdLN, X1T, fw1, fbg, fbb, fbm, fbv);
    fusion2_mfma<<<dim3(N_ / 64, C_ / 64, B_), 256, 0, stream>>>(
        X1T, fw2, fb2, featA, out);
  }
}

// Round 6
// 265.887 us; speedup vs baseline: 4.3499x; 1.0188x over previous
//
#include <hip/hip_runtime.h>

#define B_ 2
#define N_ 2048
#define C_ 256
#define H_ 8
#define HD_ 32
#define EPSf 1e-5f
#define LOG2E 1.4426950408889634f
#define THRv 8.0f

typedef __bf16   bf16x8 __attribute__((ext_vector_type(8)));
typedef float    f32x4  __attribute__((ext_vector_type(4)));
typedef _Float16 f16x4  __attribute__((ext_vector_type(4)));
typedef _Float16 f16x2  __attribute__((ext_vector_type(2)));

// ---- workspace layout (byte offsets), needs 63MB (proven available) --------
static constexpr size_t MB_ = 1024 * 1024;
static constexpr size_t OFF_FANT = 0;                    // bf16 (B,N,C)   2MB
static constexpr size_t OFF_FBT  = 2 * MB_;              // bf16 (B,N,C)   2MB
static constexpr size_t OFF_QPK  = 4 * MB_;              // bf16 (B,H,N,HD) 2MB (q*log2e/sqrt(hd))
static constexpr size_t OFF_KPK  = 6 * MB_;              // bf16 (B,H,N,HD) 2MB
static constexpr size_t OFF_VPK  = 8 * MB_;              // f16 (B,C,N)    2MB
static constexpr size_t OFF_QDT  = 10 * MB_;             // bf16 (B,N,C)   2MB
static constexpr size_t OFF_KDT  = 12 * MB_;             // bf16 (B,N,C)   2MB
static constexpr size_t OFF_QQ   = 14 * MB_;             // f32 (B,N)
static constexpr size_t OFF_KK   = 14 * MB_ + 16 * 1024; // f32 (B,N)
static constexpr size_t OFF_FSD  = 14 * MB_ + 64 * 1024; // uint (B,N,N) 32MB -> ends 46.06MB
static constexpr size_t OFF_PART  = 47 * MB_;  // f16 [path2][split2][B][N][C] = 8MB
static constexpr size_t OFF_STATM = 55 * MB_;  // f32 [path2][split2][B][H][N] = 1MB
static constexpr size_t OFF_STATL = 56 * MB_;  // f32 same
static constexpr size_t OFF_CSLN  = 15 * MB_;  // bf16 (B,N,C) 2MB (overlays dead fsd)
static constexpr size_t OFF_CDLN  = 17 * MB_;  // bf16 (B,N,C) 2MB (overlays dead fsd)
static constexpr size_t OFF_X1T   = 19 * MB_;  // bf16 (B,N,2C) 4MB (overlays dead fsd)
static constexpr size_t WS_NEED   = 63 * MB_;

__device__ __forceinline__ float rfl(float x){
  return __uint_as_float(__builtin_amdgcn_readfirstlane(__float_as_uint(x)));
}
__device__ __forceinline__ float fexp2(float x){ return __builtin_amdgcn_exp2f(x); }
__device__ __forceinline__ bf16x8 cvt8(const float* p){
  float4 a = *reinterpret_cast<const float4*>(p);
  float4 c = *reinterpret_cast<const float4*>(p + 4);
  bf16x8 r;
  r[0]=(__bf16)a.x; r[1]=(__bf16)a.y; r[2]=(__bf16)a.z; r[3]=(__bf16)a.w;
  r[4]=(__bf16)c.x; r[5]=(__bf16)c.y; r[6]=(__bf16)c.z; r[7]=(__bf16)c.w;
  return r;
}
__device__ __forceinline__ unsigned int packh2(float lo, float hi){
  f16x2 h; h[0] = (_Float16)lo; h[1] = (_Float16)hi;
  return __builtin_bit_cast(unsigned int, h);
}
__device__ __forceinline__ void unpackh2(unsigned int u, float& lo, float& hi){
  f16x2 h = __builtin_bit_cast(f16x2, u);
  lo = (float)h[0]; hi = (float)h[1];
}
__device__ __forceinline__ f16x4 pack4(float a, float b, float c, float d){
  auto lo = __builtin_amdgcn_cvt_pkrtz(a, b);
  auto hi = __builtin_amdgcn_cvt_pkrtz(c, d);
  unsigned long long u = (unsigned long long)__builtin_bit_cast(unsigned int, lo)
      | ((unsigned long long)__builtin_bit_cast(unsigned int, hi) << 32);
  return __builtin_bit_cast(f16x4, u);
}

// ---- prep: x<64 -> LN(featA)->fanT ; x>=64 -> featB->fbT transpose ----------
__global__ __launch_bounds__(256) void prep_kernel(const float* __restrict__ featA,
    const float* __restrict__ featB, __bf16* __restrict__ fanT, __bf16* __restrict__ fbT,
    const float* __restrict__ gam, const float* __restrict__ bet){
  int b = blockIdx.y;
  int t = threadIdx.x;
  __shared__ float sh[9536];
  if (blockIdx.x < 64){
    int n0 = blockIdx.x * 32;
    int nl = t & 31, cg = t >> 5;
    float* tile = sh;               // [256][33]
    float* red1 = sh + 8448;        // [8][32]
    float* red2 = red1 + 256;       // [8][32]
    float* mus  = red2 + 256;       // [32]
    float* rss  = mus + 32;         // [32]
    float* gsh  = rss + 32;         // [256]
    float* bsh  = gsh + 256;        // [256]
    gsh[t] = gam[t]; bsh[t] = bet[t];
    #pragma unroll
    for (int i = 0; i < 32; i++){
      int c = cg * 32 + i;
      tile[c * 33 + nl] = featA[((size_t)(b * C_ + c)) * N_ + n0 + nl];
    }
    __syncthreads();
    float s1 = 0.f, s2 = 0.f;
    #pragma unroll
    for (int i = 0; i < 32; i++){
      float v = tile[(cg * 32 + i) * 33 + nl];
      s1 += v; s2 += v * v;
    }
    red1[cg * 32 + nl] = s1; red2[cg * 32 + nl] = s2;
    __syncthreads();
    if (t < 32){
      float a = 0.f, q = 0.f;
      #pragma unroll
      for (int i = 0; i < 8; i++){ a += red1[i * 32 + t]; q += red2[i * 32 + t]; }
      float m = a / (float)C_;
      mus[t] = m; rss[t] = rsqrtf(q / (float)C_ - m * m + EPSf);
    }
    __syncthreads();
    float mu = mus[nl], rs = rss[nl];
    size_t obase = ((size_t)(b * N_ + n0 + nl)) * C_;
    #pragma unroll
    for (int i = 0; i < 32; i++){
      int c = cg * 32 + i;
      fanT[obase + c] = (__bf16)((tile[c * 33 + nl] - mu) * rs * gsh[c] + bsh[c]);
    }
  } else {
    int idx = blockIdx.x - 64;
    int n0 = (idx & 31) * 64, c0 = (idx >> 5) * 64;
    float* tile = sh;               // [64][65]
    int cl = t >> 6, nl = t & 63;
    #pragma unroll
    for (int i = 0; i < 16; i++)
      tile[(i * 4 + cl) * 65 + nl] = featB[((size_t)(b * C_ + c0 + i * 4 + cl)) * N_ + n0 + nl];
    __syncthreads();
    int nr = t >> 2, cc = (t & 3) * 16;
    alignas(16) __bf16 tmp[16];
    #pragma unroll
    for (int j = 0; j < 16; j++) tmp[j] = (__bf16)tile[(cc + j) * 65 + nr];
    size_t d = ((size_t)(b * N_ + n0 + nr)) * C_ + c0 + cc;
    *reinterpret_cast<uint4*>(&fbT[d])     = *reinterpret_cast<uint4*>(&tmp[0]);
    *reinterpret_cast<uint4*>(&fbT[d + 8]) = *reinterpret_cast<uint4*>(&tmp[8]);
  }
}

// ---- 5 projection GEMMs, bf16 MFMA -----------------------------------------
__global__ __launch_bounds__(256) void proj_mfma(const __bf16* __restrict__ fanT,
    const __bf16* __restrict__ fbT, __bf16* __restrict__ wsh,
    const float* __restrict__ qw, const float* __restrict__ qb,
    const float* __restrict__ kw, const float* __restrict__ kb,
    const float* __restrict__ vw, const float* __restrict__ vb,
    const float* __restrict__ qdw, const float* __restrict__ qdb,
    const float* __restrict__ kdw, const float* __restrict__ kdb){
  const int p = blockIdx.z % 5, b = blockIdx.z / 5;
  const int t = threadIdx.x, w = t >> 6, lane = t & 63, ln = lane & 15, g = lane >> 4;
  const float *W, *bias;
  const __bf16* X;
  __bf16* Y;
  if (p == 0)      { W = qw;  bias = qb;  X = fanT; Y = wsh + (OFF_QPK - OFF_FANT) / 2; }
  else if (p == 1) { W = kw;  bias = kb;  X = fbT;  Y = wsh + (OFF_KPK - OFF_FANT) / 2; }
  else if (p == 2) { W = vw;  bias = vb;  X = fbT;  Y = wsh + (OFF_VPK - OFF_FANT) / 2; }
  else if (p == 3) { W = qdw; bias = qdb; X = fanT; Y = wsh + (OFF_QDT - OFF_FANT) / 2; }
  else             { W = kdw; bias = kdb; X = fbT;  Y = wsh + (OFF_KDT - OFF_FANT) / 2; }

  f32x4 acc[4];
  #pragma unroll
  for (int i = 0; i < 4; i++) acc[i] = (f32x4){0.f, 0.f, 0.f, 0.f};

  if (p != 2){
    const int n0w = blockIdx.x * 64 + w * 16, o0 = blockIdx.y * 64;
    #pragma unroll
    for (int ks = 0; ks < 8; ks++){
      bf16x8 af = *reinterpret_cast<const bf16x8*>(
          &X[((size_t)(b * N_ + n0w + ln)) * C_ + ks * 32 + g * 8]);
      #pragma unroll
      for (int ot = 0; ot < 4; ot++){
        bf16x8 bf = cvt8(&W[(size_t)(o0 + ot * 16 + ln) * C_ + ks * 32 + g * 8]);
        acc[ot] = __builtin_amdgcn_mfma_f32_16x16x32_bf16(af, bf, acc[ot], 0, 0, 0);
      }
    }
    const float inv = 0.17677669529663687f * LOG2E;  // q: 1/sqrt(hd) * log2e
    #pragma unroll
    for (int ot = 0; ot < 4; ot++){
      int o = o0 + ot * 16 + ln;
      float bz = bias[o];
      #pragma unroll
      for (int r = 0; r < 4; r++){
        int n = n0w + g * 4 + r;
        float val = acc[ot][r] + bz;
        if (p == 0){
          val *= inv;
          Y[(((size_t)(b * H_ + (o >> 5))) * N_ + n) * HD_ + (o & 31)] = (__bf16)val;
        } else if (p == 1){
          Y[(((size_t)(b * H_ + (o >> 5))) * N_ + n) * HD_ + (o & 31)] = (__bf16)val;
        } else {
          Y[((size_t)(b * N_ + n)) * C_ + o] = (__bf16)val;
        }
      }
    }
  } else {
    const int o0w = blockIdx.y * 64 + w * 16, n0 = blockIdx.x * 64;
    #pragma unroll
    for (int ks = 0; ks < 8; ks++){
      bf16x8 af = cvt8(&W[(size_t)(o0w + ln) * C_ + ks * 32 + g * 8]);
      #pragma unroll
      for (int nt = 0; nt < 4; nt++){
        bf16x8 bf = *reinterpret_cast<const bf16x8*>(
            &X[((size_t)(b * N_ + n0 + nt * 16 + ln)) * C_ + ks * 32 + g * 8]);
        acc[nt] = __builtin_amdgcn_mfma_f32_16x16x32_bf16(af, bf, acc[nt], 0, 0, 0);
      }
    }
    float bz[4];
    #pragma unroll
    for (int r = 0; r < 4; r++) bz[r] = vb[o0w + g * 4 + r];
    #pragma unroll
    for (int nt = 0; nt < 4; nt++)
      #pragma unroll
      for (int r = 0; r < 4; r++){
        int o = o0w + g * 4 + r, n = n0 + nt * 16 + ln;
        size_t idx = ((size_t)(b * C_ + o)) * N_ + n;
        ((_Float16*)Y)[idx] = (_Float16)(acc[nt][r] + bz[r]);
      }
  }
}

// ---- row norms from bf16 qdT/kdT -------------------------------------------
__global__ __launch_bounds__(256) void norms_b(const __bf16* __restrict__ qdT,
    const __bf16* __restrict__ kdT, float* __restrict__ qq, float* __restrict__ kk){
  int b = blockIdx.y, n = blockIdx.x * 64 + (threadIdx.x >> 2), part = threadIdx.x & 3;
  size_t base = ((size_t)(b * N_ + n)) * C_ + part * 64;
  float s1 = 0.f, s2 = 0.f;
  #pragma unroll
  for (int i = 0; i < 8; i++){
    bf16x8 a = *reinterpret_cast<const bf16x8*>(&qdT[base + i * 8]);
    bf16x8 d = *reinterpret_cast<const bf16x8*>(&kdT[base + i * 8]);
    #pragma unroll
    for (int j = 0; j < 8; j++){
      float fa = (float)a[j]; s1 += fa * fa;
      float fd = (float)d[j]; s2 += fd * fd;
    }
  }
  s1 += __shfl_xor(s1, 1); s1 += __shfl_xor(s1, 2);
  s2 += __shfl_xor(s2, 1); s2 += __shfl_xor(s2, 2);
  if (part == 0){ qq[b * N_ + n] = s1; kk[b * N_ + n] = s2; }
}

// ---- feature-dist(*log2e) + spatial-dist -> fsd packed f16x2 (B,N,N) -------
__global__ __launch_bounds__(256) void pairdist_mfma(const __bf16* __restrict__ qdT,
    const __bf16* __restrict__ kdT, const float* __restrict__ qq,
    const float* __restrict__ kk, const float* __restrict__ xyzA,
    const float* __restrict__ xyzB, unsigned int* __restrict__ fsd){
  const int t = threadIdx.x, w = t >> 6, lane = t & 63, ln = lane & 15, g = lane >> 4;
  const int b = blockIdx.z, n0 = blockIdx.y * 64, n0w = n0 + w * 16, m0 = blockIdx.x * 64;
  __shared__ float4 xa[64], xb[64];
  __shared__ unsigned int sbl[4][16][68];

  if (t < 64){
    const float* p = &xyzA[((size_t)(b * N_ + n0 + t)) * 3];
    xa[t] = make_float4(p[0], p[1], p[2], 0.f);
  } else if (t < 128){
    const float* p = &xyzB[((size_t)(b * N_ + m0 + t - 64)) * 3];
    xb[t - 64] = make_float4(p[0], p[1], p[2], 0.f);
  }
  bf16x8 qfr[8];
  #pragma unroll
  for (int ks = 0; ks < 8; ks++)
    qfr[ks] = *reinterpret_cast<const bf16x8*>(
        &qdT[((size_t)(b * N_ + n0w + ln)) * C_ + ks * 32 + g * 8]);
  float qqv[4];
  #pragma unroll
  for (int r = 0; r < 4; r++) qqv[r] = qq[b * N_ + n0w + g * 4 + r];
  __syncthreads();
  float4 xav[4];
  #pragma unroll
  for (int r = 0; r < 4; r++) xav[r] = xa[w * 16 + g * 4 + r];

  #pragma unroll
  for (int mt = 0; mt < 4; mt++){
    f32x4 a = (f32x4){0.f, 0.f, 0.f, 0.f};
    #pragma unroll
    for (int ks = 0; ks < 8; ks++){
      bf16x8 kfr = *reinterpret_cast<const bf16x8*>(
          &kdT[((size_t)(b * N_ + m0 + mt * 16 + ln)) * C_ + ks * 32 + g * 8]);
      a = __builtin_amdgcn_mfma_f32_16x16x32_bf16(qfr[ks], kfr, a, 0, 0, 0);
    }
    float kkv = kk[b * N_ + m0 + mt * 16 + ln];
    float4 xbv = xb[mt * 16 + ln];
    #pragma unroll
    for (int r = 0; r < 4; r++){
      float d2 = qqv[r] + kkv - 2.f * a[r];
      float fd = sqrtf(fmaxf(d2, 0.f)) * LOG2E;   // store in log2 domain
      float dx = xav[r].x - xbv.x, dy = xav[r].y - xbv.y, dz = xav[r].z - xbv.z;
      float sd = sqrtf(dx * dx + dy * dy + dz * dz);
      sbl[w][g * 4 + r][mt * 16 + ln] = packh2(fd, sd);
    }
  }
  #pragma unroll
  for (int it = 0; it < 4; it++){
    int row = it * 4 + (lane >> 4), cq = lane & 15;
    uint4 v = *reinterpret_cast<const uint4*>(&sbl[w][row][cq * 4]);
    *reinterpret_cast<uint4*>(&fsd[((size_t)(b * N_ + n0w + row)) * N_ + m0 + cq * 4]) = v;
  }
}

// ---- dual-path flash attention: defer-max + per-lane sums + exp2 domain ----
struct TileRegs { uint4 fu[4]; bf16x8 kf[4]; };

__device__ __forceinline__ void load_tile(TileRegs& T, const __bf16* kbase,
    const unsigned int* fsdrow, int m0, int ln, int g){
  #pragma unroll
  for (int mt = 0; mt < 4; mt++){
    T.fu[mt] = *reinterpret_cast<const uint4*>(&fsdrow[m0 + mt * 16 + g * 4]);
    T.kf[mt] = *reinterpret_cast<const bf16x8*>(&kbase[(size_t)(m0 + mt * 16 + ln) * HD_ + g * 8]);
  }
}

__device__ __forceinline__ void compute_tile4(const TileRegs& T,
    const _Float16* vbase, int m0, int ln, int g, bf16x8 qf,
    const float* Ac, const float* Bc, const float* W2h, float C0,
    f32x4* os, f32x4* od, float& ms, float& lps, float& md, float& lpd){
  // swapped QK^T (log2 domain via q prescale)
  f32x4 sa[4];
  #pragma unroll
  for (int mt = 0; mt < 4; mt++){
    f32x4 z = (f32x4){0.f, 0.f, 0.f, 0.f};
    sa[mt] = __builtin_amdgcn_mfma_f32_16x16x32_bf16(T.kf[mt], qf, z, 0, 0, 0);
  }
  // V loads issued early
  f16x4 vf[2][4];
  #pragma unroll
  for (int mt = 0; mt < 4; mt++)
    #pragma unroll
    for (int dt = 0; dt < 2; dt++)
      vf[dt][mt] = *reinterpret_cast<const f16x4*>(
          &vbase[(size_t)(dt * 16 + ln) * N_ + m0 + mt * 16 + g * 4]);
  // scores + shared bias MLP
  f32x4 dvv[4];
  float mxs = -3e38f, mxd = -3e38f;
  #pragma unroll
  for (int mt = 0; mt < 4; mt++){
    #pragma unroll
    for (int r = 0; r < 4; r++){
      unsigned int uu = (r == 0) ? T.fu[mt].x : (r == 1) ? T.fu[mt].y
                      : (r == 2) ? T.fu[mt].z : T.fu[mt].w;
      float fdl, sd;
      unpackh2(uu, fdl, sd);
      float u0 = fmaxf(fmaf(Ac[0], sd, Bc[0]), 0.f);
      float u1 = fmaxf(fmaf(Ac[1], sd, Bc[1]), 0.f);
      float u2 = fmaxf(fmaf(Ac[2], sd, Bc[2]), 0.f);
      float u3 = fmaxf(fmaf(Ac[3], sd, Bc[3]), 0.f);
      float bias = fmaf(W2h[0], u0, fmaf(W2h[1], u1, fmaf(W2h[2], u2, fmaf(W2h[3], u3, C0))));
      float s = sa[mt][r] + bias;
      float d = fdl + bias;
      sa[mt][r] = s; dvv[mt][r] = d;
      mxs = fmaxf(mxs, s); mxd = fmaxf(mxd, d);
    }
  }
  // defer-max: vote, full update only on growth events (rare)
  if (!__all(mxs <= ms + THRv)){
    float mr = fmaxf(mxs, __shfl_xor(mxs, 16));
    mr = fmaxf(mr, __shfl_xor(mr, 32));
    float nms = fmaxf(ms, mr);
    float als = fexp2(ms - nms);
    ms = nms; lps *= als;
    float a0 = __shfl(als, g * 4 + 0), a1 = __shfl(als, g * 4 + 1);
    float a2 = __shfl(als, g * 4 + 2), a3 = __shfl(als, g * 4 + 3);
    #pragma unroll
    for (int dt = 0; dt < 2; dt++){
      os[dt][0] *= a0; os[dt][1] *= a1; os[dt][2] *= a2; os[dt][3] *= a3;
    }
  }
  if (!__all(mxd <= md + THRv)){
    float mr = fmaxf(mxd, __shfl_xor(mxd, 16));
    mr = fmaxf(mr, __shfl_xor(mr, 32));
    float nmd = fmaxf(md, mr);
    float ald = fexp2(md - nmd);
    md = nmd; lpd *= ald;
    float a0 = __shfl(ald, g * 4 + 0), a1 = __shfl(ald, g * 4 + 1);
    float a2 = __shfl(ald, g * 4 + 2), a3 = __shfl(ald, g * 4 + 3);
    #pragma unroll
    for (int dt = 0; dt < 2; dt++){
      od[dt][0] *= a0; od[dt][1] *= a1; od[dt][2] *= a2; od[dt][3] *= a3;
    }
  }
  // exp2 + pack + lane-local sums
  f16x4 pAs[4], pAd[4];
  #pragma unroll
  for (int mt = 0; mt < 4; mt++){
    float p0 = fexp2(sa[mt][0] - ms), p1 = fexp2(sa[mt][1] - ms);
    float p2 = fexp2(sa[mt][2] - ms), p3 = fexp2(sa[mt][3] - ms);
    lps += (p0 + p1) + (p2 + p3);
    pAs[mt] = pack4(p0, p1, p2, p3);
    float q0 = fexp2(dvv[mt][0] - md), q1 = fexp2(dvv[mt][1] - md);
    float q2 = fexp2(dvv[mt][2] - md), q3 = fexp2(dvv[mt][3] - md);
    lpd += (q0 + q1) + (q2 + q3);
    pAd[mt] = pack4(q0, q1, q2, q3);
  }
  // PV (P already in A-fragment layout)
  #pragma unroll
  for (int mt = 0; mt < 4; mt++)
    #pragma unroll
    for (int dt = 0; dt < 2; dt++){
      os[dt] = __builtin_amdgcn_mfma_f32_16x16x16f16(pAs[mt], vf[dt][mt], os[dt], 0, 0, 0);
      od[dt] = __builtin_amdgcn_mfma_f32_16x16x16f16(pAd[mt], vf[dt][mt], od[dt], 0, 0, 0);
    }
}

__global__ __launch_bounds__(256) void dual_attn4(
    const __bf16* __restrict__ qpk, const __bf16* __restrict__ kpk,
    const _Float16* __restrict__ vph, const unsigned int* __restrict__ fsd,
    const float* __restrict__ sbw1, const float* __restrict__ sbg, const float* __restrict__ sbb,
    const float* __restrict__ sbm, const float* __restrict__ sbv,
    const float* __restrict__ sbw2, const float* __restrict__ sbb2,
    _Float16* __restrict__ partO, float* __restrict__ statM, float* __restrict__ statL){
  const int t = threadIdx.x, w = t >> 6, lane = t & 63, ln = lane & 15, g = lane >> 4;
  const int h = blockIdx.y;
  const int b = blockIdx.z >> 1, split = blockIdx.z & 1;
  const int nbase = blockIdx.x * 64 + w * 16;
  const int n = nbase + ln;
  const int mstart = split * (N_ / 2);

  float Ac[4], Bc[4], W2h[4];
  #pragma unroll
  for (int j = 0; j < 4; j++){
    float rs = rsqrtf(sbv[j] + EPSf);
    Ac[j]  = rfl(-sbw1[j] * rs * sbg[j]);
    Bc[j]  = rfl(-sbm[j] * rs * sbg[j] + sbb[j]);
    W2h[j] = rfl(sbw2[h * 4 + j]) * LOG2E;   // bias in log2 domain
  }
  float C0 = rfl(sbb2[h]) * LOG2E;

  bf16x8 qf = *reinterpret_cast<const bf16x8*>(
      &qpk[(((size_t)(b * H_ + h)) * N_ + n) * HD_ + g * 8]);
  const unsigned int* fsdrow = &fsd[((size_t)(b * N_ + n)) * N_];
  const __bf16* kbase = &kpk[(((size_t)(b * H_ + h)) * N_) * HD_];
  const _Float16* vbase = &vph[((size_t)(b * C_ + h * HD_)) * N_];

  f32x4 os[2], od[2];
  #pragma unroll
  for (int i = 0; i < 2; i++){ os[i] = (f32x4){0.f,0.f,0.f,0.f}; od[i] = (f32x4){0.f,0.f,0.f,0.f}; }
  float ms = -3e38f, lps = 0.f, md = -3e38f, lpd = 0.f;

  TileRegs TA, TB;
  load_tile(TA, kbase, fsdrow, mstart, ln, g);
  for (int i = 0; i < 16; i += 2){
    int m0 = mstart + i * 64;
    load_tile(TB, kbase, fsdrow, m0 + 64, ln, g);
    compute_tile4(TA, vbase, m0, ln, g, qf, Ac, Bc, W2h, C0, os, od, ms, lps, md, lpd);
    if (i + 2 < 16) load_tile(TA, kbase, fsdrow, m0 + 128, ln, g);
    compute_tile4(TB, vbase, m0 + 64, ln, g, qf, Ac, Bc, W2h, C0, os, od, ms, lps, md, lpd);
  }

  // final row sums (one reduce for the whole kernel)
  lps += __shfl_xor(lps, 16); lps += __shfl_xor(lps, 32);
  lpd += __shfl_xor(lpd, 16); lpd += __shfl_xor(lpd, 32);
  float is = 1.f / lps, idd = 1.f / lpd;
  float isr[4], idr[4];
  #pragma unroll
  for (int r = 0; r < 4; r++){
    isr[r] = __shfl(is, g * 4 + r);
    idr[r] = __shfl(idd, g * 4 + r);
  }
  #pragma unroll
  for (int dt = 0; dt < 2; dt++)
    #pragma unroll
    for (int r = 0; r < 4; r++){
      int nn = nbase + g * 4 + r;
      int ch = h * HD_ + dt * 16 + ln;
      size_t p0 = (((size_t)(0 * 2 + split) * B_ + b) * N_ + nn) * C_ + ch;
      size_t p1 = (((size_t)(2 + split) * B_ + b) * N_ + nn) * C_ + ch;
      partO[p0] = (_Float16)(os[dt][r] * isr[r]);
      partO[p1] = (_Float16)(od[dt][r] * idr[r]);
    }
  if (lane < 16){
    int nn = nbase + lane;
    size_t s0 = (((size_t)(0 * 2 + split) * B_ + b) * H_ + h) * N_ + nn;
    size_t s1 = (((size_t)(2 + split) * B_ + b) * H_ + h) * N_ + nn;
    statM[s0] = ms; statL[s0] = lps;
    statM[s1] = md; statL[s1] = lpd;
  }
}

// ---- combine m-splits + LN -> bf16 (stats in log2 domain) -------------------
__global__ __launch_bounds__(256) void combine_ln(
    const _Float16* __restrict__ partO, const float* __restrict__ statM,
    const float* __restrict__ statL, __bf16* __restrict__ csLN, __bf16* __restrict__ cdLN,
    const float* __restrict__ lsg, const float* __restrict__ lsb,
    const float* __restrict__ ldg, const float* __restrict__ ldb){
  const int path = blockIdx.y;
  const int w = threadIdx.x >> 6, lane = threadIdx.x & 63;
  const size_t row = (size_t)blockIdx.x * 4 + w;    // b*N + n
  const int b = (int)(row >> 11), n = (int)(row & (N_ - 1));
  const int h = lane >> 3;
  const float* gg = path ? ldg : lsg;
  const float* bb = path ? ldb : lsb;
  __bf16* dst = path ? cdLN : csLN;

  size_t pb0 = (((size_t)(path * 2 + 0) * B_ + b) * N_ + n) * C_ + lane * 4;
  size_t pb1 = (((size_t)(path * 2 + 1) * B_ + b) * N_ + n) * C_ + lane * 4;
  f16x4 p0 = *reinterpret_cast<const f16x4*>(&partO[pb0]);
  f16x4 p1 = *reinterpret_cast<const f16x4*>(&partO[pb1]);
  size_t sb0 = (((size_t)(path * 2 + 0) * B_ + b) * H_ + h) * N_ + n;
  size_t sb1 = (((size_t)(path * 2 + 1) * B_ + b) * H_ + h) * N_ + n;
  float m0 = statM[sb0], l0 = statL[sb0];
  float m1 = statM[sb1], l1 = statL[sb1];
  float M = fmaxf(m0, m1);
  float w0 = l0 * fexp2(m0 - M), w1 = l1 * fexp2(m1 - M);
  float inv = 1.f / (w0 + w1);
  float o[4];
  #pragma unroll
  for (int j = 0; j < 4; j++)
    o[j] = (w0 * (float)p0[j] + w1 * (float)p1[j]) * inv;

  float s1 = o[0] + o[1] + o[2] + o[3];
  float s2 = o[0]*o[0] + o[1]*o[1] + o[2]*o[2] + o[3]*o[3];
  #pragma unroll
  for (int off = 1; off < 64; off <<= 1){
    s1 += __shfl_xor(s1, off);
    s2 += __shfl_xor(s2, off);
  }
  float mu = s1 / (float)C_;
  float rs = rsqrtf(s2 / (float)C_ - mu * mu + EPSf);
  float4 g4 = *reinterpret_cast<const float4*>(&gg[lane * 4]);
  float4 b4 = *reinterpret_cast<const float4*>(&bb[lane * 4]);
  alignas(8) __bf16 o4[4];
  o4[0] = (__bf16)((o[0] - mu) * rs * g4.x + b4.x);
  o4[1] = (__bf16)((o[1] - mu) * rs * g4.y + b4.y);
  o4[2] = (__bf16)((o[2] - mu) * rs * g4.z + b4.z);
  o4[3] = (__bf16)((o[3] - mu) * rs * g4.w + b4.w);
  *reinterpret_cast<uint2*>(&dst[row * C_ + lane * 4]) = *reinterpret_cast<uint2*>(o4);
}

// ---- fusion stage 1 ---------------------------------------------------------
__global__ __launch_bounds__(256) void fusion1_mfma(const __bf16* __restrict__ fanT,
    const __bf16* __restrict__ csLN, const __bf16* __restrict__ cdLN,
    __bf16* __restrict__ X1T, const float* __restrict__ fw1,
    const float* __restrict__ fbg, const float* __restrict__ fbb,
    const float* __restrict__ fbm, const float* __restrict__ fbv){
  const int t = threadIdx.x, w = t >> 6, lane = t & 63, ln = lane & 15, g = lane >> 4;
  const int b = blockIdx.z, o0 = blockIdx.y * 64, n0w = blockIdx.x * 64 + w * 16;
  f32x4 acc[4];
  #pragma unroll
  for (int i = 0; i < 4; i++) acc[i] = (f32x4){0.f, 0.f, 0.f, 0.f};
  const __bf16* segs[3] = {fanT, csLN, cdLN};
  #pragma unroll
  for (int ks = 0; ks < 24; ks++){
    const __bf16* base = segs[ks >> 3];
    int coff = (ks & 7) * 32 + g * 8;
    bf16x8 af = *reinterpret_cast<const bf16x8*>(
        &base[((size_t)(b * N_ + n0w + ln)) * C_ + coff]);
    #pragma unroll
    for (int ot = 0; ot < 4; ot++){
      bf16x8 bf = cvt8(&fw1[(size_t)(o0 + ot * 16 + ln) * (3 * C_) + ks * 32 + g * 8]);
      acc[ot] = __builtin_amdgcn_mfma_f32_16x16x32_bf16(af, bf, acc[ot], 0, 0, 0);
    }
  }
  #pragma unroll
  for (int ot = 0; ot < 4; ot++){
    int o = o0 + ot * 16 + ln;
    float mn = fbm[o], rs = rsqrtf(fbv[o] + EPSf), gg = fbg[o], be = fbb[o];
    #pragma unroll
    for (int r = 0; r < 4; r++){
      int n = n0w + g * 4 + r;
      float x = (acc[ot][r] - mn) * rs * gg + be;
      X1T[((size_t)(b * N_ + n)) * (2 * C_) + o] = (__bf16)fmaxf(x, 0.f);
    }
  }
}

// ---- fusion stage 2 ---------------------------------------------------------
__global__ __launch_bounds__(256) void fusion2_mfma(const __bf16* __restrict__ X1T,
    const float* __restrict__ fw2, const float* __restrict__ fb2,
    const float* __restrict__ featA, float* __restrict__ out){
  const int t = threadIdx.x, w = t >> 6, lane = t & 63, ln = lane & 15, g = lane >> 4;
  const int b = blockIdx.z, o0w = blockIdx.y * 64 + w * 16, n0 = blockIdx.x * 64;
  f32x4 acc[4];
  #pragma unroll
  for (int i = 0; i < 4; i++) acc[i] = (f32x4){0.f, 0.f, 0.f, 0.f};
  #pragma unroll
  for (int ks = 0; ks < 16; ks++){
    bf16x8 af = cvt8(&fw2[(size_t)(o0w + ln) * (2 * C_) + ks * 32 + g * 8]);
    #pragma unroll
    for (int nt = 0; nt < 4; nt++){
      bf16x8 bf = *reinterpret_cast<const bf16x8*>(
          &X1T[((size_t)(b * N_ + n0 + nt * 16 + ln)) * (2 * C_) + ks * 32 + g * 8]);
      acc[nt] = __builtin_amdgcn_mfma_f32_16x16x32_bf16(af, bf, acc[nt], 0, 0, 0);
    }
  }
  float bz[4];
  #pragma unroll
  for (int r = 0; r < 4; r++) bz[r] = fb2[o0w + g * 4 + r];
  #pragma unroll
  for (int nt = 0; nt < 4; nt++)
    #pragma unroll
    for (int r = 0; r < 4; r++){
      int o = o0w + g * 4 + r, n = n0 + nt * 16 + ln;
      size_t oi = ((size_t)(b * C_ + o)) * N_ + n;
      out[oi] = acc[nt][r] + bz[r] + featA[oi];
    }
}

extern "C" void kernel_launch(void* const* d_in, const int* in_sizes, int n_in,
                              void* d_out, int out_size, void* d_ws, size_t ws_size,
                              hipStream_t stream){
  (void)in_sizes; (void)n_in; (void)out_size;
  if (ws_size < WS_NEED) return;

  const float* xyzA  = (const float*)d_in[0];
  const float* featA = (const float*)d_in[1];
  const float* xyzB  = (const float*)d_in[2];
  const float* featB = (const float*)d_in[3];
  const float* qw  = (const float*)d_in[4];   const float* qb  = (const float*)d_in[5];
  const float* kw  = (const float*)d_in[6];   const float* kb  = (const float*)d_in[7];
  const float* vw  = (const float*)d_in[8];   const float* vb  = (const float*)d_in[9];
  const float* sbw1= (const float*)d_in[10];  const float* sbg = (const float*)d_in[11];
  const float* sbb = (const float*)d_in[12];  const float* sbm = (const float*)d_in[13];
  const float* sbv = (const float*)d_in[14];  const float* sbw2= (const float*)d_in[15];
  const float* sbb2= (const float*)d_in[16];
  const float* qdw = (const float*)d_in[17];  const float* qdb = (const float*)d_in[18];
  const float* kdw = (const float*)d_in[19];  const float* kdb = (const float*)d_in[20];
  const float* ling= (const float*)d_in[21];  const float* linb= (const float*)d_in[22];
  const float* lsg = (const float*)d_in[23];  const float* lsb = (const float*)d_in[24];
  const float* ldg = (const float*)d_in[25];  const float* ldb = (const float*)d_in[26];
  const float* fw1 = (const float*)d_in[27];  const float* fbg = (const float*)d_in[28];
  const float* fbb = (const float*)d_in[29];  const float* fbm = (const float*)d_in[30];
  const float* fbv = (const float*)d_in[31];  const float* fw2 = (const float*)d_in[32];
  const float* fb2 = (const float*)d_in[33];

  char* ws = (char*)d_ws;
  __bf16*   fanT = (__bf16*)(ws + OFF_FANT);
  __bf16*   fbT  = (__bf16*)(ws + OFF_FBT);
  __bf16*   qpk  = (__bf16*)(ws + OFF_QPK);
  __bf16*   kpk  = (__bf16*)(ws + OFF_KPK);
  _Float16* vph  = (_Float16*)(ws + OFF_VPK);
  __bf16*   qdT  = (__bf16*)(ws + OFF_QDT);
  __bf16*   kdT  = (__bf16*)(ws + OFF_KDT);
  float*    qq   = (float*)(ws + OFF_QQ);
  float*    kk   = (float*)(ws + OFF_KK);
  unsigned int* fsd = (unsigned int*)(ws + OFF_FSD);
  _Float16* partO = (_Float16*)(ws + OFF_PART);
  float*    statM = (float*)(ws + OFF_STATM);
  float*    statL = (float*)(ws + OFF_STATL);
  __bf16*   csLN  = (__bf16*)(ws + OFF_CSLN);
  __bf16*   cdLN  = (__bf16*)(ws + OFF_CDLN);
  __bf16*   X1T   = (__bf16*)(ws + OFF_X1T);
  float*    out   = (float*)d_out;

  prep_kernel<<<dim3(192, B_), 256, 0, stream>>>(featA, featB, fanT, fbT, ling, linb);
  proj_mfma<<<dim3(N_ / 64, C_ / 64, 5 * B_), 256, 0, stream>>>(
      fanT, fbT, fanT, qw, qb, kw, kb, vw, vb, qdw, qdb, kdw, kdb);
  norms_b<<<dim3(N_ / 64, B_), 256, 0, stream>>>(qdT, kdT, qq, kk);
  pairdist_mfma<<<dim3(N_ / 64, N_ / 64, B_), 256, 0, stream>>>(
      qdT, kdT, qq, kk, xyzA, xyzB, fsd);
  dual_attn4<<<dim3(N_ / 64, H_, B_ * 2), 256, 0, stream>>>(
      qpk, kpk, vph, fsd, sbw1, sbg, sbb, sbm, sbv, sbw2, sbb2,
      partO, statM, statL);
  combine_ln<<<dim3(B_ * N_ / 4, 2), 256, 0, stream>>>(
      partO, statM, statL, csLN, cdLN, lsg, lsb, ldg, ldb);
  fusion1_mfma<<<dim3(N_ / 64, (2 * C_) / 64, B_), 256, 0, stream>>>(
      fanT, csLN, cdLN, X1T, fw1, fbg, fbb, fbm, fbv);
  fusion2_mfma<<<dim3(N_ / 64, C_ / 64, B_), 256, 0, stream>>>(
      X1T, fw2, fb2, featA, out);
}